// Round 5
// baseline (4685.510 us; speedup 1.0000x reference)
//
#include <hip/hip_runtime.h>
#include <cstdint>
#include <cstddef>

typedef short bf16x8 __attribute__((ext_vector_type(8)));
typedef float f32x4 __attribute__((ext_vector_type(4)));
typedef int   i32x4 __attribute__((ext_vector_type(4)));
typedef unsigned int u32x2 __attribute__((ext_vector_type(2)));

#define DEV static __device__ __forceinline__

DEV unsigned short f2bf(float x){
  union{float f; unsigned int u;} v; v.f = x;
  unsigned int r = (v.u + 0x7FFFu + ((v.u>>16)&1u)) >> 16;
  return (unsigned short)r;
}
DEV float bf2f(unsigned short h){
  union{unsigned int u; float f;} v; v.u = ((unsigned int)h)<<16;
  return v.f;
}
// unpack bf16 half of a dword: hi=0 -> low u16, hi=1 -> high u16
DEV float bfsel(int dw, int hi){
  union{unsigned int u; float f;} v;
  v.u = hi ? ((unsigned int)dw & 0xFFFF0000u) : ((unsigned int)dw << 16);
  return v.f;
}
// fast gates: v_exp_f32 + v_rcp_f32
DEV float sigm_f(float x){ return __builtin_amdgcn_rcpf(1.0f + __expf(-x)); }
DEV float tanh_f(float x){ return 2.0f*__builtin_amdgcn_rcpf(1.0f + __expf(-2.0f*x)) - 1.0f; }

// ---------------- prep kernels ----------------
__global__ void k_f2bf(const float* __restrict__ src, unsigned short* __restrict__ dst, int n){
  int i = blockIdx.x*256 + threadIdx.x;
  if(i<n) dst[i] = f2bf(src[i]);
}

__global__ void k_transpose(const float* __restrict__ in, float* __restrict__ out, int R, int C){
  int i = blockIdx.x*256 + threadIdx.x;
  if(i < R*C){ int r = i/C, c = i - r*C; out[(size_t)c*R + r] = in[i]; }
}

__global__ void k_attw1(const float* __restrict__ w1, unsigned short* __restrict__ dst){
  int i = blockIdx.x*256 + threadIdx.x;  // 128*1824
  if(i < 128*1824){
    int r = i/1824, cc = i - r*1824;
    float v = (r<100 && cc<1794)? w1[r*1794 + cc] : 0.0f;
    dst[i] = f2bf(v);
  }
}

__global__ void k_attwT(const float* __restrict__ aw, unsigned short* __restrict__ dst){
  int i = blockIdx.x*256 + threadIdx.x;  // out[n*256+k] = aw[k*256+n]
  if(i<65536){ int n = i>>8, k = i&255; dst[i] = f2bf(aw[k*256 + n]); }
}

__global__ void k_b1pad(const float* __restrict__ b1, float* __restrict__ dst){
  int i = threadIdx.x; if(i<128) dst[i] = (i<100)? b1[i] : 0.0f;
}

__global__ void k_copy(const float* __restrict__ s, float* __restrict__ d, int n){
  int i = blockIdx.x*256+threadIdx.x; if(i<n) d[i]=s[i];
}

// ---------------- generic bf16 MFMA GEMM: C(M,N) = A(M,K) @ Bt(N,K)^T ----------------
__global__ __launch_bounds__(256) void k_gemm_bf16(
    const unsigned short* __restrict__ A, const unsigned short* __restrict__ Bt,
    int K, const float* __restrict__ bias, int act,
    float* __restrict__ outf, unsigned short* __restrict__ outbf, int ldc)
{
  int lane = threadIdx.x & 63, wave = threadIdx.x >> 6;
  int m_base = blockIdx.x*64 + (wave>>1)*32;
  int n_base = blockIdx.y*64 + (wave&1)*32;
  int cl = lane & 15, q4 = lane >> 4;
  f32x4 acc00={0.f,0.f,0.f,0.f}, acc01=acc00, acc10=acc00, acc11=acc00;
  const int kf_n = K >> 5;
  for(int kf=0; kf<kf_n; kf++){
    int ko = kf*32 + q4*8;
    bf16x8 a0 = *(const bf16x8*)(A + (size_t)(m_base+cl)*K + ko);
    bf16x8 a1 = *(const bf16x8*)(A + (size_t)(m_base+16+cl)*K + ko);
    bf16x8 b0 = *(const bf16x8*)(Bt + (size_t)(n_base+cl)*K + ko);
    bf16x8 b1 = *(const bf16x8*)(Bt + (size_t)(n_base+16+cl)*K + ko);
    acc00 = __builtin_amdgcn_mfma_f32_16x16x32_bf16(a0,b0,acc00,0,0,0);
    acc01 = __builtin_amdgcn_mfma_f32_16x16x32_bf16(a0,b1,acc01,0,0,0);
    acc10 = __builtin_amdgcn_mfma_f32_16x16x32_bf16(a1,b0,acc10,0,0,0);
    acc11 = __builtin_amdgcn_mfma_f32_16x16x32_bf16(a1,b1,acc11,0,0,0);
  }
  #pragma unroll
  for(int mt=0; mt<2; mt++){
    #pragma unroll
    for(int nt=0; nt<2; nt++){
      f32x4 av = (mt==0)? (nt==0?acc00:acc01) : (nt==0?acc10:acc11);
      int col = n_base + nt*16 + cl;
      float bv = bias? bias[col] : 0.0f;
      #pragma unroll
      for(int r=0;r<4;r++){
        int row = m_base + mt*16 + q4*4 + r;
        float v = av[r] + bv;
        if(act) v = tanh_f(v);
        if(outbf) outbf[(size_t)row*ldc + col] = f2bf(v);
        else      outf [(size_t)row*ldc + col] = v;
      }
    }
  }
}

// ---------------- gi GEMM with lane-packed scatter epilogue ----------------
// Computes gi = x @ w_ih^T + b_ih and scatters each recurrence-lane's 24 values
// contiguous. NEW owner mapping (transposed C layout in k_gru_rec): the
// recurrence lane (q4o*16 + brow) owns batch row brow and hidden cols
// w*32 + s*16 + q4o*4 + ro. idx = ((((t*2+blk)*8 + w)*64 + lane2)*24 + g*8 + s*4 + ro.
// A rows are b*steps + t (steps = 1<<ss). N = 768.
__global__ __launch_bounds__(256) void k_gemm_gi(
    const unsigned short* __restrict__ A, const unsigned short* __restrict__ Bt,
    const float* __restrict__ bias, unsigned short* __restrict__ gi_out, int ss)
{
  int lane = threadIdx.x & 63, wave = threadIdx.x >> 6;
  int m_base = blockIdx.x*64 + (wave>>1)*32;
  int n_base = blockIdx.y*64 + (wave&1)*32;
  int cl = lane & 15, q4 = lane >> 4;
  f32x4 acc00={0.f,0.f,0.f,0.f}, acc01=acc00, acc10=acc00, acc11=acc00;
  for(int kf=0; kf<4; kf++){   // K = 128
    int ko = kf*32 + q4*8;
    bf16x8 a0 = *(const bf16x8*)(A + (size_t)(m_base+cl)*128 + ko);
    bf16x8 a1 = *(const bf16x8*)(A + (size_t)(m_base+16+cl)*128 + ko);
    bf16x8 b0 = *(const bf16x8*)(Bt + (size_t)(n_base+cl)*128 + ko);
    bf16x8 b1 = *(const bf16x8*)(Bt + (size_t)(n_base+16+cl)*128 + ko);
    acc00 = __builtin_amdgcn_mfma_f32_16x16x32_bf16(a0,b0,acc00,0,0,0);
    acc01 = __builtin_amdgcn_mfma_f32_16x16x32_bf16(a0,b1,acc01,0,0,0);
    acc10 = __builtin_amdgcn_mfma_f32_16x16x32_bf16(a1,b0,acc10,0,0,0);
    acc11 = __builtin_amdgcn_mfma_f32_16x16x32_bf16(a1,b1,acc11,0,0,0);
  }
  const int tmask = (1<<ss) - 1;
  #pragma unroll
  for(int mt=0; mt<2; mt++){
    #pragma unroll
    for(int nt=0; nt<2; nt++){
      f32x4 av = (mt==0)? (nt==0?acc00:acc01) : (nt==0?acc10:acc11);
      int col = n_base + nt*16 + cl;
      float bv = bias[col];
      int g = col >> 8, rem = col & 255;
      int w = rem >> 5, s = (rem>>4)&1, q4o = (rem>>2)&3, ro = rem&3;
      #pragma unroll
      for(int r=0;r<4;r++){
        int arow = m_base + mt*16 + q4*4 + r;
        int t = arow & tmask, b = arow >> ss;
        int blk = b >> 4, brow = b & 15;
        int lane2 = q4o*16 + brow;
        size_t idx = ((((size_t)t*2 + blk)*8 + w)*64 + lane2)*24 + g*8 + s*4 + ro;
        gi_out[idx] = f2bf(av[r] + bv);
      }
    }
  }
}

// ---------------- GRU recurrence ----------------
// Round-0 phase skeleton (best measured: 2026 us): 4 blocks, 512 threads,
// gate-local tiling, W register-resident, h double-buffered in LDS, ONE
// __syncthreads per step, gi loaded at step top (NO cross-step prefetch —
// R4 showed it regresses).
// CHANGE vs round 0: MFMA operands SWAPPED — mfma(A=W, B=h). Both fragments
// are bit-identical to before (W row cl / k q4*8; h row cl / k q4*8), but the
// C layout transposes: lane owns (batch=cl, hidden cols q4*4+{0..3}).
//  -> bias folds into acc init as f32x4 (exact; element r <-> hidden col r)
//  -> h LDS write: 2x cvt_pk + one 8B store per subtile (was 8x b16 scatter)
//  -> c_out store: dwordx4 x2 (was 8x dword)
__global__ __launch_bounds__(512,1) void k_gru_rec(
    const unsigned short* __restrict__ whh_c, const unsigned short* __restrict__ whh_q,
    const unsigned short* __restrict__ gi_c,  const unsigned short* __restrict__ gi_q,
    const float* __restrict__ bhh_c, const float* __restrict__ bhh_q,
    const float* __restrict__ h0_c,  const float* __restrict__ h0_q,
    float* __restrict__ c_out, float* __restrict__ q_hT)
{
  __shared__ unsigned short hb0[16*264];   // double-buffered h (row stride 264 u16)
  __shared__ unsigned short hb1[16*264];

  const int blk = blockIdx.x;
  const bool isq = blk >= 2;
  const int cls = isq? blk-2 : blk;        // block index within class (0/1)
  const int b0 = cls * 16;
  const unsigned short* W  = isq? whh_q : whh_c;
  const unsigned short* GI = isq? gi_q  : gi_c;
  const float* bhh = isq? bhh_q : bhh_c;
  const float* h0  = isq? h0_q  : h0_c;
  const int steps  = isq? 32 : 1024;

  const int tid = threadIdx.x;
  const int lane = tid & 63, wave = tid >> 6;
  const int cl = lane & 15, q4 = lane >> 4;

  // W fragments: [gate][subtile][kfrag] — identical bits to round 0; now used
  // as the A operand. Lane holds W_g[row = g*256 + wave*32 + s*16 + cl][k=q4*8..]
  bf16x8 Bf[3][2][8];
  #pragma unroll
  for(int g=0; g<3; g++)
    #pragma unroll
    for(int s=0; s<2; s++){
      const unsigned short* wrow = W + (size_t)(g*256 + wave*32 + s*16 + cl)*256;
      #pragma unroll
      for(int kf=0; kf<8; kf++)
        Bf[g][s][kf] = *(const bf16x8*)(wrow + kf*32 + q4*8);
    }

  // per-lane bias VECTORS for owned cols (consumed via accumulator init):
  // acc element r corresponds to hidden col wave*32 + s*16 + q4*4 + r
  f32x4 bv[3][2];
  #pragma unroll
  for(int g=0; g<3; g++)
    #pragma unroll
    for(int s=0; s<2; s++)
      bv[g][s] = *(const f32x4*)&bhh[g*256 + wave*32 + s*16 + q4*4];

  // h in registers: lane owns (batch row = cl, hidden cols wave*32+s*16+q4*4+r)
  float hreg[2][4];
  #pragma unroll
  for(int s=0; s<2; s++){
    const int colb = wave*32 + s*16 + q4*4;
    f32x4 v = *(const f32x4*)&h0[(size_t)(b0+cl)*256 + colb];
    #pragma unroll
    for(int r=0; r<4; r++){
      hreg[s][r] = v[r];
      hb0[cl*264 + colb + r] = f2bf(v[r]);
    }
  }
  __syncthreads();

  unsigned short* hb_rd = hb0;
  unsigned short* hb_wr = hb1;

  // per-lane gi base for this (blk, wave, lane)
  const unsigned short* gi_lane = GI + (((size_t)cls*8 + wave)*64 + lane)*24;
  const size_t gi_tstride = (size_t)2*8*64*24;   // per-t stride in u16

  for(int t=0; t<steps; t++){
    // gi(t): 3x dwordx4 (48 B contiguous per lane); consumed in phase B
    const unsigned short* gp = gi_lane + (size_t)t*gi_tstride;
    i32x4 G0 = *(const i32x4*)(gp);        // gate r : [s0:r0..r3 | s1:r0..r3]
    i32x4 G1 = *(const i32x4*)(gp + 8);    // gate z
    i32x4 G2 = *(const i32x4*)(gp + 16);   // gate n

    // deferred c_out store of h(t-1): overlaps with MFMA phase; dwordx4
    if(!isq && t>0){
      #pragma unroll
      for(int s=0; s<2; s++){
        f32x4 hv = {hreg[s][0], hreg[s][1], hreg[s][2], hreg[s][3]};
        *(f32x4*)&c_out[((size_t)(b0+cl)*1024 + (t-1))*256 + wave*32 + s*16 + q4*4] = hv;
      }
    }

    // phase A: gates^T = W @ h^T  (48 MFMAs/wave; fragments unchanged,
    // operands swapped). acc init = per-col bias vector (exact).
    f32x4 acc[3][2];
    #pragma unroll
    for(int g=0; g<3; g++)
      #pragma unroll
      for(int s=0; s<2; s++) acc[g][s] = bv[g][s];
    #pragma unroll
    for(int kf=0; kf<8; kf++){
      bf16x8 a = *(const bf16x8*)&hb_rd[cl*264 + kf*32 + q4*8];
      #pragma unroll
      for(int g=0; g<3; g++)
        #pragma unroll
        for(int s=0; s<2; s++)
          acc[g][s] = __builtin_amdgcn_mfma_f32_16x16x32_bf16(Bf[g][s][kf], a, acc[g][s], 0,0,0);
    }

    // phase B: in-register GRU update; lane's 4 outputs per subtile are
    // 4 CONSECUTIVE hidden cols of one batch row -> packed 8B LDS store.
    #pragma unroll
    for(int s=0; s<2; s++){
      const int colb = wave*32 + s*16 + q4*4;
      float x[4];
      #pragma unroll
      for(int r=0; r<4; r++){
        const int k = s*4 + r;
        float gir = bfsel(G0[k>>1], k&1);
        float giz = bfsel(G1[k>>1], k&1);
        float gin = bfsel(G2[k>>1], k&1);
        float rr = sigm_f(gir + acc[0][s][r]);
        float zz = sigm_f(giz + acc[1][s][r]);
        float nn = tanh_f(gin + rr*acc[2][s][r]);
        x[r] = nn + zz*(hreg[s][r] - nn);
        hreg[s][r] = x[r];
      }
      unsigned int d01, d23;
      asm("v_cvt_pk_bf16_f32 %0, %1, %2" : "=v"(d01) : "v"(x[0]), "v"(x[1]));
      asm("v_cvt_pk_bf16_f32 %0, %1, %2" : "=v"(d23) : "v"(x[2]), "v"(x[3]));
      u32x2 dv = {d01, d23};
      *(u32x2*)&hb_wr[cl*264 + colb] = dv;
    }
    __syncthreads();   // hb_wr complete -> next step's phase A may read it
    unsigned short* tmp = hb_rd; hb_rd = hb_wr; hb_wr = tmp;
  }

  // final stores from hreg
  #pragma unroll
  for(int s=0; s<2; s++){
    const int colb = wave*32 + s*16 + q4*4;
    f32x4 hv = {hreg[s][0], hreg[s][1], hreg[s][2], hreg[s][3]};
    if(!isq) *(f32x4*)&c_out[((size_t)(b0+cl)*1024 + (steps-1))*256 + colb] = hv;
    else     *(f32x4*)&q_hT[(size_t)(b0+cl)*256 + colb] = hv;
  }
}

// ---------------- attention helpers ----------------
__global__ void k_gather(const float* __restrict__ c_out, const int* __restrict__ c_index,
                         float* __restrict__ c_sel, unsigned short* __restrict__ c_sel_bf){
  int row = blockIdx.x;                 // 0..4095 = b*128+s
  int b = row >> 7, s = row & 127;
  int idx = c_index[b*128 + s];
  float v = c_out[((size_t)b*1024 + idx)*256 + threadIdx.x];
  c_sel   [(size_t)row*256 + threadIdx.x] = v;
  c_sel_bf[(size_t)row*256 + threadIdx.x] = f2bf(v);
}

__global__ void k_feats(const float* __restrict__ c_sel, const float* __restrict__ cw,
                        const float* __restrict__ m_, const float* __restrict__ qh,
                        unsigned short* __restrict__ feats){
  int row = blockIdx.x, tid = threadIdx.x;
  int b = row >> 7;
  float cs  = c_sel[(size_t)row*256 + tid];
  float mj  = m_[b*256 + tid];
  float qj  = qh[b*256 + tid];
  float cwj = cw[(size_t)row*256 + tid];
  float dq = cwj*qj, dm = cwj*mj;
  #pragma unroll
  for(int o=32;o>0;o>>=1){ dq += __shfl_down(dq,o); dm += __shfl_down(dm,o); }
  __shared__ float rq[4], rm[4];
  int lane = tid&63, wave=tid>>6;
  if(lane==0){ rq[wave]=dq; rm[wave]=dm; }
  __syncthreads();
  unsigned short* fr = feats + (size_t)row*1824;
  fr[tid]      = f2bf(cs);
  fr[256+tid]  = f2bf(mj);
  fr[512+tid]  = f2bf(qj);
  fr[768+tid]  = f2bf(cs*qj);
  fr[1024+tid] = f2bf(cs*mj);
  fr[1280+tid] = f2bf(fabsf(cs-qj));
  fr[1536+tid] = f2bf(fabsf(cs-mj));
  if(tid==0){
    float DQ = rq[0]+rq[1]+rq[2]+rq[3];
    float DM = rm[0]+rm[1]+rm[2]+rm[3];
    fr[1792]=f2bf(DQ); fr[1793]=f2bf(DM);
  }
  if(tid<30) fr[1794+tid]=0;   // zero K-pad
}

__global__ void k_scores(const float* __restrict__ h1, const float* __restrict__ w2,
                         const float* __restrict__ b2, float* __restrict__ scores){
  int row = blockIdx.x*4 + (threadIdx.x>>6);
  int lane = threadIdx.x & 63;
  float v = 0.0f;
  if(lane < 100)    v += h1[(size_t)row*128 + lane]*w2[lane];
  if(lane+64 < 100) v += h1[(size_t)row*128 + lane+64]*w2[lane+64];
  #pragma unroll
  for(int o=32;o>0;o>>=1) v += __shfl_down(v,o);
  if(lane==0) scores[row] = v + b2[0];
}

__global__ void k_softmax_e(const float* __restrict__ scores, const int* __restrict__ len_c,
                            const float* __restrict__ c_sel, float* __restrict__ out_att,
                            float* __restrict__ e){
  __shared__ float red[256];
  __shared__ float p[128];
  int b = blockIdx.x, tid = threadIdx.x;
  int L = len_c[b];
  float s = -1e30f;
  if(tid<128 && tid<L) s = scores[b*128+tid];
  red[tid]=s; __syncthreads();
  for(int o=128;o>0;o>>=1){ if(tid<o) red[tid]=fmaxf(red[tid],red[tid+o]); __syncthreads(); }
  float mx = red[0]; __syncthreads();
  float ex = (tid<128 && tid<L)? __expf(s-mx) : 0.0f;
  red[tid]=ex; __syncthreads();
  for(int o=128;o>0;o>>=1){ if(tid<o) red[tid]+=red[tid+o]; __syncthreads(); }
  float inv = 1.0f/red[0];
  if(tid<128){ float pv = ex*inv; p[tid]=pv; out_att[b*128+tid]=pv; }
  __syncthreads();
  float acc = 0.0f;
  for(int si=0; si<128; si++) acc += p[si]*c_sel[((size_t)b*128+si)*256 + tid];
  e[b*256+tid] = acc;
}

// ---------------- small fp32 GRU cell (mem/ans updates), x = [x1 || x2] ----------------
__global__ void k_gru_cell(const float* __restrict__ x1, int len1,
                           const float* __restrict__ x2, int len2,
                           const float* __restrict__ hprev,
                           const float* __restrict__ wihT, const float* __restrict__ whhT,
                           const float* __restrict__ bih, const float* __restrict__ bhh,
                           float* __restrict__ hout){
  __shared__ float xs[2304];
  __shared__ float hs[256];
  int m = blockIdx.x, tid = threadIdx.x;
  int Kx = len1 + len2;
  for(int i=tid;i<len1;i+=256) xs[i] = x1[(size_t)m*len1 + i];
  for(int i=tid;i<len2;i+=256) xs[len1+i] = x2[(size_t)m*len2 + i];
  hs[tid] = hprev[m*256 + tid];
  __syncthreads();
  float ar=0, az=0, an=0;
  for(int k=0;k<Kx;k++){
    float xv = xs[k];
    const float* wr = wihT + (size_t)k*768;
    ar += xv*wr[tid]; az += xv*wr[256+tid]; an += xv*wr[512+tid];
  }
  float gr=0, gz=0, gn=0;
  for(int k=0;k<256;k++){
    float hv = hs[k];
    const float* wr = whhT + (size_t)k*768;
    gr += hv*wr[tid]; gz += hv*wr[256+tid]; gn += hv*wr[512+tid];
  }
  float rr = sigm_f(ar + bih[tid]     + gr + bhh[tid]);
  float zz = sigm_f(az + bih[256+tid] + gz + bhh[256+tid]);
  float nn = tanh_f(an + bih[512+tid] + rr*(gn + bhh[512+tid]));
  hout[m*256+tid] = (1.0f-zz)*nn + zz*hs[tid];
}

// ---------------- answer head ----------------
__global__ void k_logits(const float* __restrict__ msq, const float* __restrict__ out_wT,
                         const float* __restrict__ out_b, float* __restrict__ ylin){
  int i = blockIdx.x*256 + threadIdx.x;
  if(i >= 32*2000) return;
  int mrow = i/2000, n = i - mrow*2000;
  float acc = out_b[n];
  const float* mr = msq + mrow*256;
  for(int k=0;k<256;k++) acc += mr[k]*out_wT[(size_t)k*2000 + n];
  ylin[i] = acc;
}

__global__ void k_softmax_o(const float* __restrict__ x, float* __restrict__ y){
  __shared__ float red[256];
  int b = blockIdx.x, tid = threadIdx.x;
  const float* xr = x + (size_t)b*2000;
  float mx = -1e30f;
  for(int i=tid;i<2000;i+=256) mx = fmaxf(mx, xr[i]);
  red[tid]=mx; __syncthreads();
  for(int o=128;o>0;o>>=1){ if(tid<o) red[tid]=fmaxf(red[tid],red[tid+o]); __syncthreads(); }
  mx = red[0]; __syncthreads();
  float sum=0.0f;
  for(int i=tid;i<2000;i+=256) sum += __expf(xr[i]-mx);
  red[tid]=sum; __syncthreads();
  for(int o=128;o>0;o>>=1){ if(tid<o) red[tid]+=red[tid+o]; __syncthreads(); }
  float inv = 1.0f/red[0];
  for(int i=tid;i<2000;i+=256) y[(size_t)b*2000+i] = __expf(xr[i]-mx)*inv;
}

// ---------------- launch ----------------
extern "C" void kernel_launch(void* const* d_in, const int* in_sizes, int n_in,
                              void* d_out, int out_size, void* d_ws, size_t ws_size,
                              hipStream_t stream)
{
  const float* c        = (const float*)d_in[0];
  const float* q        = (const float*)d_in[1];
  const float* i_state  = (const float*)d_in[2];
  const float* q_state  = (const float*)d_in[3];
  const float* in_w_ih  = (const float*)d_in[4];
  const float* in_w_hh  = (const float*)d_in[5];
  const float* in_b_ih  = (const float*)d_in[6];
  const float* in_b_hh  = (const float*)d_in[7];
  const float* qe_w_ih  = (const float*)d_in[8];
  const float* qe_w_hh  = (const float*)d_in[9];
  const float* qe_b_ih  = (const float*)d_in[10];
  const float* qe_b_hh  = (const float*)d_in[11];
  const float* att_weight = (const float*)d_in[12];
  const float* att_w1   = (const float*)d_in[13];
  const float* att_b1   = (const float*)d_in[14];
  const float* att_w2   = (const float*)d_in[15];
  const float* att_b2   = (const float*)d_in[16];
  const float* mem_w_ih = (const float*)d_in[17];
  const float* mem_w_hh = (const float*)d_in[18];
  const float* mem_b_ih = (const float*)d_in[19];
  const float* mem_b_hh = (const float*)d_in[20];
  const float* out_w    = (const float*)d_in[21];
  const float* out_b    = (const float*)d_in[22];
  const float* ans_w_ih = (const float*)d_in[23];
  const float* ans_w_hh = (const float*)d_in[24];
  const float* ans_b_ih = (const float*)d_in[25];
  const float* ans_b_hh = (const float*)d_in[26];
  const int*   c_index  = (const int*)d_in[27];
  const int*   len_c    = (const int*)d_in[28];
  float* outp = (float*)d_out;   // [0,64000) y ; [64000,76288) att (3,32,128)

  char* wp = (char*)d_ws;
  auto take = [&](size_t nbytes)->char*{
    char* p = wp; wp += (nbytes + 255) & ~(size_t)255; return p;
  };
  unsigned short* c_bf      = (unsigned short*)take((size_t)32*1024*128*2);
  unsigned short* q_bf      = (unsigned short*)take((size_t)32*32*128*2);
  unsigned short* wih_in_bf = (unsigned short*)take(768*128*2);
  unsigned short* wih_qe_bf = (unsigned short*)take(768*128*2);
  unsigned short* whh_in_bf = (unsigned short*)take(768*256*2);
  unsigned short* whh_qe_bf = (unsigned short*)take(768*256*2);
  unsigned short* attwT_bf  = (unsigned short*)take(256*256*2);
  unsigned short* attw1_bf  = (unsigned short*)take(128*1824*2);
  float* b1pad              = (float*)take(128*4);
  float* out_wT             = (float*)take((size_t)256*2000*4);
  float* mem_wihT           = (float*)take(256*768*4);
  float* mem_whhT           = (float*)take(256*768*4);
  float* ans_wihT           = (float*)take((size_t)2256*768*4);
  float* ans_whhT           = (float*)take(256*768*4);
  unsigned short* gi_c_bf   = (unsigned short*)take((size_t)32768*768*2);  // lane-packed
  unsigned short* gi_q_bf   = (unsigned short*)take((size_t)1024*768*2);   // lane-packed
  float* c_out              = (float*)take((size_t)32*1024*256*4);
  float* q_hT               = (float*)take(32*256*4);
  float* c_sel              = (float*)take((size_t)4096*256*4);
  unsigned short* c_sel_bf  = (unsigned short*)take((size_t)4096*256*2);
  float* cw                 = (float*)take((size_t)4096*256*4);
  unsigned short* feats_bf  = (unsigned short*)take((size_t)4096*1824*2);
  float* h1                 = (float*)take((size_t)4096*128*4);
  float* scores             = (float*)take(4096*4);
  float* e_buf              = (float*)take(32*256*4);
  float* m_buf              = (float*)take(32*256*4);
  float* msq                = (float*)take(32*256*4);
  float* ylin               = (float*)take((size_t)32*2000*4);
  float* ybuf               = (float*)take((size_t)32*2000*4);

  // ---- prep / conversions ----
  k_f2bf<<<16384,256,0,stream>>>(c, c_bf, 32*1024*128);
  k_f2bf<<<512,256,0,stream>>>(q, q_bf, 32*32*128);
  k_f2bf<<<384,256,0,stream>>>(in_w_ih, wih_in_bf, 768*128);
  k_f2bf<<<384,256,0,stream>>>(qe_w_ih, wih_qe_bf, 768*128);
  k_f2bf<<<768,256,0,stream>>>(in_w_hh, whh_in_bf, 768*256);
  k_f2bf<<<768,256,0,stream>>>(qe_w_hh, whh_qe_bf, 768*256);
  k_attwT<<<256,256,0,stream>>>(att_weight, attwT_bf);
  k_attw1<<<912,256,0,stream>>>(att_w1, attw1_bf);
  k_b1pad<<<1,128,0,stream>>>(att_b1, b1pad);
  k_transpose<<<2000,256,0,stream>>>(out_w, out_wT, 2000, 256);
  k_transpose<<<768,256,0,stream>>>(mem_w_ih, mem_wihT, 768, 256);
  k_transpose<<<768,256,0,stream>>>(mem_w_hh, mem_whhT, 768, 256);
  k_transpose<<<6768,256,0,stream>>>(ans_w_ih, ans_wihT, 768, 2256);
  k_transpose<<<768,256,0,stream>>>(ans_w_hh, ans_whhT, 768, 256);

  // ---- time-parallel input projections with lane-packed scatter ----
  k_gemm_gi<<<dim3(512,12),256,0,stream>>>(c_bf, wih_in_bf, in_b_ih, gi_c_bf, 10);
  k_gemm_gi<<<dim3(16,12),256,0,stream>>>(q_bf, wih_qe_bf, qe_b_ih, gi_q_bf, 5);

  // ---- sequential GRU recurrences (context 1024 steps + query 32 steps) ----
  k_gru_rec<<<4,512,0,stream>>>(whh_in_bf, whh_qe_bf, gi_c_bf, gi_q_bf,
                                in_b_hh, qe_b_hh, i_state, q_state, c_out, q_hT);

  // ---- attention setup ----
  k_gather<<<4096,256,0,stream>>>(c_out, c_index, c_sel, c_sel_bf);
  k_gemm_bf16<<<dim3(64,4),256,0,stream>>>(c_sel_bf, attwT_bf, 256, nullptr, 0, cw, nullptr, 256);
  k_copy<<<32,256,0,stream>>>(q_hT, m_buf, 32*256);

  // ---- 3 episodic memory iterations ----
  for(int it=0; it<3; it++){
    k_feats<<<4096,256,0,stream>>>(c_sel, cw, m_buf, q_hT, feats_bf);
    k_gemm_bf16<<<dim3(64,2),256,0,stream>>>(feats_bf, attw1_bf, 1824, b1pad, 1, h1, nullptr, 128);
    k_scores<<<1024,256,0,stream>>>(h1, att_w2, att_b2, scores);
    k_softmax_e<<<32,256,0,stream>>>(scores, len_c, c_sel, outp + 64000 + it*4096, e_buf);
    k_gru_cell<<<32,256,0,stream>>>(e_buf, 256, nullptr, 0, m_buf,
                                    mem_wihT, mem_whhT, mem_b_ih, mem_b_hh, m_buf);
  }

  // ---- answer module ----
  k_copy<<<32,256,0,stream>>>(m_buf, msq, 32*256);
  for(int it=0; it<2; it++){
    k_logits<<<250,256,0,stream>>>(msq, out_wT, out_b, ylin);
    k_softmax_o<<<32,256,0,stream>>>(ylin, ybuf);
    k_gru_cell<<<32,256,0,stream>>>(ybuf, 2000, q_hT, 256, msq,
                                    ans_wihT, ans_whhT, ans_b_ih, ans_b_hh, msq);
  }
  k_logits<<<250,256,0,stream>>>(msq, out_wT, out_b, ylin);
  k_softmax_o<<<32,256,0,stream>>>(ylin, outp);
}

// Round 6
// 4572.364 us; speedup vs baseline: 1.0247x; 1.0247x over previous
//
#include <hip/hip_runtime.h>
#include <cstdint>
#include <cstddef>

typedef short bf16x8 __attribute__((ext_vector_type(8)));
typedef float f32x4 __attribute__((ext_vector_type(4)));
typedef int   i32x4 __attribute__((ext_vector_type(4)));

#define DEV static __device__ __forceinline__

DEV unsigned short f2bf(float x){
  union{float f; unsigned int u;} v; v.f = x;
  unsigned int r = (v.u + 0x7FFFu + ((v.u>>16)&1u)) >> 16;
  return (unsigned short)r;
}
DEV float bf2f(unsigned short h){
  union{unsigned int u; float f;} v; v.u = ((unsigned int)h)<<16;
  return v.f;
}
// unpack bf16 half of a dword: hi=0 -> low u16, hi=1 -> high u16
DEV float bfsel(int dw, int hi){
  union{unsigned int u; float f;} v;
  v.u = hi ? ((unsigned int)dw & 0xFFFF0000u) : ((unsigned int)dw << 16);
  return v.f;
}
// fast gates: v_exp_f32 + v_rcp_f32
DEV float sigm_f(float x){ return __builtin_amdgcn_rcpf(1.0f + __expf(-x)); }
DEV float tanh_f(float x){ return 2.0f*__builtin_amdgcn_rcpf(1.0f + __expf(-2.0f*x)) - 1.0f; }

// ---------------- prep kernels ----------------
__global__ void k_f2bf(const float* __restrict__ src, unsigned short* __restrict__ dst, int n){
  int i = blockIdx.x*256 + threadIdx.x;
  if(i<n) dst[i] = f2bf(src[i]);
}

__global__ void k_transpose(const float* __restrict__ in, float* __restrict__ out, int R, int C){
  int i = blockIdx.x*256 + threadIdx.x;
  if(i < R*C){ int r = i/C, c = i - r*C; out[(size_t)c*R + r] = in[i]; }
}

__global__ void k_attw1(const float* __restrict__ w1, unsigned short* __restrict__ dst){
  int i = blockIdx.x*256 + threadIdx.x;  // 128*1824
  if(i < 128*1824){
    int r = i/1824, cc = i - r*1824;
    float v = (r<100 && cc<1794)? w1[r*1794 + cc] : 0.0f;
    dst[i] = f2bf(v);
  }
}

__global__ void k_attwT(const float* __restrict__ aw, unsigned short* __restrict__ dst){
  int i = blockIdx.x*256 + threadIdx.x;  // out[n*256+k] = aw[k*256+n]
  if(i<65536){ int n = i>>8, k = i&255; dst[i] = f2bf(aw[k*256 + n]); }
}

__global__ void k_b1pad(const float* __restrict__ b1, float* __restrict__ dst){
  int i = threadIdx.x; if(i<128) dst[i] = (i<100)? b1[i] : 0.0f;
}

__global__ void k_copy(const float* __restrict__ s, float* __restrict__ d, int n){
  int i = blockIdx.x*256+threadIdx.x; if(i<n) d[i]=s[i];
}

// ---------------- generic bf16 MFMA GEMM: C(M,N) = A(M,K) @ Bt(N,K)^T ----------------
__global__ __launch_bounds__(256) void k_gemm_bf16(
    const unsigned short* __restrict__ A, const unsigned short* __restrict__ Bt,
    int K, const float* __restrict__ bias, int act,
    float* __restrict__ outf, unsigned short* __restrict__ outbf, int ldc)
{
  int lane = threadIdx.x & 63, wave = threadIdx.x >> 6;
  int m_base = blockIdx.x*64 + (wave>>1)*32;
  int n_base = blockIdx.y*64 + (wave&1)*32;
  int cl = lane & 15, q4 = lane >> 4;
  f32x4 acc00={0.f,0.f,0.f,0.f}, acc01=acc00, acc10=acc00, acc11=acc00;
  const int kf_n = K >> 5;
  for(int kf=0; kf<kf_n; kf++){
    int ko = kf*32 + q4*8;
    bf16x8 a0 = *(const bf16x8*)(A + (size_t)(m_base+cl)*K + ko);
    bf16x8 a1 = *(const bf16x8*)(A + (size_t)(m_base+16+cl)*K + ko);
    bf16x8 b0 = *(const bf16x8*)(Bt + (size_t)(n_base+cl)*K + ko);
    bf16x8 b1 = *(const bf16x8*)(Bt + (size_t)(n_base+16+cl)*K + ko);
    acc00 = __builtin_amdgcn_mfma_f32_16x16x32_bf16(a0,b0,acc00,0,0,0);
    acc01 = __builtin_amdgcn_mfma_f32_16x16x32_bf16(a0,b1,acc01,0,0,0);
    acc10 = __builtin_amdgcn_mfma_f32_16x16x32_bf16(a1,b0,acc10,0,0,0);
    acc11 = __builtin_amdgcn_mfma_f32_16x16x32_bf16(a1,b1,acc11,0,0,0);
  }
  #pragma unroll
  for(int mt=0; mt<2; mt++){
    #pragma unroll
    for(int nt=0; nt<2; nt++){
      f32x4 av = (mt==0)? (nt==0?acc00:acc01) : (nt==0?acc10:acc11);
      int col = n_base + nt*16 + cl;
      float bv = bias? bias[col] : 0.0f;
      #pragma unroll
      for(int r=0;r<4;r++){
        int row = m_base + mt*16 + q4*4 + r;
        float v = av[r] + bv;
        if(act) v = tanh_f(v);
        if(outbf) outbf[(size_t)row*ldc + col] = f2bf(v);
        else      outf [(size_t)row*ldc + col] = v;
      }
    }
  }
}

// ---------------- gi GEMM with lane-packed scatter epilogue ----------------
// Computes gi = x @ w_ih^T + b_ih and scatters each recurrence-lane's 24 values
// contiguous: idx = ((((t*2 + blk)*8 + w)*64 + lane)*24 + g*8 + s*4 + r.
// A rows are b*steps + t (steps = 1<<ss). N = 768.
__global__ __launch_bounds__(256) void k_gemm_gi(
    const unsigned short* __restrict__ A, const unsigned short* __restrict__ Bt,
    const float* __restrict__ bias, unsigned short* __restrict__ gi_out, int ss)
{
  int lane = threadIdx.x & 63, wave = threadIdx.x >> 6;
  int m_base = blockIdx.x*64 + (wave>>1)*32;
  int n_base = blockIdx.y*64 + (wave&1)*32;
  int cl = lane & 15, q4 = lane >> 4;
  f32x4 acc00={0.f,0.f,0.f,0.f}, acc01=acc00, acc10=acc00, acc11=acc00;
  for(int kf=0; kf<4; kf++){   // K = 128
    int ko = kf*32 + q4*8;
    bf16x8 a0 = *(const bf16x8*)(A + (size_t)(m_base+cl)*128 + ko);
    bf16x8 a1 = *(const bf16x8*)(A + (size_t)(m_base+16+cl)*128 + ko);
    bf16x8 b0 = *(const bf16x8*)(Bt + (size_t)(n_base+cl)*128 + ko);
    bf16x8 b1 = *(const bf16x8*)(Bt + (size_t)(n_base+16+cl)*128 + ko);
    acc00 = __builtin_amdgcn_mfma_f32_16x16x32_bf16(a0,b0,acc00,0,0,0);
    acc01 = __builtin_amdgcn_mfma_f32_16x16x32_bf16(a0,b1,acc01,0,0,0);
    acc10 = __builtin_amdgcn_mfma_f32_16x16x32_bf16(a1,b0,acc10,0,0,0);
    acc11 = __builtin_amdgcn_mfma_f32_16x16x32_bf16(a1,b1,acc11,0,0,0);
  }
  const int tmask = (1<<ss) - 1;
  #pragma unroll
  for(int mt=0; mt<2; mt++){
    #pragma unroll
    for(int nt=0; nt<2; nt++){
      f32x4 av = (mt==0)? (nt==0?acc00:acc01) : (nt==0?acc10:acc11);
      int col = n_base + nt*16 + cl;
      float bv = bias[col];
      int g = col >> 8, rem = col & 255;
      int w = rem >> 5, s = (rem>>4)&1, cl2 = rem & 15;
      #pragma unroll
      for(int r=0;r<4;r++){
        int arow = m_base + mt*16 + q4*4 + r;
        int t = arow & tmask, b = arow >> ss;
        int blk = b >> 4, brow = b & 15;
        int lane2 = (brow>>2)*16 + cl2, rc = brow & 3;
        size_t idx = ((((size_t)t*2 + blk)*8 + w)*64 + lane2)*24 + g*8 + s*4 + rc;
        gi_out[idx] = f2bf(av[r] + bv);
      }
    }
  }
}

// ---------------- GRU recurrence ----------------
// VERBATIM round-0 structure (best measured: 2026 us): 4 blocks (2 context,
// 2 query), 16 batch rows each, 8 waves, gate-local tiling, W register-
// resident, h double-buffered in LDS, ONE __syncthreads per step, gi loaded
// at step top, scalar c_out stores deferred to overlap the MFMA phase.
// ONLY delta vs round 0: b_hh folded into the MFMA accumulator INIT
// (exact: all 4 acc rows share one hidden column) -> removes 24 v_add from
// phase B. No memory op, ordering, or live-range change.
__global__ __launch_bounds__(512,1) void k_gru_rec(
    const unsigned short* __restrict__ whh_c, const unsigned short* __restrict__ whh_q,
    const unsigned short* __restrict__ gi_c,  const unsigned short* __restrict__ gi_q,
    const float* __restrict__ bhh_c, const float* __restrict__ bhh_q,
    const float* __restrict__ h0_c,  const float* __restrict__ h0_q,
    float* __restrict__ c_out, float* __restrict__ q_hT)
{
  __shared__ unsigned short hb0[16*264];   // double-buffered h (row stride 264 u16)
  __shared__ unsigned short hb1[16*264];

  const int blk = blockIdx.x;
  const bool isq = blk >= 2;
  const int cls = isq? blk-2 : blk;        // block index within class (0/1)
  const int b0 = cls * 16;
  const unsigned short* W  = isq? whh_q : whh_c;
  const unsigned short* GI = isq? gi_q  : gi_c;
  const float* bhh = isq? bhh_q : bhh_c;
  const float* h0  = isq? h0_q  : h0_c;
  const int steps  = isq? 32 : 1024;

  const int tid = threadIdx.x;
  const int lane = tid & 63, wave = tid >> 6;
  const int cl = lane & 15, q4 = lane >> 4;

  // B-fragments: [gate][subtile][kfrag], col = g*256 + wave*32 + s*16 + cl
  bf16x8 Bf[3][2][8];
  #pragma unroll
  for(int g=0; g<3; g++)
    #pragma unroll
    for(int s=0; s<2; s++){
      const unsigned short* wrow = W + (size_t)(g*256 + wave*32 + s*16 + cl)*256;
      #pragma unroll
      for(int kf=0; kf<8; kf++)
        Bf[g][s][kf] = *(const bf16x8*)(wrow + kf*32 + q4*8);
    }

  // per-lane biases for owned cols (consumed via accumulator init)
  float bR[2], bZ[2], bN[2];
  #pragma unroll
  for(int s=0; s<2; s++){
    const int col = wave*32 + s*16 + cl;
    bR[s] = bhh[col]; bZ[s] = bhh[256+col]; bN[s] = bhh[512+col];
  }

  // h in registers: lane owns (row=q4*4+r, col=wave*32+s*16+cl)
  float hreg[2][4];
  #pragma unroll
  for(int s=0; s<2; s++){
    const int col = wave*32 + s*16 + cl;
    #pragma unroll
    for(int r=0; r<4; r++){
      const int row = q4*4 + r;
      float v = h0[(size_t)(b0+row)*256 + col];
      hreg[s][r] = v;
      hb0[row*264 + col] = f2bf(v);
    }
  }
  __syncthreads();

  unsigned short* hb_rd = hb0;
  unsigned short* hb_wr = hb1;

  // per-lane gi base for this (blk, wave, lane)
  const unsigned short* gi_lane = GI + (((size_t)cls*8 + wave)*64 + lane)*24;
  const size_t gi_tstride = (size_t)2*8*64*24;   // per-t stride in u16

  for(int t=0; t<steps; t++){
    // gi(t): 3x dwordx4 (48 B contiguous per lane); consumed in phase B
    const unsigned short* gp = gi_lane + (size_t)t*gi_tstride;
    i32x4 G0 = *(const i32x4*)(gp);        // gate r : [s0r0..s0r3, s1r0..s1r3]
    i32x4 G1 = *(const i32x4*)(gp + 8);    // gate z
    i32x4 G2 = *(const i32x4*)(gp + 16);   // gate n

    // deferred c_out store of h(t-1): overlaps with MFMA phase
    if(!isq && t>0){
      #pragma unroll
      for(int s=0; s<2; s++){
        const int col = wave*32 + s*16 + cl;
        #pragma unroll
        for(int r=0; r<4; r++)
          c_out[((size_t)(b0+q4*4+r)*1024 + (t-1))*256 + col] = hreg[s][r];
      }
    }

    // phase A: gates = h @ W^T  (48 MFMAs/wave)
    // accumulator init = b_hh splat (exact: all 4 rows share one column)
    f32x4 acc[3][2];
    #pragma unroll
    for(int s=0; s<2; s++){
      acc[0][s] = (f32x4){bR[s],bR[s],bR[s],bR[s]};
      acc[1][s] = (f32x4){bZ[s],bZ[s],bZ[s],bZ[s]};
      acc[2][s] = (f32x4){bN[s],bN[s],bN[s],bN[s]};
    }
    #pragma unroll
    for(int kf=0; kf<8; kf++){
      bf16x8 a = *(const bf16x8*)&hb_rd[cl*264 + kf*32 + q4*8];
      #pragma unroll
      for(int g=0; g<3; g++)
        #pragma unroll
        for(int s=0; s<2; s++)
          acc[g][s] = __builtin_amdgcn_mfma_f32_16x16x32_bf16(a, Bf[g][s][kf], acc[g][s], 0,0,0);
    }

    // phase B: in-register GRU update (writes OTHER h buffer -> no barrier needed here)
    #pragma unroll
    for(int s=0; s<2; s++){
      const int col = wave*32 + s*16 + cl;
      #pragma unroll
      for(int r=0; r<4; r++){
        const int row = q4*4 + r;
        const int k = s*4 + r;
        float gir = bfsel(G0[k>>1], k&1);
        float giz = bfsel(G1[k>>1], k&1);
        float gin = bfsel(G2[k>>1], k&1);
        float rr = sigm_f(gir + acc[0][s][r]);
        float zz = sigm_f(giz + acc[1][s][r]);
        float nn = tanh_f(gin + rr*acc[2][s][r]);
        float x  = nn + zz*(hreg[s][r] - nn);
        hreg[s][r] = x;
        hb_wr[row*264 + col] = f2bf(x);
      }
    }
    __syncthreads();   // hb_wr complete -> next step's phase A may read it
    unsigned short* tmp = hb_rd; hb_rd = hb_wr; hb_wr = tmp;
  }

  // final stores from hreg
  #pragma unroll
  for(int s=0; s<2; s++){
    const int col = wave*32 + s*16 + cl;
    #pragma unroll
    for(int r=0; r<4; r++){
      const int row = q4*4 + r;
      if(!isq) c_out[((size_t)(b0+row)*1024 + (steps-1))*256 + col] = hreg[s][r];
      else     q_hT[(size_t)(b0+row)*256 + col] = hreg[s][r];
    }
  }
}

// ---------------- attention helpers ----------------
__global__ void k_gather(const float* __restrict__ c_out, const int* __restrict__ c_index,
                         float* __restrict__ c_sel, unsigned short* __restrict__ c_sel_bf){
  int row = blockIdx.x;                 // 0..4095 = b*128+s
  int b = row >> 7, s = row & 127;
  int idx = c_index[b*128 + s];
  float v = c_out[((size_t)b*1024 + idx)*256 + threadIdx.x];
  c_sel   [(size_t)row*256 + threadIdx.x] = v;
  c_sel_bf[(size_t)row*256 + threadIdx.x] = f2bf(v);
}

__global__ void k_feats(const float* __restrict__ c_sel, const float* __restrict__ cw,
                        const float* __restrict__ m_, const float* __restrict__ qh,
                        unsigned short* __restrict__ feats){
  int row = blockIdx.x, tid = threadIdx.x;
  int b = row >> 7;
  float cs  = c_sel[(size_t)row*256 + tid];
  float mj  = m_[b*256 + tid];
  float qj  = qh[b*256 + tid];
  float cwj = cw[(size_t)row*256 + tid];
  float dq = cwj*qj, dm = cwj*mj;
  #pragma unroll
  for(int o=32;o>0;o>>=1){ dq += __shfl_down(dq,o); dm += __shfl_down(dm,o); }
  __shared__ float rq[4], rm[4];
  int lane = tid&63, wave=tid>>6;
  if(lane==0){ rq[wave]=dq; rm[wave]=dm; }
  __syncthreads();
  unsigned short* fr = feats + (size_t)row*1824;
  fr[tid]      = f2bf(cs);
  fr[256+tid]  = f2bf(mj);
  fr[512+tid]  = f2bf(qj);
  fr[768+tid]  = f2bf(cs*qj);
  fr[1024+tid] = f2bf(cs*mj);
  fr[1280+tid] = f2bf(fabsf(cs-qj));
  fr[1536+tid] = f2bf(fabsf(cs-mj));
  if(tid==0){
    float DQ = rq[0]+rq[1]+rq[2]+rq[3];
    float DM = rm[0]+rm[1]+rm[2]+rm[3];
    fr[1792]=f2bf(DQ); fr[1793]=f2bf(DM);
  }
  if(tid<30) fr[1794+tid]=0;   // zero K-pad
}

__global__ void k_scores(const float* __restrict__ h1, const float* __restrict__ w2,
                         const float* __restrict__ b2, float* __restrict__ scores){
  int row = blockIdx.x*4 + (threadIdx.x>>6);
  int lane = threadIdx.x & 63;
  float v = 0.0f;
  if(lane < 100)    v += h1[(size_t)row*128 + lane]*w2[lane];
  if(lane+64 < 100) v += h1[(size_t)row*128 + lane+64]*w2[lane+64];
  #pragma unroll
  for(int o=32;o>0;o>>=1) v += __shfl_down(v,o);
  if(lane==0) scores[row] = v + b2[0];
}

__global__ void k_softmax_e(const float* __restrict__ scores, const int* __restrict__ len_c,
                            const float* __restrict__ c_sel, float* __restrict__ out_att,
                            float* __restrict__ e){
  __shared__ float red[256];
  __shared__ float p[128];
  int b = blockIdx.x, tid = threadIdx.x;
  int L = len_c[b];
  float s = -1e30f;
  if(tid<128 && tid<L) s = scores[b*128+tid];
  red[tid]=s; __syncthreads();
  for(int o=128;o>0;o>>=1){ if(tid<o) red[tid]=fmaxf(red[tid],red[tid+o]); __syncthreads(); }
  float mx = red[0]; __syncthreads();
  float ex = (tid<128 && tid<L)? __expf(s-mx) : 0.0f;
  red[tid]=ex; __syncthreads();
  for(int o=128;o>0;o>>=1){ if(tid<o) red[tid]+=red[tid+o]; __syncthreads(); }
  float inv = 1.0f/red[0];
  if(tid<128){ float pv = ex*inv; p[tid]=pv; out_att[b*128+tid]=pv; }
  __syncthreads();
  float acc = 0.0f;
  for(int si=0; si<128; si++) acc += p[si]*c_sel[((size_t)b*128+si)*256 + tid];
  e[b*256+tid] = acc;
}

// ---------------- small fp32 GRU cell (mem/ans updates), x = [x1 || x2] ----------------
__global__ void k_gru_cell(const float* __restrict__ x1, int len1,
                           const float* __restrict__ x2, int len2,
                           const float* __restrict__ hprev,
                           const float* __restrict__ wihT, const float* __restrict__ whhT,
                           const float* __restrict__ bih, const float* __restrict__ bhh,
                           float* __restrict__ hout){
  __shared__ float xs[2304];
  __shared__ float hs[256];
  int m = blockIdx.x, tid = threadIdx.x;
  int Kx = len1 + len2;
  for(int i=tid;i<len1;i+=256) xs[i] = x1[(size_t)m*len1 + i];
  for(int i=tid;i<len2;i+=256) xs[len1+i] = x2[(size_t)m*len2 + i];
  hs[tid] = hprev[m*256 + tid];
  __syncthreads();
  float ar=0, az=0, an=0;
  for(int k=0;k<Kx;k++){
    float xv = xs[k];
    const float* wr = wihT + (size_t)k*768;
    ar += xv*wr[tid]; az += xv*wr[256+tid]; an += xv*wr[512+tid];
  }
  float gr=0, gz=0, gn=0;
  for(int k=0;k<256;k++){
    float hv = hs[k];
    const float* wr = whhT + (size_t)k*768;
    gr += hv*wr[tid]; gz += hv*wr[256+tid]; gn += hv*wr[512+tid];
  }
  float rr = sigm_f(ar + bih[tid]     + gr + bhh[tid]);
  float zz = sigm_f(az + bih[256+tid] + gz + bhh[256+tid]);
  float nn = tanh_f(an + bih[512+tid] + rr*(gn + bhh[512+tid]));
  hout[m*256+tid] = (1.0f-zz)*nn + zz*hs[tid];
}

// ---------------- answer head ----------------
__global__ void k_logits(const float* __restrict__ msq, const float* __restrict__ out_wT,
                         const float* __restrict__ out_b, float* __restrict__ ylin){
  int i = blockIdx.x*256 + threadIdx.x;
  if(i >= 32*2000) return;
  int mrow = i/2000, n = i - mrow*2000;
  float acc = out_b[n];
  const float* mr = msq + mrow*256;
  for(int k=0;k<256;k++) acc += mr[k]*out_wT[(size_t)k*2000 + n];
  ylin[i] = acc;
}

__global__ void k_softmax_o(const float* __restrict__ x, float* __restrict__ y){
  __shared__ float red[256];
  int b = blockIdx.x, tid = threadIdx.x;
  const float* xr = x + (size_t)b*2000;
  float mx = -1e30f;
  for(int i=tid;i<2000;i+=256) mx = fmaxf(mx, xr[i]);
  red[tid]=mx; __syncthreads();
  for(int o=128;o>0;o>>=1){ if(tid<o) red[tid]=fmaxf(red[tid],red[tid+o]); __syncthreads(); }
  mx = red[0]; __syncthreads();
  float sum=0.0f;
  for(int i=tid;i<2000;i+=256) sum += __expf(xr[i]-mx);
  red[tid]=sum; __syncthreads();
  for(int o=128;o>0;o>>=1){ if(tid<o) red[tid]+=red[tid+o]; __syncthreads(); }
  float inv = 1.0f/red[0];
  for(int i=tid;i<2000;i+=256) y[(size_t)b*2000+i] = __expf(xr[i]-mx)*inv;
}

// ---------------- launch ----------------
extern "C" void kernel_launch(void* const* d_in, const int* in_sizes, int n_in,
                              void* d_out, int out_size, void* d_ws, size_t ws_size,
                              hipStream_t stream)
{
  const float* c        = (const float*)d_in[0];
  const float* q        = (const float*)d_in[1];
  const float* i_state  = (const float*)d_in[2];
  const float* q_state  = (const float*)d_in[3];
  const float* in_w_ih  = (const float*)d_in[4];
  const float* in_w_hh  = (const float*)d_in[5];
  const float* in_b_ih  = (const float*)d_in[6];
  const float* in_b_hh  = (const float*)d_in[7];
  const float* qe_w_ih  = (const float*)d_in[8];
  const float* qe_w_hh  = (const float*)d_in[9];
  const float* qe_b_ih  = (const float*)d_in[10];
  const float* qe_b_hh  = (const float*)d_in[11];
  const float* att_weight = (const float*)d_in[12];
  const float* att_w1   = (const float*)d_in[13];
  const float* att_b1   = (const float*)d_in[14];
  const float* att_w2   = (const float*)d_in[15];
  const float* att_b2   = (const float*)d_in[16];
  const float* mem_w_ih = (const float*)d_in[17];
  const float* mem_w_hh = (const float*)d_in[18];
  const float* mem_b_ih = (const float*)d_in[19];
  const float* mem_b_hh = (const float*)d_in[20];
  const float* out_w    = (const float*)d_in[21];
  const float* out_b    = (const float*)d_in[22];
  const float* ans_w_ih = (const float*)d_in[23];
  const float* ans_w_hh = (const float*)d_in[24];
  const float* ans_b_ih = (const float*)d_in[25];
  const float* ans_b_hh = (const float*)d_in[26];
  const int*   c_index  = (const int*)d_in[27];
  const int*   len_c    = (const int*)d_in[28];
  float* outp = (float*)d_out;   // [0,64000) y ; [64000,76288) att (3,32,128)

  char* wp = (char*)d_ws;
  auto take = [&](size_t nbytes)->char*{
    char* p = wp; wp += (nbytes + 255) & ~(size_t)255; return p;
  };
  unsigned short* c_bf      = (unsigned short*)take((size_t)32*1024*128*2);
  unsigned short* q_bf      = (unsigned short*)take((size_t)32*32*128*2);
  unsigned short* wih_in_bf = (unsigned short*)take(768*128*2);
  unsigned short* wih_qe_bf = (unsigned short*)take(768*128*2);
  unsigned short* whh_in_bf = (unsigned short*)take(768*256*2);
  unsigned short* whh_qe_bf = (unsigned short*)take(768*256*2);
  unsigned short* attwT_bf  = (unsigned short*)take(256*256*2);
  unsigned short* attw1_bf  = (unsigned short*)take(128*1824*2);
  float* b1pad              = (float*)take(128*4);
  float* out_wT             = (float*)take((size_t)256*2000*4);
  float* mem_wihT           = (float*)take(256*768*4);
  float* mem_whhT           = (float*)take(256*768*4);
  float* ans_wihT           = (float*)take((size_t)2256*768*4);
  float* ans_whhT           = (float*)take(256*768*4);
  unsigned short* gi_c_bf   = (unsigned short*)take((size_t)32768*768*2);  // lane-packed
  unsigned short* gi_q_bf   = (unsigned short*)take((size_t)1024*768*2);   // lane-packed
  float* c_out              = (float*)take((size_t)32*1024*256*4);
  float* q_hT               = (float*)take(32*256*4);
  float* c_sel              = (float*)take((size_t)4096*256*4);
  unsigned short* c_sel_bf  = (unsigned short*)take((size_t)4096*256*2);
  float* cw                 = (float*)take((size_t)4096*256*4);
  unsigned short* feats_bf  = (unsigned short*)take((size_t)4096*1824*2);
  float* h1                 = (float*)take((size_t)4096*128*4);
  float* scores             = (float*)take(4096*4);
  float* e_buf              = (float*)take(32*256*4);
  float* m_buf              = (float*)take(32*256*4);
  float* msq                = (float*)take(32*256*4);
  float* ylin               = (float*)take((size_t)32*2000*4);
  float* ybuf               = (float*)take((size_t)32*2000*4);

  // ---- prep / conversions ----
  k_f2bf<<<16384,256,0,stream>>>(c, c_bf, 32*1024*128);
  k_f2bf<<<512,256,0,stream>>>(q, q_bf, 32*32*128);
  k_f2bf<<<384,256,0,stream>>>(in_w_ih, wih_in_bf, 768*128);
  k_f2bf<<<384,256,0,stream>>>(qe_w_ih, wih_qe_bf, 768*128);
  k_f2bf<<<768,256,0,stream>>>(in_w_hh, whh_in_bf, 768*256);
  k_f2bf<<<768,256,0,stream>>>(qe_w_hh, whh_qe_bf, 768*256);
  k_attwT<<<256,256,0,stream>>>(att_weight, attwT_bf);
  k_attw1<<<912,256,0,stream>>>(att_w1, attw1_bf);
  k_b1pad<<<1,128,0,stream>>>(att_b1, b1pad);
  k_transpose<<<2000,256,0,stream>>>(out_w, out_wT, 2000, 256);
  k_transpose<<<768,256,0,stream>>>(mem_w_ih, mem_wihT, 768, 256);
  k_transpose<<<768,256,0,stream>>>(mem_w_hh, mem_whhT, 768, 256);
  k_transpose<<<6768,256,0,stream>>>(ans_w_ih, ans_wihT, 768, 2256);
  k_transpose<<<768,256,0,stream>>>(ans_w_hh, ans_whhT, 768, 256);

  // ---- time-parallel input projections with lane-packed scatter ----
  k_gemm_gi<<<dim3(512,12),256,0,stream>>>(c_bf, wih_in_bf, in_b_ih, gi_c_bf, 10);
  k_gemm_gi<<<dim3(16,12),256,0,stream>>>(q_bf, wih_qe_bf, qe_b_ih, gi_q_bf, 5);

  // ---- sequential GRU recurrences (context 1024 steps + query 32 steps) ----
  k_gru_rec<<<4,512,0,stream>>>(whh_in_bf, whh_qe_bf, gi_c_bf, gi_q_bf,
                                in_b_hh, qe_b_hh, i_state, q_state, c_out, q_hT);

  // ---- attention setup ----
  k_gather<<<4096,256,0,stream>>>(c_out, c_index, c_sel, c_sel_bf);
  k_gemm_bf16<<<dim3(64,4),256,0,stream>>>(c_sel_bf, attwT_bf, 256, nullptr, 0, cw, nullptr, 256);
  k_copy<<<32,256,0,stream>>>(q_hT, m_buf, 32*256);

  // ---- 3 episodic memory iterations ----
  for(int it=0; it<3; it++){
    k_feats<<<4096,256,0,stream>>>(c_sel, cw, m_buf, q_hT, feats_bf);
    k_gemm_bf16<<<dim3(64,2),256,0,stream>>>(feats_bf, attw1_bf, 1824, b1pad, 1, h1, nullptr, 128);
    k_scores<<<1024,256,0,stream>>>(h1, att_w2, att_b2, scores);
    k_softmax_e<<<32,256,0,stream>>>(scores, len_c, c_sel, outp + 64000 + it*4096, e_buf);
    k_gru_cell<<<32,256,0,stream>>>(e_buf, 256, nullptr, 0, m_buf,
                                    mem_wihT, mem_whhT, mem_b_ih, mem_b_hh, m_buf);
  }

  // ---- answer module ----
  k_copy<<<32,256,0,stream>>>(m_buf, msq, 32*256);
  for(int it=0; it<2; it++){
    k_logits<<<250,256,0,stream>>>(msq, out_wT, out_b, ylin);
    k_softmax_o<<<32,256,0,stream>>>(ylin, ybuf);
    k_gru_cell<<<32,256,0,stream>>>(ybuf, 2000, q_hT, 256, msq,
                                    ans_wihT, ans_whhT, ans_b_ih, ans_b_hh, msq);
  }
  k_logits<<<250,256,0,stream>>>(msq, out_wT, out_b, ylin);
  k_softmax_o<<<32,256,0,stream>>>(ylin, outp);
}

// Round 7
// 3063.734 us; speedup vs baseline: 1.5293x; 1.4924x over previous
//
#include <hip/hip_runtime.h>
#include <cstdint>
#include <cstddef>

typedef short bf16x8 __attribute__((ext_vector_type(8)));
typedef float f32x4 __attribute__((ext_vector_type(4)));
typedef int   i32x4 __attribute__((ext_vector_type(4)));

#define DEV static __device__ __forceinline__

DEV unsigned short f2bf(float x){
  union{float f; unsigned int u;} v; v.f = x;
  unsigned int r = (v.u + 0x7FFFu + ((v.u>>16)&1u)) >> 16;
  return (unsigned short)r;
}
DEV float bf2f(unsigned short h){
  union{unsigned int u; float f;} v; v.u = ((unsigned int)h)<<16;
  return v.f;
}
// unpack bf16 half of a dword: hi=0 -> low u16, hi=1 -> high u16
DEV float bfsel(int dw, int hi){
  union{unsigned int u; float f;} v;
  v.u = hi ? ((unsigned int)dw & 0xFFFF0000u) : ((unsigned int)dw << 16);
  return v.f;
}
// fast gates: v_exp_f32 + v_rcp_f32
DEV float sigm_f(float x){ return __builtin_amdgcn_rcpf(1.0f + __expf(-x)); }
DEV float tanh_f(float x){ return 2.0f*__builtin_amdgcn_rcpf(1.0f + __expf(-2.0f*x)) - 1.0f; }

// ---------------- prep kernels ----------------
__global__ void k_f2bf(const float* __restrict__ src, unsigned short* __restrict__ dst, int n){
  int i = blockIdx.x*256 + threadIdx.x;
  if(i<n) dst[i] = f2bf(src[i]);
}

__global__ void k_transpose(const float* __restrict__ in, float* __restrict__ out, int R, int C){
  int i = blockIdx.x*256 + threadIdx.x;
  if(i < R*C){ int r = i/C, c = i - r*C; out[(size_t)c*R + r] = in[i]; }
}

__global__ void k_attw1(const float* __restrict__ w1, unsigned short* __restrict__ dst){
  int i = blockIdx.x*256 + threadIdx.x;  // 128*1824
  if(i < 128*1824){
    int r = i/1824, cc = i - r*1824;
    float v = (r<100 && cc<1794)? w1[r*1794 + cc] : 0.0f;
    dst[i] = f2bf(v);
  }
}

__global__ void k_attwT(const float* __restrict__ aw, unsigned short* __restrict__ dst){
  int i = blockIdx.x*256 + threadIdx.x;  // out[n*256+k] = aw[k*256+n]
  if(i<65536){ int n = i>>8, k = i&255; dst[i] = f2bf(aw[k*256 + n]); }
}

__global__ void k_b1pad(const float* __restrict__ b1, float* __restrict__ dst){
  int i = threadIdx.x; if(i<128) dst[i] = (i<100)? b1[i] : 0.0f;
}

__global__ void k_copy(const float* __restrict__ s, float* __restrict__ d, int n){
  int i = blockIdx.x*256+threadIdx.x; if(i<n) d[i]=s[i];
}

// ---------------- generic bf16 MFMA GEMM: C(M,N) = A(M,K) @ Bt(N,K)^T ----------------
__global__ __launch_bounds__(256) void k_gemm_bf16(
    const unsigned short* __restrict__ A, const unsigned short* __restrict__ Bt,
    int K, const float* __restrict__ bias, int act,
    float* __restrict__ outf, unsigned short* __restrict__ outbf, int ldc)
{
  int lane = threadIdx.x & 63, wave = threadIdx.x >> 6;
  int m_base = blockIdx.x*64 + (wave>>1)*32;
  int n_base = blockIdx.y*64 + (wave&1)*32;
  int cl = lane & 15, q4 = lane >> 4;
  f32x4 acc00={0.f,0.f,0.f,0.f}, acc01=acc00, acc10=acc00, acc11=acc00;
  const int kf_n = K >> 5;
  for(int kf=0; kf<kf_n; kf++){
    int ko = kf*32 + q4*8;
    bf16x8 a0 = *(const bf16x8*)(A + (size_t)(m_base+cl)*K + ko);
    bf16x8 a1 = *(const bf16x8*)(A + (size_t)(m_base+16+cl)*K + ko);
    bf16x8 b0 = *(const bf16x8*)(Bt + (size_t)(n_base+cl)*K + ko);
    bf16x8 b1 = *(const bf16x8*)(Bt + (size_t)(n_base+16+cl)*K + ko);
    acc00 = __builtin_amdgcn_mfma_f32_16x16x32_bf16(a0,b0,acc00,0,0,0);
    acc01 = __builtin_amdgcn_mfma_f32_16x16x32_bf16(a0,b1,acc01,0,0,0);
    acc10 = __builtin_amdgcn_mfma_f32_16x16x32_bf16(a1,b0,acc10,0,0,0);
    acc11 = __builtin_amdgcn_mfma_f32_16x16x32_bf16(a1,b1,acc11,0,0,0);
  }
  #pragma unroll
  for(int mt=0; mt<2; mt++){
    #pragma unroll
    for(int nt=0; nt<2; nt++){
      f32x4 av = (mt==0)? (nt==0?acc00:acc01) : (nt==0?acc10:acc11);
      int col = n_base + nt*16 + cl;
      float bv = bias? bias[col] : 0.0f;
      #pragma unroll
      for(int r=0;r<4;r++){
        int row = m_base + mt*16 + q4*4 + r;
        float v = av[r] + bv;
        if(act) v = tanh_f(v);
        if(outbf) outbf[(size_t)row*ldc + col] = f2bf(v);
        else      outf [(size_t)row*ldc + col] = v;
      }
    }
  }
}

// ---------------- gi GEMM with lane-packed scatter epilogue ----------------
// Computes gi = x @ w_ih^T + b_ih and scatters each recurrence-lane's 24 values
// contiguous: idx = ((((t*2 + blk)*8 + w)*64 + lane)*24 + g*8 + s*4 + r.
// A rows are b*steps + t (steps = 1<<ss). N = 768.
__global__ __launch_bounds__(256) void k_gemm_gi(
    const unsigned short* __restrict__ A, const unsigned short* __restrict__ Bt,
    const float* __restrict__ bias, unsigned short* __restrict__ gi_out, int ss)
{
  int lane = threadIdx.x & 63, wave = threadIdx.x >> 6;
  int m_base = blockIdx.x*64 + (wave>>1)*32;
  int n_base = blockIdx.y*64 + (wave&1)*32;
  int cl = lane & 15, q4 = lane >> 4;
  f32x4 acc00={0.f,0.f,0.f,0.f}, acc01=acc00, acc10=acc00, acc11=acc00;
  for(int kf=0; kf<4; kf++){   // K = 128
    int ko = kf*32 + q4*8;
    bf16x8 a0 = *(const bf16x8*)(A + (size_t)(m_base+cl)*128 + ko);
    bf16x8 a1 = *(const bf16x8*)(A + (size_t)(m_base+16+cl)*128 + ko);
    bf16x8 b0 = *(const bf16x8*)(Bt + (size_t)(n_base+cl)*128 + ko);
    bf16x8 b1 = *(const bf16x8*)(Bt + (size_t)(n_base+16+cl)*128 + ko);
    acc00 = __builtin_amdgcn_mfma_f32_16x16x32_bf16(a0,b0,acc00,0,0,0);
    acc01 = __builtin_amdgcn_mfma_f32_16x16x32_bf16(a0,b1,acc01,0,0,0);
    acc10 = __builtin_amdgcn_mfma_f32_16x16x32_bf16(a1,b0,acc10,0,0,0);
    acc11 = __builtin_amdgcn_mfma_f32_16x16x32_bf16(a1,b1,acc11,0,0,0);
  }
  const int tmask = (1<<ss) - 1;
  #pragma unroll
  for(int mt=0; mt<2; mt++){
    #pragma unroll
    for(int nt=0; nt<2; nt++){
      f32x4 av = (mt==0)? (nt==0?acc00:acc01) : (nt==0?acc10:acc11);
      int col = n_base + nt*16 + cl;
      float bv = bias[col];
      int g = col >> 8, rem = col & 255;
      int w = rem >> 5, s = (rem>>4)&1, cl2 = rem & 15;
      #pragma unroll
      for(int r=0;r<4;r++){
        int arow = m_base + mt*16 + q4*4 + r;
        int t = arow & tmask, b = arow >> ss;
        int blk = b >> 4, brow = b & 15;
        int lane2 = (brow>>2)*16 + cl2, rc = brow & 3;
        size_t idx = ((((size_t)t*2 + blk)*8 + w)*64 + lane2)*24 + g*8 + s*4 + rc;
        gi_out[idx] = f2bf(av[r] + bv);
      }
    }
  }
}

// ---------------- GRU recurrence ----------------
// 4 blocks (2 context, 2 query), 16 batch rows each, 8 waves.
// Gate-local tiling (wave w owns cols [32w,32w+32) of r/z/n); W register-resident.
// h double-buffered in LDS -> ONE __syncthreads per step.
// gi loaded per-lane as 3x dwordx4 from the lane-packed layout (issued at step top,
// consumed in phase B via data-dependent vmcnt; no barrier interaction).
__global__ __launch_bounds__(512,1) void k_gru_rec(
    const unsigned short* __restrict__ whh_c, const unsigned short* __restrict__ whh_q,
    const unsigned short* __restrict__ gi_c,  const unsigned short* __restrict__ gi_q,
    const float* __restrict__ bhh_c, const float* __restrict__ bhh_q,
    const float* __restrict__ h0_c,  const float* __restrict__ h0_q,
    float* __restrict__ c_out, float* __restrict__ q_hT)
{
  __shared__ unsigned short hb0[16*264];   // double-buffered h (row stride 264 u16)
  __shared__ unsigned short hb1[16*264];

  const int blk = blockIdx.x;
  const bool isq = blk >= 2;
  const int cls = isq? blk-2 : blk;        // block index within class (0/1)
  const int b0 = cls * 16;
  const unsigned short* W  = isq? whh_q : whh_c;
  const unsigned short* GI = isq? gi_q  : gi_c;
  const float* bhh = isq? bhh_q : bhh_c;
  const float* h0  = isq? h0_q  : h0_c;
  const int steps  = isq? 32 : 1024;

  const int tid = threadIdx.x;
  const int lane = tid & 63, wave = tid >> 6;
  const int cl = lane & 15, q4 = lane >> 4;

  // B-fragments: [gate][subtile][kfrag], col = g*256 + wave*32 + s*16 + cl
  bf16x8 Bf[3][2][8];
  #pragma unroll
  for(int g=0; g<3; g++)
    #pragma unroll
    for(int s=0; s<2; s++){
      const unsigned short* wrow = W + (size_t)(g*256 + wave*32 + s*16 + cl)*256;
      #pragma unroll
      for(int kf=0; kf<8; kf++)
        Bf[g][s][kf] = *(const bf16x8*)(wrow + kf*32 + q4*8);
    }

  // per-lane biases for owned cols
  float bR[2], bZ[2], bN[2];
  #pragma unroll
  for(int s=0; s<2; s++){
    const int col = wave*32 + s*16 + cl;
    bR[s] = bhh[col]; bZ[s] = bhh[256+col]; bN[s] = bhh[512+col];
  }

  // h in registers: lane owns (row=q4*4+r, col=wave*32+s*16+cl)
  float hreg[2][4];
  #pragma unroll
  for(int s=0; s<2; s++){
    const int col = wave*32 + s*16 + cl;
    #pragma unroll
    for(int r=0; r<4; r++){
      const int row = q4*4 + r;
      float v = h0[(size_t)(b0+row)*256 + col];
      hreg[s][r] = v;
      hb0[row*264 + col] = f2bf(v);
    }
  }
  __syncthreads();

  unsigned short* hb_rd = hb0;
  unsigned short* hb_wr = hb1;

  // per-lane gi base for this (blk, wave, lane)
  const unsigned short* gi_lane = GI + (((size_t)cls*8 + wave)*64 + lane)*24;
  const size_t gi_tstride = (size_t)2*8*64*24;   // per-t stride in u16

  for(int t=0; t<steps; t++){
    // gi(t): 3x dwordx4 (48 B contiguous per lane); consumed in phase B
    const unsigned short* gp = gi_lane + (size_t)t*gi_tstride;
    i32x4 G0 = *(const i32x4*)(gp);        // gate r : [s0r0..s0r3, s1r0..s1r3]
    i32x4 G1 = *(const i32x4*)(gp + 8);    // gate z
    i32x4 G2 = *(const i32x4*)(gp + 16);   // gate n

    // deferred c_out store of h(t-1): overlaps with MFMA phase
    if(!isq && t>0){
      #pragma unroll
      for(int s=0; s<2; s++){
        const int col = wave*32 + s*16 + cl;
        #pragma unroll
        for(int r=0; r<4; r++)
          c_out[((size_t)(b0+q4*4+r)*1024 + (t-1))*256 + col] = hreg[s][r];
      }
    }

    // phase A: gates = h @ W^T  (48 MFMAs/wave)
    f32x4 acc[3][2];
    #pragma unroll
    for(int g=0; g<3; g++)
      #pragma unroll
      for(int s=0; s<2; s++){ f32x4 z={0.f,0.f,0.f,0.f}; acc[g][s]=z; }
    #pragma unroll
    for(int kf=0; kf<8; kf++){
      bf16x8 a = *(const bf16x8*)&hb_rd[cl*264 + kf*32 + q4*8];
      #pragma unroll
      for(int g=0; g<3; g++)
        #pragma unroll
        for(int s=0; s<2; s++)
          acc[g][s] = __builtin_amdgcn_mfma_f32_16x16x32_bf16(a, Bf[g][s][kf], acc[g][s], 0,0,0);
    }

    // phase B: in-register GRU update (writes OTHER h buffer -> no barrier needed here)
    #pragma unroll
    for(int s=0; s<2; s++){
      const int col = wave*32 + s*16 + cl;
      #pragma unroll
      for(int r=0; r<4; r++){
        const int row = q4*4 + r;
        const int k = s*4 + r;
        float gir = bfsel(G0[k>>1], k&1);
        float giz = bfsel(G1[k>>1], k&1);
        float gin = bfsel(G2[k>>1], k&1);
        float rr = sigm_f(gir + acc[0][s][r] + bR[s]);
        float zz = sigm_f(giz + acc[1][s][r] + bZ[s]);
        float nn = tanh_f(gin + rr*(acc[2][s][r] + bN[s]));
        float x  = nn + zz*(hreg[s][r] - nn);
        hreg[s][r] = x;
        hb_wr[row*264 + col] = f2bf(x);
      }
    }
    __syncthreads();   // hb_wr complete -> next step's phase A may read it
    unsigned short* tmp = hb_rd; hb_rd = hb_wr; hb_wr = tmp;
  }

  // final stores from hreg
  #pragma unroll
  for(int s=0; s<2; s++){
    const int col = wave*32 + s*16 + cl;
    #pragma unroll
    for(int r=0; r<4; r++){
      const int row = q4*4 + r;
      if(!isq) c_out[((size_t)(b0+row)*1024 + (steps-1))*256 + col] = hreg[s][r];
      else     q_hT[(size_t)(b0+row)*256 + col] = hreg[s][r];
    }
  }
}

// ---------------- attention helpers ----------------
__global__ void k_gather(const float* __restrict__ c_out, const int* __restrict__ c_index,
                         float* __restrict__ c_sel, unsigned short* __restrict__ c_sel_bf){
  int row = blockIdx.x;                 // 0..4095 = b*128+s
  int b = row >> 7, s = row & 127;
  int idx = c_index[b*128 + s];
  float v = c_out[((size_t)b*1024 + idx)*256 + threadIdx.x];
  c_sel   [(size_t)row*256 + threadIdx.x] = v;
  c_sel_bf[(size_t)row*256 + threadIdx.x] = f2bf(v);
}

__global__ void k_feats(const float* __restrict__ c_sel, const float* __restrict__ cw,
                        const float* __restrict__ m_, const float* __restrict__ qh,
                        unsigned short* __restrict__ feats){
  int row = blockIdx.x, tid = threadIdx.x;
  int b = row >> 7;
  float cs  = c_sel[(size_t)row*256 + tid];
  float mj  = m_[b*256 + tid];
  float qj  = qh[b*256 + tid];
  float cwj = cw[(size_t)row*256 + tid];
  float dq = cwj*qj, dm = cwj*mj;
  #pragma unroll
  for(int o=32;o>0;o>>=1){ dq += __shfl_down(dq,o); dm += __shfl_down(dm,o); }
  __shared__ float rq[4], rm[4];
  int lane = tid&63, wave=tid>>6;
  if(lane==0){ rq[wave]=dq; rm[wave]=dm; }
  __syncthreads();
  unsigned short* fr = feats + (size_t)row*1824;
  fr[tid]      = f2bf(cs);
  fr[256+tid]  = f2bf(mj);
  fr[512+tid]  = f2bf(qj);
  fr[768+tid]  = f2bf(cs*qj);
  fr[1024+tid] = f2bf(cs*mj);
  fr[1280+tid] = f2bf(fabsf(cs-qj));
  fr[1536+tid] = f2bf(fabsf(cs-mj));
  if(tid==0){
    float DQ = rq[0]+rq[1]+rq[2]+rq[3];
    float DM = rm[0]+rm[1]+rm[2]+rm[3];
    fr[1792]=f2bf(DQ); fr[1793]=f2bf(DM);
  }
  if(tid<30) fr[1794+tid]=0;   // zero K-pad
}

__global__ void k_scores(const float* __restrict__ h1, const float* __restrict__ w2,
                         const float* __restrict__ b2, float* __restrict__ scores){
  int row = blockIdx.x*4 + (threadIdx.x>>6);
  int lane = threadIdx.x & 63;
  float v = 0.0f;
  if(lane < 100)    v += h1[(size_t)row*128 + lane]*w2[lane];
  if(lane+64 < 100) v += h1[(size_t)row*128 + lane+64]*w2[lane+64];
  #pragma unroll
  for(int o=32;o>0;o>>=1) v += __shfl_down(v,o);
  if(lane==0) scores[row] = v + b2[0];
}

__global__ void k_softmax_e(const float* __restrict__ scores, const int* __restrict__ len_c,
                            const float* __restrict__ c_sel, float* __restrict__ out_att,
                            float* __restrict__ e){
  __shared__ float red[256];
  __shared__ float p[128];
  int b = blockIdx.x, tid = threadIdx.x;
  int L = len_c[b];
  float s = -1e30f;
  if(tid<128 && tid<L) s = scores[b*128+tid];
  red[tid]=s; __syncthreads();
  for(int o=128;o>0;o>>=1){ if(tid<o) red[tid]=fmaxf(red[tid],red[tid+o]); __syncthreads(); }
  float mx = red[0]; __syncthreads();
  float ex = (tid<128 && tid<L)? __expf(s-mx) : 0.0f;
  red[tid]=ex; __syncthreads();
  for(int o=128;o>0;o>>=1){ if(tid<o) red[tid]+=red[tid+o]; __syncthreads(); }
  float inv = 1.0f/red[0];
  if(tid<128){ float pv = ex*inv; p[tid]=pv; out_att[b*128+tid]=pv; }
  __syncthreads();
  float acc = 0.0f;
  for(int si=0; si<128; si++) acc += p[si]*c_sel[((size_t)b*128+si)*256 + tid];
  e[b*256+tid] = acc;
}

// ---------------- small fp32 GRU cell (mem/ans updates), x = [x1 || x2] ----------------
__global__ void k_gru_cell(const float* __restrict__ x1, int len1,
                           const float* __restrict__ x2, int len2,
                           const float* __restrict__ hprev,
                           const float* __restrict__ wihT, const float* __restrict__ whhT,
                           const float* __restrict__ bih, const float* __restrict__ bhh,
                           float* __restrict__ hout){
  __shared__ float xs[2304];
  __shared__ float hs[256];
  int m = blockIdx.x, tid = threadIdx.x;
  int Kx = len1 + len2;
  for(int i=tid;i<len1;i+=256) xs[i] = x1[(size_t)m*len1 + i];
  for(int i=tid;i<len2;i+=256) xs[len1+i] = x2[(size_t)m*len2 + i];
  hs[tid] = hprev[m*256 + tid];
  __syncthreads();
  float ar=0, az=0, an=0;
  for(int k=0;k<Kx;k++){
    float xv = xs[k];
    const float* wr = wihT + (size_t)k*768;
    ar += xv*wr[tid]; az += xv*wr[256+tid]; an += xv*wr[512+tid];
  }
  float gr=0, gz=0, gn=0;
  for(int k=0;k<256;k++){
    float hv = hs[k];
    const float* wr = whhT + (size_t)k*768;
    gr += hv*wr[tid]; gz += hv*wr[256+tid]; gn += hv*wr[512+tid];
  }
  float rr = sigm_f(ar + bih[tid]     + gr + bhh[tid]);
  float zz = sigm_f(az + bih[256+tid] + gz + bhh[256+tid]);
  float nn = tanh_f(an + bih[512+tid] + rr*(gn + bhh[512+tid]));
  hout[m*256+tid] = (1.0f-zz)*nn + zz*hs[tid];
}

// ---------------- answer head ----------------
__global__ void k_logits(const float* __restrict__ msq, const float* __restrict__ out_wT,
                         const float* __restrict__ out_b, float* __restrict__ ylin){
  int i = blockIdx.x*256 + threadIdx.x;
  if(i >= 32*2000) return;
  int mrow = i/2000, n = i - mrow*2000;
  float acc = out_b[n];
  const float* mr = msq + mrow*256;
  for(int k=0;k<256;k++) acc += mr[k]*out_wT[(size_t)k*2000 + n];
  ylin[i] = acc;
}

__global__ void k_softmax_o(const float* __restrict__ x, float* __restrict__ y){
  __shared__ float red[256];
  int b = blockIdx.x, tid = threadIdx.x;
  const float* xr = x + (size_t)b*2000;
  float mx = -1e30f;
  for(int i=tid;i<2000;i+=256) mx = fmaxf(mx, xr[i]);
  red[tid]=mx; __syncthreads();
  for(int o=128;o>0;o>>=1){ if(tid<o) red[tid]=fmaxf(red[tid],red[tid+o]); __syncthreads(); }
  mx = red[0]; __syncthreads();
  float sum=0.0f;
  for(int i=tid;i<2000;i+=256) sum += __expf(xr[i]-mx);
  red[tid]=sum; __syncthreads();
  for(int o=128;o>0;o>>=1){ if(tid<o) red[tid]+=red[tid+o]; __syncthreads(); }
  float inv = 1.0f/red[0];
  for(int i=tid;i<2000;i+=256) y[(size_t)b*2000+i] = __expf(xr[i]-mx)*inv;
}

// ---------------- launch ----------------
extern "C" void kernel_launch(void* const* d_in, const int* in_sizes, int n_in,
                              void* d_out, int out_size, void* d_ws, size_t ws_size,
                              hipStream_t stream)
{
  const float* c        = (const float*)d_in[0];
  const float* q        = (const float*)d_in[1];
  const float* i_state  = (const float*)d_in[2];
  const float* q_state  = (const float*)d_in[3];
  const float* in_w_ih  = (const float*)d_in[4];
  const float* in_w_hh  = (const float*)d_in[5];
  const float* in_b_ih  = (const float*)d_in[6];
  const float* in_b_hh  = (const float*)d_in[7];
  const float* qe_w_ih  = (const float*)d_in[8];
  const float* qe_w_hh  = (const float*)d_in[9];
  const float* qe_b_ih  = (const float*)d_in[10];
  const float* qe_b_hh  = (const float*)d_in[11];
  const float* att_weight = (const float*)d_in[12];
  const float* att_w1   = (const float*)d_in[13];
  const float* att_b1   = (const float*)d_in[14];
  const float* att_w2   = (const float*)d_in[15];
  const float* att_b2   = (const float*)d_in[16];
  const float* mem_w_ih = (const float*)d_in[17];
  const float* mem_w_hh = (const float*)d_in[18];
  const float* mem_b_ih = (const float*)d_in[19];
  const float* mem_b_hh = (const float*)d_in[20];
  const float* out_w    = (const float*)d_in[21];
  const float* out_b    = (const float*)d_in[22];
  const float* ans_w_ih = (const float*)d_in[23];
  const float* ans_w_hh = (const float*)d_in[24];
  const float* ans_b_ih = (const float*)d_in[25];
  const float* ans_b_hh = (const float*)d_in[26];
  const int*   c_index  = (const int*)d_in[27];
  const int*   len_c    = (const int*)d_in[28];
  float* outp = (float*)d_out;   // [0,64000) y ; [64000,76288) att (3,32,128)

  char* wp = (char*)d_ws;
  auto take = [&](size_t nbytes)->char*{
    char* p = wp; wp += (nbytes + 255) & ~(size_t)255; return p;
  };
  unsigned short* c_bf      = (unsigned short*)take((size_t)32*1024*128*2);
  unsigned short* q_bf      = (unsigned short*)take((size_t)32*32*128*2);
  unsigned short* wih_in_bf = (unsigned short*)take(768*128*2);
  unsigned short* wih_qe_bf = (unsigned short*)take(768*128*2);
  unsigned short* whh_in_bf = (unsigned short*)take(768*256*2);
  unsigned short* whh_qe_bf = (unsigned short*)take(768*256*2);
  unsigned short* attwT_bf  = (unsigned short*)take(256*256*2);
  unsigned short* attw1_bf  = (unsigned short*)take(128*1824*2);
  float* b1pad              = (float*)take(128*4);
  float* out_wT             = (float*)take((size_t)256*2000*4);
  float* mem_wihT           = (float*)take(256*768*4);
  float* mem_whhT           = (float*)take(256*768*4);
  float* ans_wihT           = (float*)take((size_t)2256*768*4);
  float* ans_whhT           = (float*)take(256*768*4);
  unsigned short* gi_c_bf   = (unsigned short*)take((size_t)32768*768*2);  // lane-packed
  unsigned short* gi_q_bf   = (unsigned short*)take((size_t)1024*768*2);   // lane-packed
  float* c_out              = (float*)take((size_t)32*1024*256*4);
  float* q_hT               = (float*)take(32*256*4);
  float* c_sel              = (float*)take((size_t)4096*256*4);
  unsigned short* c_sel_bf  = (unsigned short*)take((size_t)4096*256*2);
  float* cw                 = (float*)take((size_t)4096*256*4);
  unsigned short* feats_bf  = (unsigned short*)take((size_t)4096*1824*2);
  float* h1                 = (float*)take((size_t)4096*128*4);
  float* scores             = (float*)take(4096*4);
  float* e_buf              = (float*)take(32*256*4);
  float* m_buf              = (float*)take(32*256*4);
  float* msq                = (float*)take(32*256*4);
  float* ylin               = (float*)take((size_t)32*2000*4);
  float* ybuf               = (float*)take((size_t)32*2000*4);

  // ---- prep / conversions ----
  k_f2bf<<<16384,256,0,stream>>>(c, c_bf, 32*1024*128);
  k_f2bf<<<512,256,0,stream>>>(q, q_bf, 32*32*128);
  k_f2bf<<<384,256,0,stream>>>(in_w_ih, wih_in_bf, 768*128);
  k_f2bf<<<384,256,0,stream>>>(qe_w_ih, wih_qe_bf, 768*128);
  k_f2bf<<<768,256,0,stream>>>(in_w_hh, whh_in_bf, 768*256);
  k_f2bf<<<768,256,0,stream>>>(qe_w_hh, whh_qe_bf, 768*256);
  k_attwT<<<256,256,0,stream>>>(att_weight, attwT_bf);
  k_attw1<<<912,256,0,stream>>>(att_w1, attw1_bf);
  k_b1pad<<<1,128,0,stream>>>(att_b1, b1pad);
  k_transpose<<<2000,256,0,stream>>>(out_w, out_wT, 2000, 256);
  k_transpose<<<768,256,0,stream>>>(mem_w_ih, mem_wihT, 768, 256);
  k_transpose<<<768,256,0,stream>>>(mem_w_hh, mem_whhT, 768, 256);
  k_transpose<<<6768,256,0,stream>>>(ans_w_ih, ans_wihT, 768, 2256);
  k_transpose<<<768,256,0,stream>>>(ans_w_hh, ans_whhT, 768, 256);

  // ---- time-parallel input projections with lane-packed scatter ----
  k_gemm_gi<<<dim3(512,12),256,0,stream>>>(c_bf, wih_in_bf, in_b_ih, gi_c_bf, 10);
  k_gemm_gi<<<dim3(16,12),256,0,stream>>>(q_bf, wih_qe_bf, qe_b_ih, gi_q_bf, 5);

  // ---- sequential GRU recurrences (context 1024 steps + query 32 steps) ----
  k_gru_rec<<<4,512,0,stream>>>(whh_in_bf, whh_qe_bf, gi_c_bf, gi_q_bf,
                                in_b_hh, qe_b_hh, i_state, q_state, c_out, q_hT);

  // ---- attention setup ----
  k_gather<<<4096,256,0,stream>>>(c_out, c_index, c_sel, c_sel_bf);
  k_gemm_bf16<<<dim3(64,4),256,0,stream>>>(c_sel_bf, attwT_bf, 256, nullptr, 0, cw, nullptr, 256);
  k_copy<<<32,256,0,stream>>>(q_hT, m_buf, 32*256);

  // ---- 3 episodic memory iterations ----
  for(int it=0; it<3; it++){
    k_feats<<<4096,256,0,stream>>>(c_sel, cw, m_buf, q_hT, feats_bf);
    k_gemm_bf16<<<dim3(64,2),256,0,stream>>>(feats_bf, attw1_bf, 1824, b1pad, 1, h1, nullptr, 128);
    k_scores<<<1024,256,0,stream>>>(h1, att_w2, att_b2, scores);
    k_softmax_e<<<32,256,0,stream>>>(scores, len_c, c_sel, outp + 64000 + it*4096, e_buf);
    k_gru_cell<<<32,256,0,stream>>>(e_buf, 256, nullptr, 0, m_buf,
                                    mem_wihT, mem_whhT, mem_b_ih, mem_b_hh, m_buf);
  }

  // ---- answer module ----
  k_copy<<<32,256,0,stream>>>(m_buf, msq, 32*256);
  for(int it=0; it<2; it++){
    k_logits<<<250,256,0,stream>>>(msq, out_wT, out_b, ylin);
    k_softmax_o<<<32,256,0,stream>>>(ylin, ybuf);
    k_gru_cell<<<32,256,0,stream>>>(ybuf, 2000, q_hT, 256, msq,
                                    ans_wihT, ans_whhT, ans_b_ih, ans_b_hh, msq);
  }
  k_logits<<<250,256,0,stream>>>(msq, out_wT, out_b, ylin);
  k_softmax_o<<<32,256,0,stream>>>(ylin, outp);
}

// Round 8
// 2957.258 us; speedup vs baseline: 1.5844x; 1.0360x over previous
//
#include <hip/hip_runtime.h>
#include <cstdint>
#include <cstddef>

typedef short bf16x8 __attribute__((ext_vector_type(8)));
typedef float f32x4 __attribute__((ext_vector_type(4)));
typedef int   i32x4 __attribute__((ext_vector_type(4)));

#define DEV static __device__ __forceinline__

DEV unsigned short f2bf(float x){
  union{float f; unsigned int u;} v; v.f = x;
  unsigned int r = (v.u + 0x7FFFu + ((v.u>>16)&1u)) >> 16;
  return (unsigned short)r;
}
DEV float bf2f(unsigned short h){
  union{unsigned int u; float f;} v; v.u = ((unsigned int)h)<<16;
  return v.f;
}
// unpack bf16 half of a dword: hi=0 -> low u16, hi=1 -> high u16
DEV float bfsel(int dw, int hi){
  union{unsigned int u; float f;} v;
  v.u = hi ? ((unsigned int)dw & 0xFFFF0000u) : ((unsigned int)dw << 16);
  return v.f;
}
// fast gates: v_exp_f32 + v_rcp_f32
DEV float sigm_f(float x){ return __builtin_amdgcn_rcpf(1.0f + __expf(-x)); }
DEV float tanh_f(float x){ return 2.0f*__builtin_amdgcn_rcpf(1.0f + __expf(-2.0f*x)) - 1.0f; }

// ---------------- prep kernels ----------------
__global__ void k_f2bf(const float* __restrict__ src, unsigned short* __restrict__ dst, int n){
  int i = blockIdx.x*256 + threadIdx.x;
  if(i<n) dst[i] = f2bf(src[i]);
}

__global__ void k_transpose(const float* __restrict__ in, float* __restrict__ out, int R, int C){
  int i = blockIdx.x*256 + threadIdx.x;
  if(i < R*C){ int r = i/C, c = i - r*C; out[(size_t)c*R + r] = in[i]; }
}

__global__ void k_attw1(const float* __restrict__ w1, unsigned short* __restrict__ dst){
  int i = blockIdx.x*256 + threadIdx.x;  // 128*1824
  if(i < 128*1824){
    int r = i/1824, cc = i - r*1824;
    float v = (r<100 && cc<1794)? w1[r*1794 + cc] : 0.0f;
    dst[i] = f2bf(v);
  }
}

__global__ void k_attwT(const float* __restrict__ aw, unsigned short* __restrict__ dst){
  int i = blockIdx.x*256 + threadIdx.x;  // out[n*256+k] = aw[k*256+n]
  if(i<65536){ int n = i>>8, k = i&255; dst[i] = f2bf(aw[k*256 + n]); }
}

__global__ void k_b1pad(const float* __restrict__ b1, float* __restrict__ dst){
  int i = threadIdx.x; if(i<128) dst[i] = (i<100)? b1[i] : 0.0f;
}

// ---------------- generic bf16 MFMA GEMM: C(M,N) = A(M,K) @ Bt(N,K)^T ----------------
__global__ __launch_bounds__(256) void k_gemm_bf16(
    const unsigned short* __restrict__ A, const unsigned short* __restrict__ Bt,
    int K, const float* __restrict__ bias, int act,
    float* __restrict__ outf, unsigned short* __restrict__ outbf, int ldc)
{
  int lane = threadIdx.x & 63, wave = threadIdx.x >> 6;
  int m_base = blockIdx.x*64 + (wave>>1)*32;
  int n_base = blockIdx.y*64 + (wave&1)*32;
  int cl = lane & 15, q4 = lane >> 4;
  f32x4 acc00={0.f,0.f,0.f,0.f}, acc01=acc00, acc10=acc00, acc11=acc00;
  const int kf_n = K >> 5;
  for(int kf=0; kf<kf_n; kf++){
    int ko = kf*32 + q4*8;
    bf16x8 a0 = *(const bf16x8*)(A + (size_t)(m_base+cl)*K + ko);
    bf16x8 a1 = *(const bf16x8*)(A + (size_t)(m_base+16+cl)*K + ko);
    bf16x8 b0 = *(const bf16x8*)(Bt + (size_t)(n_base+cl)*K + ko);
    bf16x8 b1 = *(const bf16x8*)(Bt + (size_t)(n_base+16+cl)*K + ko);
    acc00 = __builtin_amdgcn_mfma_f32_16x16x32_bf16(a0,b0,acc00,0,0,0);
    acc01 = __builtin_amdgcn_mfma_f32_16x16x32_bf16(a0,b1,acc01,0,0,0);
    acc10 = __builtin_amdgcn_mfma_f32_16x16x32_bf16(a1,b0,acc10,0,0,0);
    acc11 = __builtin_amdgcn_mfma_f32_16x16x32_bf16(a1,b1,acc11,0,0,0);
  }
  #pragma unroll
  for(int mt=0; mt<2; mt++){
    #pragma unroll
    for(int nt=0; nt<2; nt++){
      f32x4 av = (mt==0)? (nt==0?acc00:acc01) : (nt==0?acc10:acc11);
      int col = n_base + nt*16 + cl;
      float bv = bias? bias[col] : 0.0f;
      #pragma unroll
      for(int r=0;r<4;r++){
        int row = m_base + mt*16 + q4*4 + r;
        float v = av[r] + bv;
        if(act) v = tanh_f(v);
        if(outbf) outbf[(size_t)row*ldc + col] = f2bf(v);
        else      outf [(size_t)row*ldc + col] = v;
      }
    }
  }
}

// ---------------- gi GEMM with lane-packed scatter epilogue ----------------
// Computes gi = x @ w_ih^T + b_ih and scatters each recurrence-lane's 24 values
// contiguous: idx = ((((t*2 + blk)*8 + w)*64 + lane)*24 + g*8 + s*4 + r.
// A rows are b*steps + t (steps = 1<<ss). N = 768.
__global__ __launch_bounds__(256) void k_gemm_gi(
    const unsigned short* __restrict__ A, const unsigned short* __restrict__ Bt,
    const float* __restrict__ bias, unsigned short* __restrict__ gi_out, int ss)
{
  int lane = threadIdx.x & 63, wave = threadIdx.x >> 6;
  int m_base = blockIdx.x*64 + (wave>>1)*32;
  int n_base = blockIdx.y*64 + (wave&1)*32;
  int cl = lane & 15, q4 = lane >> 4;
  f32x4 acc00={0.f,0.f,0.f,0.f}, acc01=acc00, acc10=acc00, acc11=acc00;
  for(int kf=0; kf<4; kf++){   // K = 128
    int ko = kf*32 + q4*8;
    bf16x8 a0 = *(const bf16x8*)(A + (size_t)(m_base+cl)*128 + ko);
    bf16x8 a1 = *(const bf16x8*)(A + (size_t)(m_base+16+cl)*128 + ko);
    bf16x8 b0 = *(const bf16x8*)(Bt + (size_t)(n_base+cl)*128 + ko);
    bf16x8 b1 = *(const bf16x8*)(Bt + (size_t)(n_base+16+cl)*128 + ko);
    acc00 = __builtin_amdgcn_mfma_f32_16x16x32_bf16(a0,b0,acc00,0,0,0);
    acc01 = __builtin_amdgcn_mfma_f32_16x16x32_bf16(a0,b1,acc01,0,0,0);
    acc10 = __builtin_amdgcn_mfma_f32_16x16x32_bf16(a1,b0,acc10,0,0,0);
    acc11 = __builtin_amdgcn_mfma_f32_16x16x32_bf16(a1,b1,acc11,0,0,0);
  }
  const int tmask = (1<<ss) - 1;
  #pragma unroll
  for(int mt=0; mt<2; mt++){
    #pragma unroll
    for(int nt=0; nt<2; nt++){
      f32x4 av = (mt==0)? (nt==0?acc00:acc01) : (nt==0?acc10:acc11);
      int col = n_base + nt*16 + cl;
      float bv = bias[col];
      int g = col >> 8, rem = col & 255;
      int w = rem >> 5, s = (rem>>4)&1, cl2 = rem & 15;
      #pragma unroll
      for(int r=0;r<4;r++){
        int arow = m_base + mt*16 + q4*4 + r;
        int t = arow & tmask, b = arow >> ss;
        int blk = b >> 4, brow = b & 15;
        int lane2 = (brow>>2)*16 + cl2, rc = brow & 3;
        size_t idx = ((((size_t)t*2 + blk)*8 + w)*64 + lane2)*24 + g*8 + s*4 + rc;
        gi_out[idx] = f2bf(av[r] + bv);
      }
    }
  }
}

// ---------------- GRU recurrence ----------------
// BYTE-IDENTICAL to the verified best (round 0 / round 7: 2026/2034 us).
// DO NOT TOUCH: the compiled schedule is a knife-edge optimum; every probed
// perturbation (pass-split, 16-wave, gi prefetch, operand swap, bias-fold)
// regressed 17-75% (rounds 1-6, all code-real per round-7 reproduction).
__global__ __launch_bounds__(512,1) void k_gru_rec(
    const unsigned short* __restrict__ whh_c, const unsigned short* __restrict__ whh_q,
    const unsigned short* __restrict__ gi_c,  const unsigned short* __restrict__ gi_q,
    const float* __restrict__ bhh_c, const float* __restrict__ bhh_q,
    const float* __restrict__ h0_c,  const float* __restrict__ h0_q,
    float* __restrict__ c_out, float* __restrict__ q_hT)
{
  __shared__ unsigned short hb0[16*264];   // double-buffered h (row stride 264 u16)
  __shared__ unsigned short hb1[16*264];

  const int blk = blockIdx.x;
  const bool isq = blk >= 2;
  const int cls = isq? blk-2 : blk;        // block index within class (0/1)
  const int b0 = cls * 16;
  const unsigned short* W  = isq? whh_q : whh_c;
  const unsigned short* GI = isq? gi_q  : gi_c;
  const float* bhh = isq? bhh_q : bhh_c;
  const float* h0  = isq? h0_q  : h0_c;
  const int steps  = isq? 32 : 1024;

  const int tid = threadIdx.x;
  const int lane = tid & 63, wave = tid >> 6;
  const int cl = lane & 15, q4 = lane >> 4;

  // B-fragments: [gate][subtile][kfrag], col = g*256 + wave*32 + s*16 + cl
  bf16x8 Bf[3][2][8];
  #pragma unroll
  for(int g=0; g<3; g++)
    #pragma unroll
    for(int s=0; s<2; s++){
      const unsigned short* wrow = W + (size_t)(g*256 + wave*32 + s*16 + cl)*256;
      #pragma unroll
      for(int kf=0; kf<8; kf++)
        Bf[g][s][kf] = *(const bf16x8*)(wrow + kf*32 + q4*8);
    }

  // per-lane biases for owned cols
  float bR[2], bZ[2], bN[2];
  #pragma unroll
  for(int s=0; s<2; s++){
    const int col = wave*32 + s*16 + cl;
    bR[s] = bhh[col]; bZ[s] = bhh[256+col]; bN[s] = bhh[512+col];
  }

  // h in registers: lane owns (row=q4*4+r, col=wave*32+s*16+cl)
  float hreg[2][4];
  #pragma unroll
  for(int s=0; s<2; s++){
    const int col = wave*32 + s*16 + cl;
    #pragma unroll
    for(int r=0; r<4; r++){
      const int row = q4*4 + r;
      float v = h0[(size_t)(b0+row)*256 + col];
      hreg[s][r] = v;
      hb0[row*264 + col] = f2bf(v);
    }
  }
  __syncthreads();

  unsigned short* hb_rd = hb0;
  unsigned short* hb_wr = hb1;

  // per-lane gi base for this (blk, wave, lane)
  const unsigned short* gi_lane = GI + (((size_t)cls*8 + wave)*64 + lane)*24;
  const size_t gi_tstride = (size_t)2*8*64*24;   // per-t stride in u16

  for(int t=0; t<steps; t++){
    // gi(t): 3x dwordx4 (48 B contiguous per lane); consumed in phase B
    const unsigned short* gp = gi_lane + (size_t)t*gi_tstride;
    i32x4 G0 = *(const i32x4*)(gp);        // gate r : [s0r0..s0r3, s1r0..s1r3]
    i32x4 G1 = *(const i32x4*)(gp + 8);    // gate z
    i32x4 G2 = *(const i32x4*)(gp + 16);   // gate n

    // deferred c_out store of h(t-1): overlaps with MFMA phase
    if(!isq && t>0){
      #pragma unroll
      for(int s=0; s<2; s++){
        const int col = wave*32 + s*16 + cl;
        #pragma unroll
        for(int r=0; r<4; r++)
          c_out[((size_t)(b0+q4*4+r)*1024 + (t-1))*256 + col] = hreg[s][r];
      }
    }

    // phase A: gates = h @ W^T  (48 MFMAs/wave)
    f32x4 acc[3][2];
    #pragma unroll
    for(int g=0; g<3; g++)
      #pragma unroll
      for(int s=0; s<2; s++){ f32x4 z={0.f,0.f,0.f,0.f}; acc[g][s]=z; }
    #pragma unroll
    for(int kf=0; kf<8; kf++){
      bf16x8 a = *(const bf16x8*)&hb_rd[cl*264 + kf*32 + q4*8];
      #pragma unroll
      for(int g=0; g<3; g++)
        #pragma unroll
        for(int s=0; s<2; s++)
          acc[g][s] = __builtin_amdgcn_mfma_f32_16x16x32_bf16(a, Bf[g][s][kf], acc[g][s], 0,0,0);
    }

    // phase B: in-register GRU update (writes OTHER h buffer -> no barrier needed here)
    #pragma unroll
    for(int s=0; s<2; s++){
      const int col = wave*32 + s*16 + cl;
      #pragma unroll
      for(int r=0; r<4; r++){
        const int row = q4*4 + r;
        const int k = s*4 + r;
        float gir = bfsel(G0[k>>1], k&1);
        float giz = bfsel(G1[k>>1], k&1);
        float gin = bfsel(G2[k>>1], k&1);
        float rr = sigm_f(gir + acc[0][s][r] + bR[s]);
        float zz = sigm_f(giz + acc[1][s][r] + bZ[s]);
        float nn = tanh_f(gin + rr*(acc[2][s][r] + bN[s]));
        float x  = nn + zz*(hreg[s][r] - nn);
        hreg[s][r] = x;
        hb_wr[row*264 + col] = f2bf(x);
      }
    }
    __syncthreads();   // hb_wr complete -> next step's phase A may read it
    unsigned short* tmp = hb_rd; hb_rd = hb_wr; hb_wr = tmp;
  }

  // final stores from hreg
  #pragma unroll
  for(int s=0; s<2; s++){
    const int col = wave*32 + s*16 + cl;
    #pragma unroll
    for(int r=0; r<4; r++){
      const int row = q4*4 + r;
      if(!isq) c_out[((size_t)(b0+row)*1024 + (steps-1))*256 + col] = hreg[s][r];
      else     q_hT[(size_t)(b0+row)*256 + col] = hreg[s][r];
    }
  }
}

// ---------------- attention helpers ----------------
__global__ void k_gather(const float* __restrict__ c_out, const int* __restrict__ c_index,
                         float* __restrict__ c_sel, unsigned short* __restrict__ c_sel_bf){
  int row = blockIdx.x;                 // 0..4095 = b*128+s
  int b = row >> 7, s = row & 127;
  int idx = c_index[b*128 + s];
  float v = c_out[((size_t)b*1024 + idx)*256 + threadIdx.x];
  c_sel   [(size_t)row*256 + threadIdx.x] = v;
  c_sel_bf[(size_t)row*256 + threadIdx.x] = f2bf(v);
}

__global__ void k_feats(const float* __restrict__ c_sel, const float* __restrict__ cw,
                        const float* __restrict__ m_, const float* __restrict__ qh,
                        unsigned short* __restrict__ feats){
  int row = blockIdx.x, tid = threadIdx.x;
  int b = row >> 7;
  float cs  = c_sel[(size_t)row*256 + tid];
  float mj  = m_[b*256 + tid];
  float qj  = qh[b*256 + tid];
  float cwj = cw[(size_t)row*256 + tid];
  float dq = cwj*qj, dm = cwj*mj;
  #pragma unroll
  for(int o=32;o>0;o>>=1){ dq += __shfl_down(dq,o); dm += __shfl_down(dm,o); }
  __shared__ float rq[4], rm[4];
  int lane = tid&63, wave=tid>>6;
  if(lane==0){ rq[wave]=dq; rm[wave]=dm; }
  __syncthreads();
  unsigned short* fr = feats + (size_t)row*1824;
  fr[tid]      = f2bf(cs);
  fr[256+tid]  = f2bf(mj);
  fr[512+tid]  = f2bf(qj);
  fr[768+tid]  = f2bf(cs*qj);
  fr[1024+tid] = f2bf(cs*mj);
  fr[1280+tid] = f2bf(fabsf(cs-qj));
  fr[1536+tid] = f2bf(fabsf(cs-mj));
  if(tid==0){
    float DQ = rq[0]+rq[1]+rq[2]+rq[3];
    float DM = rm[0]+rm[1]+rm[2]+rm[3];
    fr[1792]=f2bf(DQ); fr[1793]=f2bf(DM);
  }
  if(tid<30) fr[1794+tid]=0;   // zero K-pad
}

// ---------------- fused episodic tail: scores + masked softmax + e + mem GRU cell ----
// One block per batch row (grid=32, block=256). Replaces k_scores + k_softmax_e +
// k_gru_cell(mem) and keeps scores/p/e in LDS. Per-output arithmetic order matches
// the kernels it replaces (scores dot is serial instead of shuffle-tree).
__global__ void k_att_tail(const float* __restrict__ h1, const float* __restrict__ w2,
                           const float* __restrict__ b2, const int* __restrict__ len_c,
                           const float* __restrict__ c_sel,
                           const float* __restrict__ m_in,
                           const float* __restrict__ wihT, const float* __restrict__ whhT,
                           const float* __restrict__ bih, const float* __restrict__ bhh,
                           float* __restrict__ out_att, float* __restrict__ m_out){
  __shared__ float red[256];
  __shared__ float p[128];
  __shared__ float es[256];
  __shared__ float hs[256];
  int b = blockIdx.x, tid = threadIdx.x;
  int L = len_c[b];
  // scores (rows tid<128): dot(h1[row,0:100], w2) + b2
  float s = -1e30f;
  if(tid < 128 && tid < L){
    const float* hr = h1 + ((size_t)b*128 + tid)*128;
    float a = 0.0f;
    for(int k=0;k<100;k++) a += hr[k]*w2[k];
    s = a + b2[0];
  }
  red[tid]=s; __syncthreads();
  for(int o=128;o>0;o>>=1){ if(tid<o) red[tid]=fmaxf(red[tid],red[tid+o]); __syncthreads(); }
  float mx = red[0]; __syncthreads();
  float ex = (tid<128 && tid<L)? __expf(s-mx) : 0.0f;
  red[tid]=ex; __syncthreads();
  for(int o=128;o>0;o>>=1){ if(tid<o) red[tid]+=red[tid+o]; __syncthreads(); }
  float inv = 1.0f/red[0];
  if(tid<128){ float pv = ex*inv; p[tid]=pv; out_att[b*128+tid]=pv; }
  hs[tid] = m_in[b*256+tid];
  __syncthreads();
  // e = sum_s p[s] * c_sel[b,s,:]
  float acc = 0.0f;
  for(int si=0; si<128; si++) acc += p[si]*c_sel[((size_t)b*128+si)*256 + tid];
  es[tid] = acc;
  __syncthreads();
  // mem GRU cell (identical order to k_gru_cell)
  float ar=0, az=0, an=0;
  for(int k=0;k<256;k++){
    float xv = es[k];
    const float* wr = wihT + (size_t)k*768;
    ar += xv*wr[tid]; az += xv*wr[256+tid]; an += xv*wr[512+tid];
  }
  float gr=0, gz=0, gn=0;
  for(int k=0;k<256;k++){
    float hv = hs[k];
    const float* wr = whhT + (size_t)k*768;
    gr += hv*wr[tid]; gz += hv*wr[256+tid]; gn += hv*wr[512+tid];
  }
  float rr = sigm_f(ar + bih[tid]     + gr + bhh[tid]);
  float zz = sigm_f(az + bih[256+tid] + gz + bhh[256+tid]);
  float nn = tanh_f(an + bih[512+tid] + rr*(gn + bhh[512+tid]));
  m_out[b*256+tid] = (1.0f-zz)*nn + zz*hs[tid];
}

// ---------------- fused answer step: logits + softmax (+ optional ans GRU cell) ----
// One block per batch row (grid=32, block=256). Replaces k_logits + k_softmax_o +
// k_gru_cell(ans); y stays in LDS. Accumulation orders identical to the originals.
__global__ void k_ans(const float* __restrict__ msq_in, const float* __restrict__ out_wT,
                      const float* __restrict__ out_b, const float* __restrict__ qh,
                      const float* __restrict__ wihT, const float* __restrict__ whhT,
                      const float* __restrict__ bih, const float* __restrict__ bhh,
                      int do_cell, float* __restrict__ y_out, float* __restrict__ msq_out){
  __shared__ float yl[2000];
  __shared__ float ms[256];
  __shared__ float qs[256];
  __shared__ float red[256];
  int b = blockIdx.x, tid = threadIdx.x;
  ms[tid] = msq_in[b*256+tid];
  qs[tid] = qh[b*256+tid];
  __syncthreads();
  // logits (same order as k_logits: serial k, bias first)
  for(int n=tid; n<2000; n+=256){
    float acc = out_b[n];
    for(int k=0;k<256;k++) acc += ms[k]*out_wT[(size_t)k*2000 + n];
    yl[n] = acc;
  }
  __syncthreads();
  // softmax over 2000 (same structure as k_softmax_o)
  float mx = -1e30f;
  for(int i=tid;i<2000;i+=256) mx = fmaxf(mx, yl[i]);
  red[tid]=mx; __syncthreads();
  for(int o=128;o>0;o>>=1){ if(tid<o) red[tid]=fmaxf(red[tid],red[tid+o]); __syncthreads(); }
  mx = red[0]; __syncthreads();
  float sum=0.0f;
  for(int i=tid;i<2000;i+=256) sum += __expf(yl[i]-mx);
  red[tid]=sum; __syncthreads();
  for(int o=128;o>0;o>>=1){ if(tid<o) red[tid]+=red[tid+o]; __syncthreads(); }
  float inv = 1.0f/red[0];
  // each yl[i] is read/written only by thread i%256 -> in-place safe
  for(int i=tid;i<2000;i+=256){
    float yv = __expf(yl[i]-mx)*inv;
    yl[i] = yv;
    if(y_out) y_out[(size_t)b*2000+i] = yv;
  }
  if(!do_cell) return;
  __syncthreads();
  // ans GRU cell: x = [y(2000) || qh(256)] (identical order to k_gru_cell)
  float ar=0, az=0, an=0;
  for(int k=0;k<2000;k++){
    float xv = yl[k];
    const float* wr = wihT + (size_t)k*768;
    ar += xv*wr[tid]; az += xv*wr[256+tid]; an += xv*wr[512+tid];
  }
  for(int k=0;k<256;k++){
    float xv = qs[k];
    const float* wr = wihT + (size_t)(2000+k)*768;
    ar += xv*wr[tid]; az += xv*wr[256+tid]; an += xv*wr[512+tid];
  }
  float gr=0, gz=0, gn=0;
  for(int k=0;k<256;k++){
    float hv = ms[k];
    const float* wr = whhT + (size_t)k*768;
    gr += hv*wr[tid]; gz += hv*wr[256+tid]; gn += hv*wr[512+tid];
  }
  float rr = sigm_f(ar + bih[tid]     + gr + bhh[tid]);
  float zz = sigm_f(az + bih[256+tid] + gz + bhh[256+tid]);
  float nn = tanh_f(an + bih[512+tid] + rr*(gn + bhh[512+tid]));
  msq_out[b*256+tid] = (1.0f-zz)*nn + zz*ms[tid];
}

// ---------------- launch ----------------
extern "C" void kernel_launch(void* const* d_in, const int* in_sizes, int n_in,
                              void* d_out, int out_size, void* d_ws, size_t ws_size,
                              hipStream_t stream)
{
  const float* c        = (const float*)d_in[0];
  const float* q        = (const float*)d_in[1];
  const float* i_state  = (const float*)d_in[2];
  const float* q_state  = (const float*)d_in[3];
  const float* in_w_ih  = (const float*)d_in[4];
  const float* in_w_hh  = (const float*)d_in[5];
  const float* in_b_ih  = (const float*)d_in[6];
  const float* in_b_hh  = (const float*)d_in[7];
  const float* qe_w_ih  = (const float*)d_in[8];
  const float* qe_w_hh  = (const float*)d_in[9];
  const float* qe_b_ih  = (const float*)d_in[10];
  const float* qe_b_hh  = (const float*)d_in[11];
  const float* att_weight = (const float*)d_in[12];
  const float* att_w1   = (const float*)d_in[13];
  const float* att_b1   = (const float*)d_in[14];
  const float* att_w2   = (const float*)d_in[15];
  const float* att_b2   = (const float*)d_in[16];
  const float* mem_w_ih = (const float*)d_in[17];
  const float* mem_w_hh = (const float*)d_in[18];
  const float* mem_b_ih = (const float*)d_in[19];
  const float* mem_b_hh = (const float*)d_in[20];
  const float* out_w    = (const float*)d_in[21];
  const float* out_b    = (const float*)d_in[22];
  const float* ans_w_ih = (const float*)d_in[23];
  const float* ans_w_hh = (const float*)d_in[24];
  const float* ans_b_ih = (const float*)d_in[25];
  const float* ans_b_hh = (const float*)d_in[26];
  const int*   c_index  = (const int*)d_in[27];
  const int*   len_c    = (const int*)d_in[28];
  float* outp = (float*)d_out;   // [0,64000) y ; [64000,76288) att (3,32,128)

  char* wp = (char*)d_ws;
  auto take = [&](size_t nbytes)->char*{
    char* p = wp; wp += (nbytes + 255) & ~(size_t)255; return p;
  };
  unsigned short* c_bf      = (unsigned short*)take((size_t)32*1024*128*2);
  unsigned short* q_bf      = (unsigned short*)take((size_t)32*32*128*2);
  unsigned short* wih_in_bf = (unsigned short*)take(768*128*2);
  unsigned short* wih_qe_bf = (unsigned short*)take(768*128*2);
  unsigned short* whh_in_bf = (unsigned short*)take(768*256*2);
  unsigned short* whh_qe_bf = (unsigned short*)take(768*256*2);
  unsigned short* attwT_bf  = (unsigned short*)take(256*256*2);
  unsigned short* attw1_bf  = (unsigned short*)take(128*1824*2);
  float* b1pad              = (float*)take(128*4);
  float* out_wT             = (float*)take((size_t)256*2000*4);
  float* mem_wihT           = (float*)take(256*768*4);
  float* mem_whhT           = (float*)take(256*768*4);
  float* ans_wihT           = (float*)take((size_t)2256*768*4);
  float* ans_whhT           = (float*)take(256*768*4);
  unsigned short* gi_c_bf   = (unsigned short*)take((size_t)32768*768*2);  // lane-packed
  unsigned short* gi_q_bf   = (unsigned short*)take((size_t)1024*768*2);   // lane-packed
  float* c_out              = (float*)take((size_t)32*1024*256*4);
  float* q_hT               = (float*)take(32*256*4);
  float* c_sel              = (float*)take((size_t)4096*256*4);
  unsigned short* c_sel_bf  = (unsigned short*)take((size_t)4096*256*2);
  float* cw                 = (float*)take((size_t)4096*256*4);
  unsigned short* feats_bf  = (unsigned short*)take((size_t)4096*1824*2);
  float* h1                 = (float*)take((size_t)4096*128*4);
  float* m_buf              = (float*)take(32*256*4);
  float* msq                = (float*)take(32*256*4);

  // ---- prep / conversions ----
  k_f2bf<<<16384,256,0,stream>>>(c, c_bf, 32*1024*128);
  k_f2bf<<<512,256,0,stream>>>(q, q_bf, 32*32*128);
  k_f2bf<<<384,256,0,stream>>>(in_w_ih, wih_in_bf, 768*128);
  k_f2bf<<<384,256,0,stream>>>(qe_w_ih, wih_qe_bf, 768*128);
  k_f2bf<<<768,256,0,stream>>>(in_w_hh, whh_in_bf, 768*256);
  k_f2bf<<<768,256,0,stream>>>(qe_w_hh, whh_qe_bf, 768*256);
  k_attwT<<<256,256,0,stream>>>(att_weight, attwT_bf);
  k_attw1<<<912,256,0,stream>>>(att_w1, attw1_bf);
  k_b1pad<<<1,128,0,stream>>>(att_b1, b1pad);
  k_transpose<<<2000,256,0,stream>>>(out_w, out_wT, 2000, 256);
  k_transpose<<<768,256,0,stream>>>(mem_w_ih, mem_wihT, 768, 256);
  k_transpose<<<768,256,0,stream>>>(mem_w_hh, mem_whhT, 768, 256);
  k_transpose<<<6768,256,0,stream>>>(ans_w_ih, ans_wihT, 768, 2256);
  k_transpose<<<768,256,0,stream>>>(ans_w_hh, ans_whhT, 768, 256);

  // ---- time-parallel input projections with lane-packed scatter ----
  k_gemm_gi<<<dim3(512,12),256,0,stream>>>(c_bf, wih_in_bf, in_b_ih, gi_c_bf, 10);
  k_gemm_gi<<<dim3(16,12),256,0,stream>>>(q_bf, wih_qe_bf, qe_b_ih, gi_q_bf, 5);

  // ---- sequential GRU recurrences (context 1024 steps + query 32 steps) ----
  k_gru_rec<<<4,512,0,stream>>>(whh_in_bf, whh_qe_bf, gi_c_bf, gi_q_bf,
                                in_b_hh, qe_b_hh, i_state, q_state, c_out, q_hT);

  // ---- attention setup ----
  k_gather<<<4096,256,0,stream>>>(c_out, c_index, c_sel, c_sel_bf);
  k_gemm_bf16<<<dim3(64,4),256,0,stream>>>(c_sel_bf, attwT_bf, 256, nullptr, 0, cw, nullptr, 256);

  // ---- 3 episodic memory iterations (m starts as q_hT; fused tail) ----
  for(int it=0; it<3; it++){
    const float* m_cur = (it==0)? q_hT : m_buf;
    k_feats<<<4096,256,0,stream>>>(c_sel, cw, m_cur, q_hT, feats_bf);
    k_gemm_bf16<<<dim3(64,2),256,0,stream>>>(feats_bf, attw1_bf, 1824, b1pad, 1, h1, nullptr, 128);
    k_att_tail<<<32,256,0,stream>>>(h1, att_w2, att_b2, len_c, c_sel, m_cur,
                                    mem_wihT, mem_whhT, mem_b_ih, mem_b_hh,
                                    outp + 64000 + it*4096, m_buf);
  }

  // ---- answer module (fused logits+softmax+cell) ----
  k_ans<<<32,256,0,stream>>>(m_buf, out_wT, out_b, q_hT,
                             ans_wihT, ans_whhT, ans_b_ih, ans_b_hh,
                             1, nullptr, msq);
  k_ans<<<32,256,0,stream>>>(msq, out_wT, out_b, q_hT,
                             ans_wihT, ans_whhT, ans_b_ih, ans_b_hh,
                             1, nullptr, msq);
  k_ans<<<32,256,0,stream>>>(msq, out_wT, out_b, q_hT,
                             ans_wihT, ans_whhT, ans_b_ih, ans_b_hh,
                             0, outp, nullptr);
}

// Round 9
// 2923.654 us; speedup vs baseline: 1.6026x; 1.0115x over previous
//
#include <hip/hip_runtime.h>
#include <cstdint>
#include <cstddef>

typedef short bf16x8 __attribute__((ext_vector_type(8)));
typedef float f32x4 __attribute__((ext_vector_type(4)));
typedef int   i32x4 __attribute__((ext_vector_type(4)));

#define DEV static __device__ __forceinline__

DEV unsigned short f2bf(float x){
  union{float f; unsigned int u;} v; v.f = x;
  unsigned int r = (v.u + 0x7FFFu + ((v.u>>16)&1u)) >> 16;
  return (unsigned short)r;
}
DEV float bf2f(unsigned short h){
  union{unsigned int u; float f;} v; v.u = ((unsigned int)h)<<16;
  return v.f;
}
// unpack bf16 half of a dword: hi=0 -> low u16, hi=1 -> high u16
DEV float bfsel(int dw, int hi){
  union{unsigned int u; float f;} v;
  v.u = hi ? ((unsigned int)dw & 0xFFFF0000u) : ((unsigned int)dw << 16);
  return v.f;
}
// fast gates: v_exp_f32 + v_rcp_f32
DEV float sigm_f(float x){ return __builtin_amdgcn_rcpf(1.0f + __expf(-x)); }
DEV float tanh_f(float x){ return 2.0f*__builtin_amdgcn_rcpf(1.0f + __expf(-2.0f*x)) - 1.0f; }

// ---------------- prep kernels ----------------
__global__ void k_f2bf(const float* __restrict__ src, unsigned short* __restrict__ dst, int n){
  int i = blockIdx.x*256 + threadIdx.x;
  if(i<n) dst[i] = f2bf(src[i]);
}

// Fused prep: all small conversions/transposes in ONE launch, dispatched by
// blockIdx range. Each branch reproduces the original kernel's exact
// indexing/arithmetic (launch-overhead reduction only; numerics identical).
// Block budget: q(512) wih_in(384) wih_qe(384) whh_in(768) whh_qe(768)
// attwT(256) attw1(912) b1pad(1) T_out_w(2000) T_mem_ih(768) T_mem_hh(768)
// T_ans_ih(6768) T_ans_hh(768)  => total 15057 blocks of 256.
__global__ void k_prep(
    const float* __restrict__ q,        unsigned short* __restrict__ q_bf,
    const float* __restrict__ in_w_ih,  unsigned short* __restrict__ wih_in_bf,
    const float* __restrict__ qe_w_ih,  unsigned short* __restrict__ wih_qe_bf,
    const float* __restrict__ in_w_hh,  unsigned short* __restrict__ whh_in_bf,
    const float* __restrict__ qe_w_hh,  unsigned short* __restrict__ whh_qe_bf,
    const float* __restrict__ att_weight, unsigned short* __restrict__ attwT_bf,
    const float* __restrict__ att_w1,   unsigned short* __restrict__ attw1_bf,
    const float* __restrict__ att_b1,   float* __restrict__ b1pad,
    const float* __restrict__ out_w,    float* __restrict__ out_wT,
    const float* __restrict__ mem_w_ih, float* __restrict__ mem_wihT,
    const float* __restrict__ mem_w_hh, float* __restrict__ mem_whhT,
    const float* __restrict__ ans_w_ih, float* __restrict__ ans_wihT,
    const float* __restrict__ ans_w_hh, float* __restrict__ ans_whhT)
{
  int bid = blockIdx.x;
  const int tid = threadIdx.x;
  // f2bf q : 32*32*128
  if(bid < 512){ int i = bid*256 + tid; if(i < 131072) q_bf[i] = f2bf(q[i]); return; }
  bid -= 512;
  // f2bf in_w_ih : 768*128
  if(bid < 384){ int i = bid*256 + tid; if(i < 98304) wih_in_bf[i] = f2bf(in_w_ih[i]); return; }
  bid -= 384;
  // f2bf qe_w_ih : 768*128
  if(bid < 384){ int i = bid*256 + tid; if(i < 98304) wih_qe_bf[i] = f2bf(qe_w_ih[i]); return; }
  bid -= 384;
  // f2bf in_w_hh : 768*256
  if(bid < 768){ int i = bid*256 + tid; if(i < 196608) whh_in_bf[i] = f2bf(in_w_hh[i]); return; }
  bid -= 768;
  // f2bf qe_w_hh : 768*256
  if(bid < 768){ int i = bid*256 + tid; if(i < 196608) whh_qe_bf[i] = f2bf(qe_w_hh[i]); return; }
  bid -= 768;
  // attwT : out[n*256+k] = aw[k*256+n]
  if(bid < 256){ int i = bid*256 + tid; if(i < 65536){ int n = i>>8, k = i&255; attwT_bf[i] = f2bf(att_weight[k*256 + n]); } return; }
  bid -= 256;
  // attw1 : 128*1824 padded
  if(bid < 912){
    int i = bid*256 + tid;
    if(i < 128*1824){
      int r = i/1824, cc = i - r*1824;
      float v = (r<100 && cc<1794)? att_w1[r*1794 + cc] : 0.0f;
      attw1_bf[i] = f2bf(v);
    }
    return;
  }
  bid -= 912;
  // b1pad
  if(bid < 1){ if(tid < 128) b1pad[tid] = (tid<100)? att_b1[tid] : 0.0f; return; }
  bid -= 1;
  // transpose out_w (2000,256)
  if(bid < 2000){ int i = bid*256 + tid; if(i < 2000*256){ int r = i/256, c = i - r*256; out_wT[(size_t)c*2000 + r] = out_w[i]; } return; }
  bid -= 2000;
  // transpose mem_w_ih (768,256)
  if(bid < 768){ int i = bid*256 + tid; if(i < 768*256){ int r = i/256, c = i - r*256; mem_wihT[(size_t)c*768 + r] = mem_w_ih[i]; } return; }
  bid -= 768;
  // transpose mem_w_hh (768,256)
  if(bid < 768){ int i = bid*256 + tid; if(i < 768*256){ int r = i/256, c = i - r*256; mem_whhT[(size_t)c*768 + r] = mem_w_hh[i]; } return; }
  bid -= 768;
  // transpose ans_w_ih (768,2256)
  if(bid < 6768){ int i = bid*256 + tid; if(i < 768*2256){ int r = i/2256, c = i - r*2256; ans_wihT[(size_t)c*768 + r] = ans_w_ih[i]; } return; }
  bid -= 6768;
  // transpose ans_w_hh (768,256)
  if(bid < 768){ int i = bid*256 + tid; if(i < 768*256){ int r = i/256, c = i - r*256; ans_whhT[(size_t)c*768 + r] = ans_w_hh[i]; } return; }
}

// ---------------- generic bf16 MFMA GEMM: C(M,N) = A(M,K) @ Bt(N,K)^T ----------------
__global__ __launch_bounds__(256) void k_gemm_bf16(
    const unsigned short* __restrict__ A, const unsigned short* __restrict__ Bt,
    int K, const float* __restrict__ bias, int act,
    float* __restrict__ outf, unsigned short* __restrict__ outbf, int ldc)
{
  int lane = threadIdx.x & 63, wave = threadIdx.x >> 6;
  int m_base = blockIdx.x*64 + (wave>>1)*32;
  int n_base = blockIdx.y*64 + (wave&1)*32;
  int cl = lane & 15, q4 = lane >> 4;
  f32x4 acc00={0.f,0.f,0.f,0.f}, acc01=acc00, acc10=acc00, acc11=acc00;
  const int kf_n = K >> 5;
  for(int kf=0; kf<kf_n; kf++){
    int ko = kf*32 + q4*8;
    bf16x8 a0 = *(const bf16x8*)(A + (size_t)(m_base+cl)*K + ko);
    bf16x8 a1 = *(const bf16x8*)(A + (size_t)(m_base+16+cl)*K + ko);
    bf16x8 b0 = *(const bf16x8*)(Bt + (size_t)(n_base+cl)*K + ko);
    bf16x8 b1 = *(const bf16x8*)(Bt + (size_t)(n_base+16+cl)*K + ko);
    acc00 = __builtin_amdgcn_mfma_f32_16x16x32_bf16(a0,b0,acc00,0,0,0);
    acc01 = __builtin_amdgcn_mfma_f32_16x16x32_bf16(a0,b1,acc01,0,0,0);
    acc10 = __builtin_amdgcn_mfma_f32_16x16x32_bf16(a1,b0,acc10,0,0,0);
    acc11 = __builtin_amdgcn_mfma_f32_16x16x32_bf16(a1,b1,acc11,0,0,0);
  }
  #pragma unroll
  for(int mt=0; mt<2; mt++){
    #pragma unroll
    for(int nt=0; nt<2; nt++){
      f32x4 av = (mt==0)? (nt==0?acc00:acc01) : (nt==0?acc10:acc11);
      int col = n_base + nt*16 + cl;
      float bv = bias? bias[col] : 0.0f;
      #pragma unroll
      for(int r=0;r<4;r++){
        int row = m_base + mt*16 + q4*4 + r;
        float v = av[r] + bv;
        if(act) v = tanh_f(v);
        if(outbf) outbf[(size_t)row*ldc + col] = f2bf(v);
        else      outf [(size_t)row*ldc + col] = v;
      }
    }
  }
}

// ---------------- gi GEMM with lane-packed scatter epilogue ----------------
// Computes gi = x @ w_ih^T + b_ih and scatters each recurrence-lane's 24 values
// contiguous: idx = ((((t*2 + blk)*8 + w)*64 + lane)*24 + g*8 + s*4 + r.
// A rows are b*steps + t (steps = 1<<ss). N = 768.
__global__ __launch_bounds__(256) void k_gemm_gi(
    const unsigned short* __restrict__ A, const unsigned short* __restrict__ Bt,
    const float* __restrict__ bias, unsigned short* __restrict__ gi_out, int ss)
{
  int lane = threadIdx.x & 63, wave = threadIdx.x >> 6;
  int m_base = blockIdx.x*64 + (wave>>1)*32;
  int n_base = blockIdx.y*64 + (wave&1)*32;
  int cl = lane & 15, q4 = lane >> 4;
  f32x4 acc00={0.f,0.f,0.f,0.f}, acc01=acc00, acc10=acc00, acc11=acc00;
  for(int kf=0; kf<4; kf++){   // K = 128
    int ko = kf*32 + q4*8;
    bf16x8 a0 = *(const bf16x8*)(A + (size_t)(m_base+cl)*128 + ko);
    bf16x8 a1 = *(const bf16x8*)(A + (size_t)(m_base+16+cl)*128 + ko);
    bf16x8 b0 = *(const bf16x8*)(Bt + (size_t)(n_base+cl)*128 + ko);
    bf16x8 b1 = *(const bf16x8*)(Bt + (size_t)(n_base+16+cl)*128 + ko);
    acc00 = __builtin_amdgcn_mfma_f32_16x16x32_bf16(a0,b0,acc00,0,0,0);
    acc01 = __builtin_amdgcn_mfma_f32_16x16x32_bf16(a0,b1,acc01,0,0,0);
    acc10 = __builtin_amdgcn_mfma_f32_16x16x32_bf16(a1,b0,acc10,0,0,0);
    acc11 = __builtin_amdgcn_mfma_f32_16x16x32_bf16(a1,b1,acc11,0,0,0);
  }
  const int tmask = (1<<ss) - 1;
  #pragma unroll
  for(int mt=0; mt<2; mt++){
    #pragma unroll
    for(int nt=0; nt<2; nt++){
      f32x4 av = (mt==0)? (nt==0?acc00:acc01) : (nt==0?acc10:acc11);
      int col = n_base + nt*16 + cl;
      float bv = bias[col];
      int g = col >> 8, rem = col & 255;
      int w = rem >> 5, s = (rem>>4)&1, cl2 = rem & 15;
      #pragma unroll
      for(int r=0;r<4;r++){
        int arow = m_base + mt*16 + q4*4 + r;
        int t = arow & tmask, b = arow >> ss;
        int blk = b >> 4, brow = b & 15;
        int lane2 = (brow>>2)*16 + cl2, rc = brow & 3;
        size_t idx = ((((size_t)t*2 + blk)*8 + w)*64 + lane2)*24 + g*8 + s*4 + rc;
        gi_out[idx] = f2bf(av[r] + bv);
      }
    }
  }
}

// ---------------- GRU recurrence ----------------
// BYTE-IDENTICAL to the verified best (round 0 / 7 / 8: 2024-2034 us).
// DO NOT TOUCH: the compiled schedule is a knife-edge optimum; every probed
// perturbation (pass-split, 16-wave, gi prefetch, operand swap, bias-fold)
// regressed 17-75% (rounds 1-6, all code-real per round-7 reproduction).
__global__ __launch_bounds__(512,1) void k_gru_rec(
    const unsigned short* __restrict__ whh_c, const unsigned short* __restrict__ whh_q,
    const unsigned short* __restrict__ gi_c,  const unsigned short* __restrict__ gi_q,
    const float* __restrict__ bhh_c, const float* __restrict__ bhh_q,
    const float* __restrict__ h0_c,  const float* __restrict__ h0_q,
    float* __restrict__ c_out, float* __restrict__ q_hT)
{
  __shared__ unsigned short hb0[16*264];   // double-buffered h (row stride 264 u16)
  __shared__ unsigned short hb1[16*264];

  const int blk = blockIdx.x;
  const bool isq = blk >= 2;
  const int cls = isq? blk-2 : blk;        // block index within class (0/1)
  const int b0 = cls * 16;
  const unsigned short* W  = isq? whh_q : whh_c;
  const unsigned short* GI = isq? gi_q  : gi_c;
  const float* bhh = isq? bhh_q : bhh_c;
  const float* h0  = isq? h0_q  : h0_c;
  const int steps  = isq? 32 : 1024;

  const int tid = threadIdx.x;
  const int lane = tid & 63, wave = tid >> 6;
  const int cl = lane & 15, q4 = lane >> 4;

  // B-fragments: [gate][subtile][kfrag], col = g*256 + wave*32 + s*16 + cl
  bf16x8 Bf[3][2][8];
  #pragma unroll
  for(int g=0; g<3; g++)
    #pragma unroll
    for(int s=0; s<2; s++){
      const unsigned short* wrow = W + (size_t)(g*256 + wave*32 + s*16 + cl)*256;
      #pragma unroll
      for(int kf=0; kf<8; kf++)
        Bf[g][s][kf] = *(const bf16x8*)(wrow + kf*32 + q4*8);
    }

  // per-lane biases for owned cols
  float bR[2], bZ[2], bN[2];
  #pragma unroll
  for(int s=0; s<2; s++){
    const int col = wave*32 + s*16 + cl;
    bR[s] = bhh[col]; bZ[s] = bhh[256+col]; bN[s] = bhh[512+col];
  }

  // h in registers: lane owns (row=q4*4+r, col=wave*32+s*16+cl)
  float hreg[2][4];
  #pragma unroll
  for(int s=0; s<2; s++){
    const int col = wave*32 + s*16 + cl;
    #pragma unroll
    for(int r=0; r<4; r++){
      const int row = q4*4 + r;
      float v = h0[(size_t)(b0+row)*256 + col];
      hreg[s][r] = v;
      hb0[row*264 + col] = f2bf(v);
    }
  }
  __syncthreads();

  unsigned short* hb_rd = hb0;
  unsigned short* hb_wr = hb1;

  // per-lane gi base for this (blk, wave, lane)
  const unsigned short* gi_lane = GI + (((size_t)cls*8 + wave)*64 + lane)*24;
  const size_t gi_tstride = (size_t)2*8*64*24;   // per-t stride in u16

  for(int t=0; t<steps; t++){
    // gi(t): 3x dwordx4 (48 B contiguous per lane); consumed in phase B
    const unsigned short* gp = gi_lane + (size_t)t*gi_tstride;
    i32x4 G0 = *(const i32x4*)(gp);        // gate r : [s0r0..s0r3, s1r0..s1r3]
    i32x4 G1 = *(const i32x4*)(gp + 8);    // gate z
    i32x4 G2 = *(const i32x4*)(gp + 16);   // gate n

    // deferred c_out store of h(t-1): overlaps with MFMA phase
    if(!isq && t>0){
      #pragma unroll
      for(int s=0; s<2; s++){
        const int col = wave*32 + s*16 + cl;
        #pragma unroll
        for(int r=0; r<4; r++)
          c_out[((size_t)(b0+q4*4+r)*1024 + (t-1))*256 + col] = hreg[s][r];
      }
    }

    // phase A: gates = h @ W^T  (48 MFMAs/wave)
    f32x4 acc[3][2];
    #pragma unroll
    for(int g=0; g<3; g++)
      #pragma unroll
      for(int s=0; s<2; s++){ f32x4 z={0.f,0.f,0.f,0.f}; acc[g][s]=z; }
    #pragma unroll
    for(int kf=0; kf<8; kf++){
      bf16x8 a = *(const bf16x8*)&hb_rd[cl*264 + kf*32 + q4*8];
      #pragma unroll
      for(int g=0; g<3; g++)
        #pragma unroll
        for(int s=0; s<2; s++)
          acc[g][s] = __builtin_amdgcn_mfma_f32_16x16x32_bf16(a, Bf[g][s][kf], acc[g][s], 0,0,0);
    }

    // phase B: in-register GRU update (writes OTHER h buffer -> no barrier needed here)
    #pragma unroll
    for(int s=0; s<2; s++){
      const int col = wave*32 + s*16 + cl;
      #pragma unroll
      for(int r=0; r<4; r++){
        const int row = q4*4 + r;
        const int k = s*4 + r;
        float gir = bfsel(G0[k>>1], k&1);
        float giz = bfsel(G1[k>>1], k&1);
        float gin = bfsel(G2[k>>1], k&1);
        float rr = sigm_f(gir + acc[0][s][r] + bR[s]);
        float zz = sigm_f(giz + acc[1][s][r] + bZ[s]);
        float nn = tanh_f(gin + rr*(acc[2][s][r] + bN[s]));
        float x  = nn + zz*(hreg[s][r] - nn);
        hreg[s][r] = x;
        hb_wr[row*264 + col] = f2bf(x);
      }
    }
    __syncthreads();   // hb_wr complete -> next step's phase A may read it
    unsigned short* tmp = hb_rd; hb_rd = hb_wr; hb_wr = tmp;
  }

  // final stores from hreg
  #pragma unroll
  for(int s=0; s<2; s++){
    const int col = wave*32 + s*16 + cl;
    #pragma unroll
    for(int r=0; r<4; r++){
      const int row = q4*4 + r;
      if(!isq) c_out[((size_t)(b0+row)*1024 + (steps-1))*256 + col] = hreg[s][r];
      else     q_hT[(size_t)(b0+row)*256 + col] = hreg[s][r];
    }
  }
}

// ---------------- attention helpers ----------------
__global__ void k_gather(const float* __restrict__ c_out, const int* __restrict__ c_index,
                         float* __restrict__ c_sel, unsigned short* __restrict__ c_sel_bf){
  int row = blockIdx.x;                 // 0..4095 = b*128+s
  int b = row >> 7, s = row & 127;
  int idx = c_index[b*128 + s];
  float v = c_out[((size_t)b*1024 + idx)*256 + threadIdx.x];
  c_sel   [(size_t)row*256 + threadIdx.x] = v;
  c_sel_bf[(size_t)row*256 + threadIdx.x] = f2bf(v);
}

__global__ void k_feats(const float* __restrict__ c_sel, const float* __restrict__ cw,
                        const float* __restrict__ m_, const float* __restrict__ qh,
                        unsigned short* __restrict__ feats){
  int row = blockIdx.x, tid = threadIdx.x;
  int b = row >> 7;
  float cs  = c_sel[(size_t)row*256 + tid];
  float mj  = m_[b*256 + tid];
  float qj  = qh[b*256 + tid];
  float cwj = cw[(size_t)row*256 + tid];
  float dq = cwj*qj, dm = cwj*mj;
  #pragma unroll
  for(int o=32;o>0;o>>=1){ dq += __shfl_down(dq,o); dm += __shfl_down(dm,o); }
  __shared__ float rq[4], rm[4];
  int lane = tid&63, wave=tid>>6;
  if(lane==0){ rq[wave]=dq; rm[wave]=dm; }
  __syncthreads();
  unsigned short* fr = feats + (size_t)row*1824;
  fr[tid]      = f2bf(cs);
  fr[256+tid]  = f2bf(mj);
  fr[512+tid]  = f2bf(qj);
  fr[768+tid]  = f2bf(cs*qj);
  fr[1024+tid] = f2bf(cs*mj);
  fr[1280+tid] = f2bf(fabsf(cs-qj));
  fr[1536+tid] = f2bf(fabsf(cs-mj));
  if(tid==0){
    float DQ = rq[0]+rq[1]+rq[2]+rq[3];
    float DM = rm[0]+rm[1]+rm[2]+rm[3];
    fr[1792]=f2bf(DQ); fr[1793]=f2bf(DM);
  }
  if(tid<30) fr[1794+tid]=0;   // zero K-pad
}

// ---------------- fused episodic tail: scores + masked softmax + e + mem GRU cell ----
// One block per batch row (grid=32, block=256). Replaces k_scores + k_softmax_e +
// k_gru_cell(mem) and keeps scores/p/e in LDS. Per-output arithmetic order matches
// the kernels it replaces (scores dot is serial instead of shuffle-tree).
__global__ void k_att_tail(const float* __restrict__ h1, const float* __restrict__ w2,
                           const float* __restrict__ b2, const int* __restrict__ len_c,
                           const float* __restrict__ c_sel,
                           const float* __restrict__ m_in,
                           const float* __restrict__ wihT, const float* __restrict__ whhT,
                           const float* __restrict__ bih, const float* __restrict__ bhh,
                           float* __restrict__ out_att, float* __restrict__ m_out){
  __shared__ float red[256];
  __shared__ float p[128];
  __shared__ float es[256];
  __shared__ float hs[256];
  int b = blockIdx.x, tid = threadIdx.x;
  int L = len_c[b];
  // scores (rows tid<128): dot(h1[row,0:100], w2) + b2
  float s = -1e30f;
  if(tid < 128 && tid < L){
    const float* hr = h1 + ((size_t)b*128 + tid)*128;
    float a = 0.0f;
    for(int k=0;k<100;k++) a += hr[k]*w2[k];
    s = a + b2[0];
  }
  red[tid]=s; __syncthreads();
  for(int o=128;o>0;o>>=1){ if(tid<o) red[tid]=fmaxf(red[tid],red[tid+o]); __syncthreads(); }
  float mx = red[0]; __syncthreads();
  float ex = (tid<128 && tid<L)? __expf(s-mx) : 0.0f;
  red[tid]=ex; __syncthreads();
  for(int o=128;o>0;o>>=1){ if(tid<o) red[tid]+=red[tid+o]; __syncthreads(); }
  float inv = 1.0f/red[0];
  if(tid<128){ float pv = ex*inv; p[tid]=pv; out_att[b*128+tid]=pv; }
  hs[tid] = m_in[b*256+tid];
  __syncthreads();
  // e = sum_s p[s] * c_sel[b,s,:]
  float acc = 0.0f;
  for(int si=0; si<128; si++) acc += p[si]*c_sel[((size_t)b*128+si)*256 + tid];
  es[tid] = acc;
  __syncthreads();
  // mem GRU cell (identical order to the original k_gru_cell)
  float ar=0, az=0, an=0;
  for(int k=0;k<256;k++){
    float xv = es[k];
    const float* wr = wihT + (size_t)k*768;
    ar += xv*wr[tid]; az += xv*wr[256+tid]; an += xv*wr[512+tid];
  }
  float gr=0, gz=0, gn=0;
  for(int k=0;k<256;k++){
    float hv = hs[k];
    const float* wr = whhT + (size_t)k*768;
    gr += hv*wr[tid]; gz += hv*wr[256+tid]; gn += hv*wr[512+tid];
  }
  float rr = sigm_f(ar + bih[tid]     + gr + bhh[tid]);
  float zz = sigm_f(az + bih[256+tid] + gz + bhh[256+tid]);
  float nn = tanh_f(an + bih[512+tid] + rr*(gn + bhh[512+tid]));
  m_out[b*256+tid] = (1.0f-zz)*nn + zz*hs[tid];
}

// ---------------- fused answer step: logits + softmax (+ optional ans GRU cell) ----
// One block per batch row (grid=32, block=256). Replaces k_logits + k_softmax_o +
// k_gru_cell(ans); y stays in LDS. Accumulation orders identical to the originals.
__global__ void k_ans(const float* __restrict__ msq_in, const float* __restrict__ out_wT,
                      const float* __restrict__ out_b, const float* __restrict__ qh,
                      const float* __restrict__ wihT, const float* __restrict__ whhT,
                      const float* __restrict__ bih, const float* __restrict__ bhh,
                      int do_cell, float* __restrict__ y_out, float* __restrict__ msq_out){
  __shared__ float yl[2000];
  __shared__ float ms[256];
  __shared__ float qs[256];
  __shared__ float red[256];
  int b = blockIdx.x, tid = threadIdx.x;
  ms[tid] = msq_in[b*256+tid];
  qs[tid] = qh[b*256+tid];
  __syncthreads();
  // logits (same order as the original k_logits: serial k, bias first)
  for(int n=tid; n<2000; n+=256){
    float acc = out_b[n];
    for(int k=0;k<256;k++) acc += ms[k]*out_wT[(size_t)k*2000 + n];
    yl[n] = acc;
  }
  __syncthreads();
  // softmax over 2000 (same structure as the original k_softmax_o)
  float mx = -1e30f;
  for(int i=tid;i<2000;i+=256) mx = fmaxf(mx, yl[i]);
  red[tid]=mx; __syncthreads();
  for(int o=128;o>0;o>>=1){ if(tid<o) red[tid]=fmaxf(red[tid],red[tid+o]); __syncthreads(); }
  mx = red[0]; __syncthreads();
  float sum=0.0f;
  for(int i=tid;i<2000;i+=256) sum += __expf(yl[i]-mx);
  red[tid]=sum; __syncthreads();
  for(int o=128;o>0;o>>=1){ if(tid<o) red[tid]+=red[tid+o]; __syncthreads(); }
  float inv = 1.0f/red[0];
  // each yl[i] is read/written only by thread i%256 -> in-place safe
  for(int i=tid;i<2000;i+=256){
    float yv = __expf(yl[i]-mx)*inv;
    yl[i] = yv;
    if(y_out) y_out[(size_t)b*2000+i] = yv;
  }
  if(!do_cell) return;
  __syncthreads();
  // ans GRU cell: x = [y(2000) || qh(256)] (identical order to the original)
  float ar=0, az=0, an=0;
  for(int k=0;k<2000;k++){
    float xv = yl[k];
    const float* wr = wihT + (size_t)k*768;
    ar += xv*wr[tid]; az += xv*wr[256+tid]; an += xv*wr[512+tid];
  }
  for(int k=0;k<256;k++){
    float xv = qs[k];
    const float* wr = wihT + (size_t)(2000+k)*768;
    ar += xv*wr[tid]; az += xv*wr[256+tid]; an += xv*wr[512+tid];
  }
  float gr=0, gz=0, gn=0;
  for(int k=0;k<256;k++){
    float hv = ms[k];
    const float* wr = whhT + (size_t)k*768;
    gr += hv*wr[tid]; gz += hv*wr[256+tid]; gn += hv*wr[512+tid];
  }
  float rr = sigm_f(ar + bih[tid]     + gr + bhh[tid]);
  float zz = sigm_f(az + bih[256+tid] + gz + bhh[256+tid]);
  float nn = tanh_f(an + bih[512+tid] + rr*(gn + bhh[512+tid]));
  msq_out[b*256+tid] = (1.0f-zz)*nn + zz*ms[tid];
}

// ---------------- launch ----------------
extern "C" void kernel_launch(void* const* d_in, const int* in_sizes, int n_in,
                              void* d_out, int out_size, void* d_ws, size_t ws_size,
                              hipStream_t stream)
{
  const float* c        = (const float*)d_in[0];
  const float* q        = (const float*)d_in[1];
  const float* i_state  = (const float*)d_in[2];
  const float* q_state  = (const float*)d_in[3];
  const float* in_w_ih  = (const float*)d_in[4];
  const float* in_w_hh  = (const float*)d_in[5];
  const float* in_b_ih  = (const float*)d_in[6];
  const float* in_b_hh  = (const float*)d_in[7];
  const float* qe_w_ih  = (const float*)d_in[8];
  const float* qe_w_hh  = (const float*)d_in[9];
  const float* qe_b_ih  = (const float*)d_in[10];
  const float* qe_b_hh  = (const float*)d_in[11];
  const float* att_weight = (const float*)d_in[12];
  const float* att_w1   = (const float*)d_in[13];
  const float* att_b1   = (const float*)d_in[14];
  const float* att_w2   = (const float*)d_in[15];
  const float* att_b2   = (const float*)d_in[16];
  const float* mem_w_ih = (const float*)d_in[17];
  const float* mem_w_hh = (const float*)d_in[18];
  const float* mem_b_ih = (const float*)d_in[19];
  const float* mem_b_hh = (const float*)d_in[20];
  const float* out_w    = (const float*)d_in[21];
  const float* out_b    = (const float*)d_in[22];
  const float* ans_w_ih = (const float*)d_in[23];
  const float* ans_w_hh = (const float*)d_in[24];
  const float* ans_b_ih = (const float*)d_in[25];
  const float* ans_b_hh = (const float*)d_in[26];
  const int*   c_index  = (const int*)d_in[27];
  const int*   len_c    = (const int*)d_in[28];
  float* outp = (float*)d_out;   // [0,64000) y ; [64000,76288) att (3,32,128)

  char* wp = (char*)d_ws;
  auto take = [&](size_t nbytes)->char*{
    char* p = wp; wp += (nbytes + 255) & ~(size_t)255; return p;
  };
  unsigned short* c_bf      = (unsigned short*)take((size_t)32*1024*128*2);
  unsigned short* q_bf      = (unsigned short*)take((size_t)32*32*128*2);
  unsigned short* wih_in_bf = (unsigned short*)take(768*128*2);
  unsigned short* wih_qe_bf = (unsigned short*)take(768*128*2);
  unsigned short* whh_in_bf = (unsigned short*)take(768*256*2);
  unsigned short* whh_qe_bf = (unsigned short*)take(768*256*2);
  unsigned short* attwT_bf  = (unsigned short*)take(256*256*2);
  unsigned short* attw1_bf  = (unsigned short*)take(128*1824*2);
  float* b1pad              = (float*)take(128*4);
  float* out_wT             = (float*)take((size_t)256*2000*4);
  float* mem_wihT           = (float*)take(256*768*4);
  float* mem_whhT           = (float*)take(256*768*4);
  float* ans_wihT           = (float*)take((size_t)2256*768*4);
  float* ans_whhT           = (float*)take(256*768*4);
  unsigned short* gi_c_bf   = (unsigned short*)take((size_t)32768*768*2);  // lane-packed
  unsigned short* gi_q_bf   = (unsigned short*)take((size_t)1024*768*2);   // lane-packed
  float* c_out              = (float*)take((size_t)32*1024*256*4);
  float* q_hT               = (float*)take(32*256*4);
  float* c_sel              = (float*)take((size_t)4096*256*4);
  unsigned short* c_sel_bf  = (unsigned short*)take((size_t)4096*256*2);
  float* cw                 = (float*)take((size_t)4096*256*4);
  unsigned short* feats_bf  = (unsigned short*)take((size_t)4096*1824*2);
  float* h1                 = (float*)take((size_t)4096*128*4);
  float* m_buf              = (float*)take(32*256*4);
  float* msq                = (float*)take(32*256*4);

  // ---- prep / conversions: big c conversion + ONE fused prep launch ----
  k_f2bf<<<16384,256,0,stream>>>(c, c_bf, 32*1024*128);
  k_prep<<<15057,256,0,stream>>>(q, q_bf,
                                 in_w_ih, wih_in_bf, qe_w_ih, wih_qe_bf,
                                 in_w_hh, whh_in_bf, qe_w_hh, whh_qe_bf,
                                 att_weight, attwT_bf, att_w1, attw1_bf,
                                 att_b1, b1pad,
                                 out_w, out_wT,
                                 mem_w_ih, mem_wihT, mem_w_hh, mem_whhT,
                                 ans_w_ih, ans_wihT, ans_w_hh, ans_whhT);

  // ---- time-parallel input projections with lane-packed scatter ----
  k_gemm_gi<<<dim3(512,12),256,0,stream>>>(c_bf, wih_in_bf, in_b_ih, gi_c_bf, 10);
  k_gemm_gi<<<dim3(16,12),256,0,stream>>>(q_bf, wih_qe_bf, qe_b_ih, gi_q_bf, 5);

  // ---- sequential GRU recurrences (context 1024 steps + query 32 steps) ----
  k_gru_rec<<<4,512,0,stream>>>(whh_in_bf, whh_qe_bf, gi_c_bf, gi_q_bf,
                                in_b_hh, qe_b_hh, i_state, q_state, c_out, q_hT);

  // ---- attention setup ----
  k_gather<<<4096,256,0,stream>>>(c_out, c_index, c_sel, c_sel_bf);
  k_gemm_bf16<<<dim3(64,4),256,0,stream>>>(c_sel_bf, attwT_bf, 256, nullptr, 0, cw, nullptr, 256);

  // ---- 3 episodic memory iterations (m starts as q_hT; fused tail) ----
  for(int it=0; it<3; it++){
    const float* m_cur = (it==0)? q_hT : m_buf;
    k_feats<<<4096,256,0,stream>>>(c_sel, cw, m_cur, q_hT, feats_bf);
    k_gemm_bf16<<<dim3(64,2),256,0,stream>>>(feats_bf, attw1_bf, 1824, b1pad, 1, h1, nullptr, 128);
    k_att_tail<<<32,256,0,stream>>>(h1, att_w2, att_b2, len_c, c_sel, m_cur,
                                    mem_wihT, mem_whhT, mem_b_ih, mem_b_hh,
                                    outp + 64000 + it*4096, m_buf);
  }

  // ---- answer module (fused logits+softmax+cell) ----
  k_ans<<<32,256,0,stream>>>(m_buf, out_wT, out_b, q_hT,
                             ans_wihT, ans_whhT, ans_b_ih, ans_b_hh,
                             1, nullptr, msq);
  k_ans<<<32,256,0,stream>>>(msq, out_wT, out_b, q_hT,
                             ans_wihT, ans_whhT, ans_b_ih, ans_b_hh,
                             1, nullptr, msq);
  k_ans<<<32,256,0,stream>>>(msq, out_wT, out_b, q_hT,
                             ans_wihT, ans_whhT, ans_b_ih, ans_b_hh,
                             0, outp, nullptr);
}

// Round 10
// 2922.470 us; speedup vs baseline: 1.6033x; 1.0004x over previous
//
#include <hip/hip_runtime.h>
#include <cstdint>
#include <cstddef>

typedef short bf16x8 __attribute__((ext_vector_type(8)));
typedef float f32x4 __attribute__((ext_vector_type(4)));
typedef int   i32x4 __attribute__((ext_vector_type(4)));

#define DEV static __device__ __forceinline__

DEV unsigned short f2bf(float x){
  union{float f; unsigned int u;} v; v.f = x;
  unsigned int r = (v.u + 0x7FFFu + ((v.u>>16)&1u)) >> 16;
  return (unsigned short)r;
}
DEV float bf2f(unsigned short h){
  union{unsigned int u; float f;} v; v.u = ((unsigned int)h)<<16;
  return v.f;
}
// unpack bf16 half of a dword: hi=0 -> low u16, hi=1 -> high u16
DEV float bfsel(int dw, int hi){
  union{unsigned int u; float f;} v;
  v.u = hi ? ((unsigned int)dw & 0xFFFF0000u) : ((unsigned int)dw << 16);
  return v.f;
}
// fast gates: v_exp_f32 + v_rcp_f32
DEV float sigm_f(float x){ return __builtin_amdgcn_rcpf(1.0f + __expf(-x)); }
DEV float tanh_f(float x){ return 2.0f*__builtin_amdgcn_rcpf(1.0f + __expf(-2.0f*x)) - 1.0f; }

// ---------------- fused prep: big c conversion + all small conversions/transposes ----
// ONE launch, dispatched by blockIdx range. Each branch reproduces the original
// kernel's exact indexing/arithmetic (launch-overhead reduction only).
// Block budget: c(16384) q(512) wih_in(384) wih_qe(384) whh_in(768) whh_qe(768)
// attwT(256) attw1(912) b1pad(1) T_out_w(2000) T_mem_ih(768) T_mem_hh(768)
// T_ans_ih(6768) T_ans_hh(768)  => total 31441 blocks of 256.
__global__ void k_prep_all(
    const float* __restrict__ c,        unsigned short* __restrict__ c_bf,
    const float* __restrict__ q,        unsigned short* __restrict__ q_bf,
    const float* __restrict__ in_w_ih,  unsigned short* __restrict__ wih_in_bf,
    const float* __restrict__ qe_w_ih,  unsigned short* __restrict__ wih_qe_bf,
    const float* __restrict__ in_w_hh,  unsigned short* __restrict__ whh_in_bf,
    const float* __restrict__ qe_w_hh,  unsigned short* __restrict__ whh_qe_bf,
    const float* __restrict__ att_weight, unsigned short* __restrict__ attwT_bf,
    const float* __restrict__ att_w1,   unsigned short* __restrict__ attw1_bf,
    const float* __restrict__ att_b1,   float* __restrict__ b1pad,
    const float* __restrict__ out_w,    float* __restrict__ out_wT,
    const float* __restrict__ mem_w_ih, float* __restrict__ mem_wihT,
    const float* __restrict__ mem_w_hh, float* __restrict__ mem_whhT,
    const float* __restrict__ ans_w_ih, float* __restrict__ ans_wihT,
    const float* __restrict__ ans_w_hh, float* __restrict__ ans_whhT)
{
  int bid = blockIdx.x;
  const int tid = threadIdx.x;
  // f2bf c : 32*1024*128
  if(bid < 16384){ int i = bid*256 + tid; if(i < 4194304) c_bf[i] = f2bf(c[i]); return; }
  bid -= 16384;
  // f2bf q : 32*32*128
  if(bid < 512){ int i = bid*256 + tid; if(i < 131072) q_bf[i] = f2bf(q[i]); return; }
  bid -= 512;
  // f2bf in_w_ih : 768*128
  if(bid < 384){ int i = bid*256 + tid; if(i < 98304) wih_in_bf[i] = f2bf(in_w_ih[i]); return; }
  bid -= 384;
  // f2bf qe_w_ih : 768*128
  if(bid < 384){ int i = bid*256 + tid; if(i < 98304) wih_qe_bf[i] = f2bf(qe_w_ih[i]); return; }
  bid -= 384;
  // f2bf in_w_hh : 768*256
  if(bid < 768){ int i = bid*256 + tid; if(i < 196608) whh_in_bf[i] = f2bf(in_w_hh[i]); return; }
  bid -= 768;
  // f2bf qe_w_hh : 768*256
  if(bid < 768){ int i = bid*256 + tid; if(i < 196608) whh_qe_bf[i] = f2bf(qe_w_hh[i]); return; }
  bid -= 768;
  // attwT : out[n*256+k] = aw[k*256+n]
  if(bid < 256){ int i = bid*256 + tid; if(i < 65536){ int n = i>>8, k = i&255; attwT_bf[i] = f2bf(att_weight[k*256 + n]); } return; }
  bid -= 256;
  // attw1 : 128*1824 padded
  if(bid < 912){
    int i = bid*256 + tid;
    if(i < 128*1824){
      int r = i/1824, cc = i - r*1824;
      float v = (r<100 && cc<1794)? att_w1[r*1794 + cc] : 0.0f;
      attw1_bf[i] = f2bf(v);
    }
    return;
  }
  bid -= 912;
  // b1pad
  if(bid < 1){ if(tid < 128) b1pad[tid] = (tid<100)? att_b1[tid] : 0.0f; return; }
  bid -= 1;
  // transpose out_w (2000,256)
  if(bid < 2000){ int i = bid*256 + tid; if(i < 2000*256){ int r = i/256, cc = i - r*256; out_wT[(size_t)cc*2000 + r] = out_w[i]; } return; }
  bid -= 2000;
  // transpose mem_w_ih (768,256)
  if(bid < 768){ int i = bid*256 + tid; if(i < 768*256){ int r = i/256, cc = i - r*256; mem_wihT[(size_t)cc*768 + r] = mem_w_ih[i]; } return; }
  bid -= 768;
  // transpose mem_w_hh (768,256)
  if(bid < 768){ int i = bid*256 + tid; if(i < 768*256){ int r = i/256, cc = i - r*256; mem_whhT[(size_t)cc*768 + r] = mem_w_hh[i]; } return; }
  bid -= 768;
  // transpose ans_w_ih (768,2256)
  if(bid < 6768){ int i = bid*256 + tid; if(i < 768*2256){ int r = i/2256, cc = i - r*2256; ans_wihT[(size_t)cc*768 + r] = ans_w_ih[i]; } return; }
  bid -= 6768;
  // transpose ans_w_hh (768,256)
  if(bid < 768){ int i = bid*256 + tid; if(i < 768*256){ int r = i/256, cc = i - r*256; ans_whhT[(size_t)cc*768 + r] = ans_w_hh[i]; } return; }
}

// ---------------- generic bf16 MFMA GEMM: C(M,N) = A(M,K) @ Bt(N,K)^T ----------------
__global__ __launch_bounds__(256) void k_gemm_bf16(
    const unsigned short* __restrict__ A, const unsigned short* __restrict__ Bt,
    int K, const float* __restrict__ bias, int act,
    float* __restrict__ outf, unsigned short* __restrict__ outbf, int ldc)
{
  int lane = threadIdx.x & 63, wave = threadIdx.x >> 6;
  int m_base = blockIdx.x*64 + (wave>>1)*32;
  int n_base = blockIdx.y*64 + (wave&1)*32;
  int cl = lane & 15, q4 = lane >> 4;
  f32x4 acc00={0.f,0.f,0.f,0.f}, acc01=acc00, acc10=acc00, acc11=acc00;
  const int kf_n = K >> 5;
  for(int kf=0; kf<kf_n; kf++){
    int ko = kf*32 + q4*8;
    bf16x8 a0 = *(const bf16x8*)(A + (size_t)(m_base+cl)*K + ko);
    bf16x8 a1 = *(const bf16x8*)(A + (size_t)(m_base+16+cl)*K + ko);
    bf16x8 b0 = *(const bf16x8*)(Bt + (size_t)(n_base+cl)*K + ko);
    bf16x8 b1 = *(const bf16x8*)(Bt + (size_t)(n_base+16+cl)*K + ko);
    acc00 = __builtin_amdgcn_mfma_f32_16x16x32_bf16(a0,b0,acc00,0,0,0);
    acc01 = __builtin_amdgcn_mfma_f32_16x16x32_bf16(a0,b1,acc01,0,0,0);
    acc10 = __builtin_amdgcn_mfma_f32_16x16x32_bf16(a1,b0,acc10,0,0,0);
    acc11 = __builtin_amdgcn_mfma_f32_16x16x32_bf16(a1,b1,acc11,0,0,0);
  }
  #pragma unroll
  for(int mt=0; mt<2; mt++){
    #pragma unroll
    for(int nt=0; nt<2; nt++){
      f32x4 av = (mt==0)? (nt==0?acc00:acc01) : (nt==0?acc10:acc11);
      int col = n_base + nt*16 + cl;
      float bv = bias? bias[col] : 0.0f;
      #pragma unroll
      for(int r=0;r<4;r++){
        int row = m_base + mt*16 + q4*4 + r;
        float v = av[r] + bv;
        if(act) v = tanh_f(v);
        if(outbf) outbf[(size_t)row*ldc + col] = f2bf(v);
        else      outf [(size_t)row*ldc + col] = v;
      }
    }
  }
}

// ---------------- gi GEMM with lane-packed scatter epilogue (c and q in ONE launch) ----
// Computes gi = x @ w_ih^T + b_ih and scatters each recurrence-lane's 24 values
// contiguous: idx = ((((t*2 + blk)*8 + w)*64 + lane)*24 + g*8 + s*4 + r.
// A rows are b*steps + t (steps = 1<<ss). N = 768.
// Grid (528,12): x<512 -> context problem (ss=10), else query problem (ss=5).
// Inner body identical to the previous k_gemm_gi.
__global__ __launch_bounds__(256) void k_gemm_gi2(
    const unsigned short* __restrict__ Ac, const unsigned short* __restrict__ Btc,
    const float* __restrict__ biasc, unsigned short* __restrict__ outc,
    const unsigned short* __restrict__ Aq, const unsigned short* __restrict__ Btq,
    const float* __restrict__ biasq, unsigned short* __restrict__ outq)
{
  int bx = blockIdx.x;
  const unsigned short* A; const unsigned short* Bt; const float* bias;
  unsigned short* gi_out; int ss; int mblk;
  if(bx < 512){ A = Ac; Bt = Btc; bias = biasc; gi_out = outc; ss = 10; mblk = bx; }
  else        { A = Aq; Bt = Btq; bias = biasq; gi_out = outq; ss = 5;  mblk = bx - 512; }

  int lane = threadIdx.x & 63, wave = threadIdx.x >> 6;
  int m_base = mblk*64 + (wave>>1)*32;
  int n_base = blockIdx.y*64 + (wave&1)*32;
  int cl = lane & 15, q4 = lane >> 4;
  f32x4 acc00={0.f,0.f,0.f,0.f}, acc01=acc00, acc10=acc00, acc11=acc00;
  for(int kf=0; kf<4; kf++){   // K = 128
    int ko = kf*32 + q4*8;
    bf16x8 a0 = *(const bf16x8*)(A + (size_t)(m_base+cl)*128 + ko);
    bf16x8 a1 = *(const bf16x8*)(A + (size_t)(m_base+16+cl)*128 + ko);
    bf16x8 b0 = *(const bf16x8*)(Bt + (size_t)(n_base+cl)*128 + ko);
    bf16x8 b1 = *(const bf16x8*)(Bt + (size_t)(n_base+16+cl)*128 + ko);
    acc00 = __builtin_amdgcn_mfma_f32_16x16x32_bf16(a0,b0,acc00,0,0,0);
    acc01 = __builtin_amdgcn_mfma_f32_16x16x32_bf16(a0,b1,acc01,0,0,0);
    acc10 = __builtin_amdgcn_mfma_f32_16x16x32_bf16(a1,b0,acc10,0,0,0);
    acc11 = __builtin_amdgcn_mfma_f32_16x16x32_bf16(a1,b1,acc11,0,0,0);
  }
  const int tmask = (1<<ss) - 1;
  #pragma unroll
  for(int mt=0; mt<2; mt++){
    #pragma unroll
    for(int nt=0; nt<2; nt++){
      f32x4 av = (mt==0)? (nt==0?acc00:acc01) : (nt==0?acc10:acc11);
      int col = n_base + nt*16 + cl;
      float bv = bias[col];
      int g = col >> 8, rem = col & 255;
      int w = rem >> 5, s = (rem>>4)&1, cl2 = rem & 15;
      #pragma unroll
      for(int r=0;r<4;r++){
        int arow = m_base + mt*16 + q4*4 + r;
        int t = arow & tmask, b = arow >> ss;
        int blk = b >> 4, brow = b & 15;
        int lane2 = (brow>>2)*16 + cl2, rc = brow & 3;
        size_t idx = ((((size_t)t*2 + blk)*8 + w)*64 + lane2)*24 + g*8 + s*4 + rc;
        gi_out[idx] = f2bf(av[r] + bv);
      }
    }
  }
}

// ---------------- GRU recurrence ----------------
// BYTE-IDENTICAL to the verified best (rounds 0/7/8/9: 2020-2034 us).
// DO NOT TOUCH: the compiled schedule is a knife-edge optimum; every probed
// perturbation (pass-split, 16-wave, gi prefetch, operand swap, bias-fold)
// regressed 17-75% (rounds 1-6, all code-real per round-7 reproduction).
__global__ __launch_bounds__(512,1) void k_gru_rec(
    const unsigned short* __restrict__ whh_c, const unsigned short* __restrict__ whh_q,
    const unsigned short* __restrict__ gi_c,  const unsigned short* __restrict__ gi_q,
    const float* __restrict__ bhh_c, const float* __restrict__ bhh_q,
    const float* __restrict__ h0_c,  const float* __restrict__ h0_q,
    float* __restrict__ c_out, float* __restrict__ q_hT)
{
  __shared__ unsigned short hb0[16*264];   // double-buffered h (row stride 264 u16)
  __shared__ unsigned short hb1[16*264];

  const int blk = blockIdx.x;
  const bool isq = blk >= 2;
  const int cls = isq? blk-2 : blk;        // block index within class (0/1)
  const int b0 = cls * 16;
  const unsigned short* W  = isq? whh_q : whh_c;
  const unsigned short* GI = isq? gi_q  : gi_c;
  const float* bhh = isq? bhh_q : bhh_c;
  const float* h0  = isq? h0_q  : h0_c;
  const int steps  = isq? 32 : 1024;

  const int tid = threadIdx.x;
  const int lane = tid & 63, wave = tid >> 6;
  const int cl = lane & 15, q4 = lane >> 4;

  // B-fragments: [gate][subtile][kfrag], col = g*256 + wave*32 + s*16 + cl
  bf16x8 Bf[3][2][8];
  #pragma unroll
  for(int g=0; g<3; g++)
    #pragma unroll
    for(int s=0; s<2; s++){
      const unsigned short* wrow = W + (size_t)(g*256 + wave*32 + s*16 + cl)*256;
      #pragma unroll
      for(int kf=0; kf<8; kf++)
        Bf[g][s][kf] = *(const bf16x8*)(wrow + kf*32 + q4*8);
    }

  // per-lane biases for owned cols
  float bR[2], bZ[2], bN[2];
  #pragma unroll
  for(int s=0; s<2; s++){
    const int col = wave*32 + s*16 + cl;
    bR[s] = bhh[col]; bZ[s] = bhh[256+col]; bN[s] = bhh[512+col];
  }

  // h in registers: lane owns (row=q4*4+r, col=wave*32+s*16+cl)
  float hreg[2][4];
  #pragma unroll
  for(int s=0; s<2; s++){
    const int col = wave*32 + s*16 + cl;
    #pragma unroll
    for(int r=0; r<4; r++){
      const int row = q4*4 + r;
      float v = h0[(size_t)(b0+row)*256 + col];
      hreg[s][r] = v;
      hb0[row*264 + col] = f2bf(v);
    }
  }
  __syncthreads();

  unsigned short* hb_rd = hb0;
  unsigned short* hb_wr = hb1;

  // per-lane gi base for this (blk, wave, lane)
  const unsigned short* gi_lane = GI + (((size_t)cls*8 + wave)*64 + lane)*24;
  const size_t gi_tstride = (size_t)2*8*64*24;   // per-t stride in u16

  for(int t=0; t<steps; t++){
    // gi(t): 3x dwordx4 (48 B contiguous per lane); consumed in phase B
    const unsigned short* gp = gi_lane + (size_t)t*gi_tstride;
    i32x4 G0 = *(const i32x4*)(gp);        // gate r : [s0r0..s0r3, s1r0..s1r3]
    i32x4 G1 = *(const i32x4*)(gp + 8);    // gate z
    i32x4 G2 = *(const i32x4*)(gp + 16);   // gate n

    // deferred c_out store of h(t-1): overlaps with MFMA phase
    if(!isq && t>0){
      #pragma unroll
      for(int s=0; s<2; s++){
        const int col = wave*32 + s*16 + cl;
        #pragma unroll
        for(int r=0; r<4; r++)
          c_out[((size_t)(b0+q4*4+r)*1024 + (t-1))*256 + col] = hreg[s][r];
      }
    }

    // phase A: gates = h @ W^T  (48 MFMAs/wave)
    f32x4 acc[3][2];
    #pragma unroll
    for(int g=0; g<3; g++)
      #pragma unroll
      for(int s=0; s<2; s++){ f32x4 z={0.f,0.f,0.f,0.f}; acc[g][s]=z; }
    #pragma unroll
    for(int kf=0; kf<8; kf++){
      bf16x8 a = *(const bf16x8*)&hb_rd[cl*264 + kf*32 + q4*8];
      #pragma unroll
      for(int g=0; g<3; g++)
        #pragma unroll
        for(int s=0; s<2; s++)
          acc[g][s] = __builtin_amdgcn_mfma_f32_16x16x32_bf16(a, Bf[g][s][kf], acc[g][s], 0,0,0);
    }

    // phase B: in-register GRU update (writes OTHER h buffer -> no barrier needed here)
    #pragma unroll
    for(int s=0; s<2; s++){
      const int col = wave*32 + s*16 + cl;
      #pragma unroll
      for(int r=0; r<4; r++){
        const int row = q4*4 + r;
        const int k = s*4 + r;
        float gir = bfsel(G0[k>>1], k&1);
        float giz = bfsel(G1[k>>1], k&1);
        float gin = bfsel(G2[k>>1], k&1);
        float rr = sigm_f(gir + acc[0][s][r] + bR[s]);
        float zz = sigm_f(giz + acc[1][s][r] + bZ[s]);
        float nn = tanh_f(gin + rr*(acc[2][s][r] + bN[s]));
        float x  = nn + zz*(hreg[s][r] - nn);
        hreg[s][r] = x;
        hb_wr[row*264 + col] = f2bf(x);
      }
    }
    __syncthreads();   // hb_wr complete -> next step's phase A may read it
    unsigned short* tmp = hb_rd; hb_rd = hb_wr; hb_wr = tmp;
  }

  // final stores from hreg
  #pragma unroll
  for(int s=0; s<2; s++){
    const int col = wave*32 + s*16 + cl;
    #pragma unroll
    for(int r=0; r<4; r++){
      const int row = q4*4 + r;
      if(!isq) c_out[((size_t)(b0+row)*1024 + (steps-1))*256 + col] = hreg[s][r];
      else     q_hT[(size_t)(b0+row)*256 + col] = hreg[s][r];
    }
  }
}

// ---------------- attention helpers ----------------
__global__ void k_gather(const float* __restrict__ c_out, const int* __restrict__ c_index,
                         float* __restrict__ c_sel, unsigned short* __restrict__ c_sel_bf){
  int row = blockIdx.x;                 // 0..4095 = b*128+s
  int b = row >> 7, s = row & 127;
  int idx = c_index[b*128 + s];
  float v = c_out[((size_t)b*1024 + idx)*256 + threadIdx.x];
  c_sel   [(size_t)row*256 + threadIdx.x] = v;
  c_sel_bf[(size_t)row*256 + threadIdx.x] = f2bf(v);
}

__global__ void k_feats(const float* __restrict__ c_sel, const float* __restrict__ cw,
                        const float* __restrict__ m_, const float* __restrict__ qh,
                        unsigned short* __restrict__ feats){
  int row = blockIdx.x, tid = threadIdx.x;
  int b = row >> 7;
  float cs  = c_sel[(size_t)row*256 + tid];
  float mj  = m_[b*256 + tid];
  float qj  = qh[b*256 + tid];
  float cwj = cw[(size_t)row*256 + tid];
  float dq = cwj*qj, dm = cwj*mj;
  #pragma unroll
  for(int o=32;o>0;o>>=1){ dq += __shfl_down(dq,o); dm += __shfl_down(dm,o); }
  __shared__ float rq[4], rm[4];
  int lane = tid&63, wave=tid>>6;
  if(lane==0){ rq[wave]=dq; rm[wave]=dm; }
  __syncthreads();
  unsigned short* fr = feats + (size_t)row*1824;
  fr[tid]      = f2bf(cs);
  fr[256+tid]  = f2bf(mj);
  fr[512+tid]  = f2bf(qj);
  fr[768+tid]  = f2bf(cs*qj);
  fr[1024+tid] = f2bf(cs*mj);
  fr[1280+tid] = f2bf(fabsf(cs-qj));
  fr[1536+tid] = f2bf(fabsf(cs-mj));
  if(tid==0){
    float DQ = rq[0]+rq[1]+rq[2]+rq[3];
    float DM = rm[0]+rm[1]+rm[2]+rm[3];
    fr[1792]=f2bf(DQ); fr[1793]=f2bf(DM);
  }
  if(tid<30) fr[1794+tid]=0;   // zero K-pad
}

// ---------------- fused episodic tail: scores + masked softmax + e + mem GRU cell ----
// One block per batch row (grid=32, block=256). Keeps scores/p/e in LDS.
// Per-output arithmetic order matches the kernels it replaced.
__global__ void k_att_tail(const float* __restrict__ h1, const float* __restrict__ w2,
                           const float* __restrict__ b2, const int* __restrict__ len_c,
                           const float* __restrict__ c_sel,
                           const float* __restrict__ m_in,
                           const float* __restrict__ wihT, const float* __restrict__ whhT,
                           const float* __restrict__ bih, const float* __restrict__ bhh,
                           float* __restrict__ out_att, float* __restrict__ m_out){
  __shared__ float red[256];
  __shared__ float p[128];
  __shared__ float es[256];
  __shared__ float hs[256];
  int b = blockIdx.x, tid = threadIdx.x;
  int L = len_c[b];
  // scores (rows tid<128): dot(h1[row,0:100], w2) + b2
  float s = -1e30f;
  if(tid < 128 && tid < L){
    const float* hr = h1 + ((size_t)b*128 + tid)*128;
    float a = 0.0f;
    for(int k=0;k<100;k++) a += hr[k]*w2[k];
    s = a + b2[0];
  }
  red[tid]=s; __syncthreads();
  for(int o=128;o>0;o>>=1){ if(tid<o) red[tid]=fmaxf(red[tid],red[tid+o]); __syncthreads(); }
  float mx = red[0]; __syncthreads();
  float ex = (tid<128 && tid<L)? __expf(s-mx) : 0.0f;
  red[tid]=ex; __syncthreads();
  for(int o=128;o>0;o>>=1){ if(tid<o) red[tid]+=red[tid+o]; __syncthreads(); }
  float inv = 1.0f/red[0];
  if(tid<128){ float pv = ex*inv; p[tid]=pv; out_att[b*128+tid]=pv; }
  hs[tid] = m_in[b*256+tid];
  __syncthreads();
  // e = sum_s p[s] * c_sel[b,s,:]
  float acc = 0.0f;
  for(int si=0; si<128; si++) acc += p[si]*c_sel[((size_t)b*128+si)*256 + tid];
  es[tid] = acc;
  __syncthreads();
  // mem GRU cell (identical order to the original k_gru_cell)
  float ar=0, az=0, an=0;
  for(int k=0;k<256;k++){
    float xv = es[k];
    const float* wr = wihT + (size_t)k*768;
    ar += xv*wr[tid]; az += xv*wr[256+tid]; an += xv*wr[512+tid];
  }
  float gr=0, gz=0, gn=0;
  for(int k=0;k<256;k++){
    float hv = hs[k];
    const float* wr = whhT + (size_t)k*768;
    gr += hv*wr[tid]; gz += hv*wr[256+tid]; gn += hv*wr[512+tid];
  }
  float rr = sigm_f(ar + bih[tid]     + gr + bhh[tid]);
  float zz = sigm_f(az + bih[256+tid] + gz + bhh[256+tid]);
  float nn = tanh_f(an + bih[512+tid] + rr*(gn + bhh[512+tid]));
  m_out[b*256+tid] = (1.0f-zz)*nn + zz*hs[tid];
}

// ---------------- fused answer step: logits + softmax (+ optional ans GRU cell) ----
// One block per batch row (grid=32, block=256); y stays in LDS.
// Accumulation orders identical to the originals.
__global__ void k_ans(const float* __restrict__ msq_in, const float* __restrict__ out_wT,
                      const float* __restrict__ out_b, const float* __restrict__ qh,
                      const float* __restrict__ wihT, const float* __restrict__ whhT,
                      const float* __restrict__ bih, const float* __restrict__ bhh,
                      int do_cell, float* __restrict__ y_out, float* __restrict__ msq_out){
  __shared__ float yl[2000];
  __shared__ float ms[256];
  __shared__ float qs[256];
  __shared__ float red[256];
  int b = blockIdx.x, tid = threadIdx.x;
  ms[tid] = msq_in[b*256+tid];
  qs[tid] = qh[b*256+tid];
  __syncthreads();
  // logits (serial k, bias first)
  for(int n=tid; n<2000; n+=256){
    float acc = out_b[n];
    for(int k=0;k<256;k++) acc += ms[k]*out_wT[(size_t)k*2000 + n];
    yl[n] = acc;
  }
  __syncthreads();
  // softmax over 2000
  float mx = -1e30f;
  for(int i=tid;i<2000;i+=256) mx = fmaxf(mx, yl[i]);
  red[tid]=mx; __syncthreads();
  for(int o=128;o>0;o>>=1){ if(tid<o) red[tid]=fmaxf(red[tid],red[tid+o]); __syncthreads(); }
  mx = red[0]; __syncthreads();
  float sum=0.0f;
  for(int i=tid;i<2000;i+=256) sum += __expf(yl[i]-mx);
  red[tid]=sum; __syncthreads();
  for(int o=128;o>0;o>>=1){ if(tid<o) red[tid]+=red[tid+o]; __syncthreads(); }
  float inv = 1.0f/red[0];
  // each yl[i] is read/written only by thread i%256 -> in-place safe
  for(int i=tid;i<2000;i+=256){
    float yv = __expf(yl[i]-mx)*inv;
    yl[i] = yv;
    if(y_out) y_out[(size_t)b*2000+i] = yv;
  }
  if(!do_cell) return;
  __syncthreads();
  // ans GRU cell: x = [y(2000) || qh(256)] (identical order to the original)
  float ar=0, az=0, an=0;
  for(int k=0;k<2000;k++){
    float xv = yl[k];
    const float* wr = wihT + (size_t)k*768;
    ar += xv*wr[tid]; az += xv*wr[256+tid]; an += xv*wr[512+tid];
  }
  for(int k=0;k<256;k++){
    float xv = qs[k];
    const float* wr = wihT + (size_t)(2000+k)*768;
    ar += xv*wr[tid]; az += xv*wr[256+tid]; an += xv*wr[512+tid];
  }
  float gr=0, gz=0, gn=0;
  for(int k=0;k<256;k++){
    float hv = ms[k];
    const float* wr = whhT + (size_t)k*768;
    gr += hv*wr[tid]; gz += hv*wr[256+tid]; gn += hv*wr[512+tid];
  }
  float rr = sigm_f(ar + bih[tid]     + gr + bhh[tid]);
  float zz = sigm_f(az + bih[256+tid] + gz + bhh[256+tid]);
  float nn = tanh_f(an + bih[512+tid] + rr*(gn + bhh[512+tid]));
  msq_out[b*256+tid] = (1.0f-zz)*nn + zz*ms[tid];
}

// ---------------- launch ----------------
extern "C" void kernel_launch(void* const* d_in, const int* in_sizes, int n_in,
                              void* d_out, int out_size, void* d_ws, size_t ws_size,
                              hipStream_t stream)
{
  const float* c        = (const float*)d_in[0];
  const float* q        = (const float*)d_in[1];
  const float* i_state  = (const float*)d_in[2];
  const float* q_state  = (const float*)d_in[3];
  const float* in_w_ih  = (const float*)d_in[4];
  const float* in_w_hh  = (const float*)d_in[5];
  const float* in_b_ih  = (const float*)d_in[6];
  const float* in_b_hh  = (const float*)d_in[7];
  const float* qe_w_ih  = (const float*)d_in[8];
  const float* qe_w_hh  = (const float*)d_in[9];
  const float* qe_b_ih  = (const float*)d_in[10];
  const float* qe_b_hh  = (const float*)d_in[11];
  const float* att_weight = (const float*)d_in[12];
  const float* att_w1   = (const float*)d_in[13];
  const float* att_b1   = (const float*)d_in[14];
  const float* att_w2   = (const float*)d_in[15];
  const float* att_b2   = (const float*)d_in[16];
  const float* mem_w_ih = (const float*)d_in[17];
  const float* mem_w_hh = (const float*)d_in[18];
  const float* mem_b_ih = (const float*)d_in[19];
  const float* mem_b_hh = (const float*)d_in[20];
  const float* out_w    = (const float*)d_in[21];
  const float* out_b    = (const float*)d_in[22];
  const float* ans_w_ih = (const float*)d_in[23];
  const float* ans_w_hh = (const float*)d_in[24];
  const float* ans_b_ih = (const float*)d_in[25];
  const float* ans_b_hh = (const float*)d_in[26];
  const int*   c_index  = (const int*)d_in[27];
  const int*   len_c    = (const int*)d_in[28];
  float* outp = (float*)d_out;   // [0,64000) y ; [64000,76288) att (3,32,128)

  char* wp = (char*)d_ws;
  auto take = [&](size_t nbytes)->char*{
    char* p = wp; wp += (nbytes + 255) & ~(size_t)255; return p;
  };
  unsigned short* c_bf      = (unsigned short*)take((size_t)32*1024*128*2);
  unsigned short* q_bf      = (unsigned short*)take((size_t)32*32*128*2);
  unsigned short* wih_in_bf = (unsigned short*)take(768*128*2);
  unsigned short* wih_qe_bf = (unsigned short*)take(768*128*2);
  unsigned short* whh_in_bf = (unsigned short*)take(768*256*2);
  unsigned short* whh_qe_bf = (unsigned short*)take(768*256*2);
  unsigned short* attwT_bf  = (unsigned short*)take(256*256*2);
  unsigned short* attw1_bf  = (unsigned short*)take(128*1824*2);
  float* b1pad              = (float*)take(128*4);
  float* out_wT             = (float*)take((size_t)256*2000*4);
  float* mem_wihT           = (float*)take(256*768*4);
  float* mem_whhT           = (float*)take(256*768*4);
  float* ans_wihT           = (float*)take((size_t)2256*768*4);
  float* ans_whhT           = (float*)take(256*768*4);
  unsigned short* gi_c_bf   = (unsigned short*)take((size_t)32768*768*2);  // lane-packed
  unsigned short* gi_q_bf   = (unsigned short*)take((size_t)1024*768*2);   // lane-packed
  float* c_out              = (float*)take((size_t)32*1024*256*4);
  float* q_hT               = (float*)take(32*256*4);
  float* c_sel              = (float*)take((size_t)4096*256*4);
  unsigned short* c_sel_bf  = (unsigned short*)take((size_t)4096*256*2);
  float* cw                 = (float*)take((size_t)4096*256*4);
  unsigned short* feats_bf  = (unsigned short*)take((size_t)4096*1824*2);
  float* h1                 = (float*)take((size_t)4096*128*4);
  float* m_buf              = (float*)take(32*256*4);
  float* msq                = (float*)take(32*256*4);

  // ---- prep / conversions: ONE fused launch ----
  k_prep_all<<<31441,256,0,stream>>>(c, c_bf, q, q_bf,
                                     in_w_ih, wih_in_bf, qe_w_ih, wih_qe_bf,
                                     in_w_hh, whh_in_bf, qe_w_hh, whh_qe_bf,
                                     att_weight, attwT_bf, att_w1, attw1_bf,
                                     att_b1, b1pad,
                                     out_w, out_wT,
                                     mem_w_ih, mem_wihT, mem_w_hh, mem_whhT,
                                     ans_w_ih, ans_wihT, ans_w_hh, ans_whhT);

  // ---- time-parallel input projections (c and q problems in ONE launch) ----
  k_gemm_gi2<<<dim3(528,12),256,0,stream>>>(c_bf, wih_in_bf, in_b_ih, gi_c_bf,
                                            q_bf, wih_qe_bf, qe_b_ih, gi_q_bf);

  // ---- sequential GRU recurrences (context 1024 steps + query 32 steps) ----
  k_gru_rec<<<4,512,0,stream>>>(whh_in_bf, whh_qe_bf, gi_c_bf, gi_q_bf,
                                in_b_hh, qe_b_hh, i_state, q_state, c_out, q_hT);

  // ---- attention setup ----
  k_gather<<<4096,256,0,stream>>>(c_out, c_index, c_sel, c_sel_bf);
  k_gemm_bf16<<<dim3(64,4),256,0,stream>>>(c_sel_bf, attwT_bf, 256, nullptr, 0, cw, nullptr, 256);

  // ---- 3 episodic memory iterations (m starts as q_hT; fused tail) ----
  for(int it=0; it<3; it++){
    const float* m_cur = (it==0)? q_hT : m_buf;
    k_feats<<<4096,256,0,stream>>>(c_sel, cw, m_cur, q_hT, feats_bf);
    k_gemm_bf16<<<dim3(64,2),256,0,stream>>>(feats_bf, attw1_bf, 1824, b1pad, 1, h1, nullptr, 128);
    k_att_tail<<<32,256,0,stream>>>(h1, att_w2, att_b2, len_c, c_sel, m_cur,
                                    mem_wihT, mem_whhT, mem_b_ih, mem_b_hh,
                                    outp + 64000 + it*4096, m_buf);
  }

  // ---- answer module (fused logits+softmax+cell) ----
  k_ans<<<32,256,0,stream>>>(m_buf, out_wT, out_b, q_hT,
                             ans_wihT, ans_whhT, ans_b_ih, ans_b_hh,
                             1, nullptr, msq);
  k_ans<<<32,256,0,stream>>>(msq, out_wT, out_b, q_hT,
                             ans_wihT, ans_whhT, ans_b_ih, ans_b_hh,
                             1, nullptr, msq);
  k_ans<<<32,256,0,stream>>>(msq, out_wT, out_b, q_hT,
                             ans_wihT, ans_whhT, ans_b_ih, ans_b_hh,
                             0, outp, nullptr);
}

// Round 11
// 2915.043 us; speedup vs baseline: 1.6074x; 1.0025x over previous
//
#include <hip/hip_runtime.h>
#include <cstdint>
#include <cstddef>

typedef short bf16x8 __attribute__((ext_vector_type(8)));
typedef float f32x4 __attribute__((ext_vector_type(4)));
typedef int   i32x4 __attribute__((ext_vector_type(4)));

#define DEV static __device__ __forceinline__

DEV unsigned short f2bf(float x){
  union{float f; unsigned int u;} v; v.f = x;
  unsigned int r = (v.u + 0x7FFFu + ((v.u>>16)&1u)) >> 16;
  return (unsigned short)r;
}
DEV float bf2f(unsigned short h){
  union{unsigned int u; float f;} v; v.u = ((unsigned int)h)<<16;
  return v.f;
}
// unpack bf16 half of a dword: hi=0 -> low u16, hi=1 -> high u16
DEV float bfsel(int dw, int hi){
  union{unsigned int u; float f;} v;
  v.u = hi ? ((unsigned int)dw & 0xFFFF0000u) : ((unsigned int)dw << 16);
  return v.f;
}
// fast gates: v_exp_f32 + v_rcp_f32
DEV float sigm_f(float x){ return __builtin_amdgcn_rcpf(1.0f + __expf(-x)); }
DEV float tanh_f(float x){ return 2.0f*__builtin_amdgcn_rcpf(1.0f + __expf(-2.0f*x)) - 1.0f; }

// ---------------- fused prep: big c conversion + all small conversions/transposes ----
// ONE launch, dispatched by blockIdx range. Each branch reproduces the original
// kernel's exact indexing/arithmetic (launch-overhead reduction only).
__global__ void k_prep_all(
    const float* __restrict__ c,        unsigned short* __restrict__ c_bf,
    const float* __restrict__ q,        unsigned short* __restrict__ q_bf,
    const float* __restrict__ in_w_ih,  unsigned short* __restrict__ wih_in_bf,
    const float* __restrict__ qe_w_ih,  unsigned short* __restrict__ wih_qe_bf,
    const float* __restrict__ in_w_hh,  unsigned short* __restrict__ whh_in_bf,
    const float* __restrict__ qe_w_hh,  unsigned short* __restrict__ whh_qe_bf,
    const float* __restrict__ att_weight, unsigned short* __restrict__ attwT_bf,
    const float* __restrict__ att_w1,   unsigned short* __restrict__ attw1_bf,
    const float* __restrict__ att_b1,   float* __restrict__ b1pad,
    const float* __restrict__ out_w,    float* __restrict__ out_wT,
    const float* __restrict__ mem_w_ih, float* __restrict__ mem_wihT,
    const float* __restrict__ mem_w_hh, float* __restrict__ mem_whhT,
    const float* __restrict__ ans_w_ih, float* __restrict__ ans_wihT,
    const float* __restrict__ ans_w_hh, float* __restrict__ ans_whhT)
{
  int bid = blockIdx.x;
  const int tid = threadIdx.x;
  if(bid < 16384){ int i = bid*256 + tid; if(i < 4194304) c_bf[i] = f2bf(c[i]); return; }
  bid -= 16384;
  if(bid < 512){ int i = bid*256 + tid; if(i < 131072) q_bf[i] = f2bf(q[i]); return; }
  bid -= 512;
  if(bid < 384){ int i = bid*256 + tid; if(i < 98304) wih_in_bf[i] = f2bf(in_w_ih[i]); return; }
  bid -= 384;
  if(bid < 384){ int i = bid*256 + tid; if(i < 98304) wih_qe_bf[i] = f2bf(qe_w_ih[i]); return; }
  bid -= 384;
  if(bid < 768){ int i = bid*256 + tid; if(i < 196608) whh_in_bf[i] = f2bf(in_w_hh[i]); return; }
  bid -= 768;
  if(bid < 768){ int i = bid*256 + tid; if(i < 196608) whh_qe_bf[i] = f2bf(qe_w_hh[i]); return; }
  bid -= 768;
  if(bid < 256){ int i = bid*256 + tid; if(i < 65536){ int n = i>>8, k = i&255; attwT_bf[i] = f2bf(att_weight[k*256 + n]); } return; }
  bid -= 256;
  if(bid < 912){
    int i = bid*256 + tid;
    if(i < 128*1824){
      int r = i/1824, cc = i - r*1824;
      float v = (r<100 && cc<1794)? att_w1[r*1794 + cc] : 0.0f;
      attw1_bf[i] = f2bf(v);
    }
    return;
  }
  bid -= 912;
  if(bid < 1){ if(tid < 128) b1pad[tid] = (tid<100)? att_b1[tid] : 0.0f; return; }
  bid -= 1;
  if(bid < 2000){ int i = bid*256 + tid; if(i < 2000*256){ int r = i/256, cc = i - r*256; out_wT[(size_t)cc*2000 + r] = out_w[i]; } return; }
  bid -= 2000;
  if(bid < 768){ int i = bid*256 + tid; if(i < 768*256){ int r = i/256, cc = i - r*256; mem_wihT[(size_t)cc*768 + r] = mem_w_ih[i]; } return; }
  bid -= 768;
  if(bid < 768){ int i = bid*256 + tid; if(i < 768*256){ int r = i/256, cc = i - r*256; mem_whhT[(size_t)cc*768 + r] = mem_w_hh[i]; } return; }
  bid -= 768;
  if(bid < 6768){ int i = bid*256 + tid; if(i < 768*2256){ int r = i/2256, cc = i - r*2256; ans_wihT[(size_t)cc*768 + r] = ans_w_ih[i]; } return; }
  bid -= 6768;
  if(bid < 768){ int i = bid*256 + tid; if(i < 768*256){ int r = i/256, cc = i - r*256; ans_whhT[(size_t)cc*768 + r] = ans_w_hh[i]; } return; }
}

// ---------------- generic bf16 MFMA GEMM: C(M,N) = A(M,K) @ Bt(N,K)^T ----------------
__global__ __launch_bounds__(256) void k_gemm_bf16(
    const unsigned short* __restrict__ A, const unsigned short* __restrict__ Bt,
    int K, const float* __restrict__ bias, int act,
    float* __restrict__ outf, unsigned short* __restrict__ outbf, int ldc)
{
  int lane = threadIdx.x & 63, wave = threadIdx.x >> 6;
  int m_base = blockIdx.x*64 + (wave>>1)*32;
  int n_base = blockIdx.y*64 + (wave&1)*32;
  int cl = lane & 15, q4 = lane >> 4;
  f32x4 acc00={0.f,0.f,0.f,0.f}, acc01=acc00, acc10=acc00, acc11=acc00;
  const int kf_n = K >> 5;
  for(int kf=0; kf<kf_n; kf++){
    int ko = kf*32 + q4*8;
    bf16x8 a0 = *(const bf16x8*)(A + (size_t)(m_base+cl)*K + ko);
    bf16x8 a1 = *(const bf16x8*)(A + (size_t)(m_base+16+cl)*K + ko);
    bf16x8 b0 = *(const bf16x8*)(Bt + (size_t)(n_base+cl)*K + ko);
    bf16x8 b1 = *(const bf16x8*)(Bt + (size_t)(n_base+16+cl)*K + ko);
    acc00 = __builtin_amdgcn_mfma_f32_16x16x32_bf16(a0,b0,acc00,0,0,0);
    acc01 = __builtin_amdgcn_mfma_f32_16x16x32_bf16(a0,b1,acc01,0,0,0);
    acc10 = __builtin_amdgcn_mfma_f32_16x16x32_bf16(a1,b0,acc10,0,0,0);
    acc11 = __builtin_amdgcn_mfma_f32_16x16x32_bf16(a1,b1,acc11,0,0,0);
  }
  #pragma unroll
  for(int mt=0; mt<2; mt++){
    #pragma unroll
    for(int nt=0; nt<2; nt++){
      f32x4 av = (mt==0)? (nt==0?acc00:acc01) : (nt==0?acc10:acc11);
      int col = n_base + nt*16 + cl;
      float bv = bias? bias[col] : 0.0f;
      #pragma unroll
      for(int r=0;r<4;r++){
        int row = m_base + mt*16 + q4*4 + r;
        float v = av[r] + bv;
        if(act) v = tanh_f(v);
        if(outbf) outbf[(size_t)row*ldc + col] = f2bf(v);
        else      outf [(size_t)row*ldc + col] = v;
      }
    }
  }
}

// ---------------- gi GEMM with lane-packed scatter epilogue (c and q in ONE launch) ----
__global__ __launch_bounds__(256) void k_gemm_gi2(
    const unsigned short* __restrict__ Ac, const unsigned short* __restrict__ Btc,
    const float* __restrict__ biasc, unsigned short* __restrict__ outc,
    const unsigned short* __restrict__ Aq, const unsigned short* __restrict__ Btq,
    const float* __restrict__ biasq, unsigned short* __restrict__ outq)
{
  int bx = blockIdx.x;
  const unsigned short* A; const unsigned short* Bt; const float* bias;
  unsigned short* gi_out; int ss; int mblk;
  if(bx < 512){ A = Ac; Bt = Btc; bias = biasc; gi_out = outc; ss = 10; mblk = bx; }
  else        { A = Aq; Bt = Btq; bias = biasq; gi_out = outq; ss = 5;  mblk = bx - 512; }

  int lane = threadIdx.x & 63, wave = threadIdx.x >> 6;
  int m_base = mblk*64 + (wave>>1)*32;
  int n_base = blockIdx.y*64 + (wave&1)*32;
  int cl = lane & 15, q4 = lane >> 4;
  f32x4 acc00={0.f,0.f,0.f,0.f}, acc01=acc00, acc10=acc00, acc11=acc00;
  for(int kf=0; kf<4; kf++){   // K = 128
    int ko = kf*32 + q4*8;
    bf16x8 a0 = *(const bf16x8*)(A + (size_t)(m_base+cl)*128 + ko);
    bf16x8 a1 = *(const bf16x8*)(A + (size_t)(m_base+16+cl)*128 + ko);
    bf16x8 b0 = *(const bf16x8*)(Bt + (size_t)(n_base+cl)*128 + ko);
    bf16x8 b1 = *(const bf16x8*)(Bt + (size_t)(n_base+16+cl)*128 + ko);
    acc00 = __builtin_amdgcn_mfma_f32_16x16x32_bf16(a0,b0,acc00,0,0,0);
    acc01 = __builtin_amdgcn_mfma_f32_16x16x32_bf16(a0,b1,acc01,0,0,0);
    acc10 = __builtin_amdgcn_mfma_f32_16x16x32_bf16(a1,b0,acc10,0,0,0);
    acc11 = __builtin_amdgcn_mfma_f32_16x16x32_bf16(a1,b1,acc11,0,0,0);
  }
  const int tmask = (1<<ss) - 1;
  #pragma unroll
  for(int mt=0; mt<2; mt++){
    #pragma unroll
    for(int nt=0; nt<2; nt++){
      f32x4 av = (mt==0)? (nt==0?acc00:acc01) : (nt==0?acc10:acc11);
      int col = n_base + nt*16 + cl;
      float bv = bias[col];
      int g = col >> 8, rem = col & 255;
      int w = rem >> 5, s = (rem>>4)&1, cl2 = rem & 15;
      #pragma unroll
      for(int r=0;r<4;r++){
        int arow = m_base + mt*16 + q4*4 + r;
        int t = arow & tmask, b = arow >> ss;
        int blk = b >> 4, brow = b & 15;
        int lane2 = (brow>>2)*16 + cl2, rc = brow & 3;
        size_t idx = ((((size_t)t*2 + blk)*8 + w)*64 + lane2)*24 + g*8 + s*4 + rc;
        gi_out[idx] = f2bf(av[r] + bv);
      }
    }
  }
}

// ---------------- GRU recurrence ----------------
// BYTE-IDENTICAL to the verified best (rounds 0/7/8/9/10: 2020-2034 us).
// DO NOT TOUCH: the compiled schedule is a knife-edge optimum; every probed
// perturbation (pass-split, 16-wave, gi prefetch, operand swap, bias-fold)
// regressed 17-75% (rounds 1-6, all code-real per round-7 reproduction).
__global__ __launch_bounds__(512,1) void k_gru_rec(
    const unsigned short* __restrict__ whh_c, const unsigned short* __restrict__ whh_q,
    const unsigned short* __restrict__ gi_c,  const unsigned short* __restrict__ gi_q,
    const float* __restrict__ bhh_c, const float* __restrict__ bhh_q,
    const float* __restrict__ h0_c,  const float* __restrict__ h0_q,
    float* __restrict__ c_out, float* __restrict__ q_hT)
{
  __shared__ unsigned short hb0[16*264];   // double-buffered h (row stride 264 u16)
  __shared__ unsigned short hb1[16*264];

  const int blk = blockIdx.x;
  const bool isq = blk >= 2;
  const int cls = isq? blk-2 : blk;        // block index within class (0/1)
  const int b0 = cls * 16;
  const unsigned short* W  = isq? whh_q : whh_c;
  const unsigned short* GI = isq? gi_q  : gi_c;
  const float* bhh = isq? bhh_q : bhh_c;
  const float* h0  = isq? h0_q  : h0_c;
  const int steps  = isq? 32 : 1024;

  const int tid = threadIdx.x;
  const int lane = tid & 63, wave = tid >> 6;
  const int cl = lane & 15, q4 = lane >> 4;

  // B-fragments: [gate][subtile][kfrag], col = g*256 + wave*32 + s*16 + cl
  bf16x8 Bf[3][2][8];
  #pragma unroll
  for(int g=0; g<3; g++)
    #pragma unroll
    for(int s=0; s<2; s++){
      const unsigned short* wrow = W + (size_t)(g*256 + wave*32 + s*16 + cl)*256;
      #pragma unroll
      for(int kf=0; kf<8; kf++)
        Bf[g][s][kf] = *(const bf16x8*)(wrow + kf*32 + q4*8);
    }

  // per-lane biases for owned cols
  float bR[2], bZ[2], bN[2];
  #pragma unroll
  for(int s=0; s<2; s++){
    const int col = wave*32 + s*16 + cl;
    bR[s] = bhh[col]; bZ[s] = bhh[256+col]; bN[s] = bhh[512+col];
  }

  // h in registers: lane owns (row=q4*4+r, col=wave*32+s*16+cl)
  float hreg[2][4];
  #pragma unroll
  for(int s=0; s<2; s++){
    const int col = wave*32 + s*16 + cl;
    #pragma unroll
    for(int r=0; r<4; r++){
      const int row = q4*4 + r;
      float v = h0[(size_t)(b0+row)*256 + col];
      hreg[s][r] = v;
      hb0[row*264 + col] = f2bf(v);
    }
  }
  __syncthreads();

  unsigned short* hb_rd = hb0;
  unsigned short* hb_wr = hb1;

  // per-lane gi base for this (blk, wave, lane)
  const unsigned short* gi_lane = GI + (((size_t)cls*8 + wave)*64 + lane)*24;
  const size_t gi_tstride = (size_t)2*8*64*24;   // per-t stride in u16

  for(int t=0; t<steps; t++){
    // gi(t): 3x dwordx4 (48 B contiguous per lane); consumed in phase B
    const unsigned short* gp = gi_lane + (size_t)t*gi_tstride;
    i32x4 G0 = *(const i32x4*)(gp);        // gate r : [s0r0..s0r3, s1r0..s1r3]
    i32x4 G1 = *(const i32x4*)(gp + 8);    // gate z
    i32x4 G2 = *(const i32x4*)(gp + 16);   // gate n

    // deferred c_out store of h(t-1): overlaps with MFMA phase
    if(!isq && t>0){
      #pragma unroll
      for(int s=0; s<2; s++){
        const int col = wave*32 + s*16 + cl;
        #pragma unroll
        for(int r=0; r<4; r++)
          c_out[((size_t)(b0+q4*4+r)*1024 + (t-1))*256 + col] = hreg[s][r];
      }
    }

    // phase A: gates = h @ W^T  (48 MFMAs/wave)
    f32x4 acc[3][2];
    #pragma unroll
    for(int g=0; g<3; g++)
      #pragma unroll
      for(int s=0; s<2; s++){ f32x4 z={0.f,0.f,0.f,0.f}; acc[g][s]=z; }
    #pragma unroll
    for(int kf=0; kf<8; kf++){
      bf16x8 a = *(const bf16x8*)&hb_rd[cl*264 + kf*32 + q4*8];
      #pragma unroll
      for(int g=0; g<3; g++)
        #pragma unroll
        for(int s=0; s<2; s++)
          acc[g][s] = __builtin_amdgcn_mfma_f32_16x16x32_bf16(a, Bf[g][s][kf], acc[g][s], 0,0,0);
    }

    // phase B: in-register GRU update (writes OTHER h buffer -> no barrier needed here)
    #pragma unroll
    for(int s=0; s<2; s++){
      const int col = wave*32 + s*16 + cl;
      #pragma unroll
      for(int r=0; r<4; r++){
        const int row = q4*4 + r;
        const int k = s*4 + r;
        float gir = bfsel(G0[k>>1], k&1);
        float giz = bfsel(G1[k>>1], k&1);
        float gin = bfsel(G2[k>>1], k&1);
        float rr = sigm_f(gir + acc[0][s][r] + bR[s]);
        float zz = sigm_f(giz + acc[1][s][r] + bZ[s]);
        float nn = tanh_f(gin + rr*(acc[2][s][r] + bN[s]));
        float x  = nn + zz*(hreg[s][r] - nn);
        hreg[s][r] = x;
        hb_wr[row*264 + col] = f2bf(x);
      }
    }
    __syncthreads();   // hb_wr complete -> next step's phase A may read it
    unsigned short* tmp = hb_rd; hb_rd = hb_wr; hb_wr = tmp;
  }

  // final stores from hreg
  #pragma unroll
  for(int s=0; s<2; s++){
    const int col = wave*32 + s*16 + cl;
    #pragma unroll
    for(int r=0; r<4; r++){
      const int row = q4*4 + r;
      if(!isq) c_out[((size_t)(b0+row)*1024 + (steps-1))*256 + col] = hreg[s][r];
      else     q_hT[(size_t)(b0+row)*256 + col] = hreg[s][r];
    }
  }
}

// ---------------- attention helpers ----------------
__global__ void k_gather(const float* __restrict__ c_out, const int* __restrict__ c_index,
                         float* __restrict__ c_sel, unsigned short* __restrict__ c_sel_bf){
  int row = blockIdx.x;                 // 0..4095 = b*128+s
  int b = row >> 7, s = row & 127;
  int idx = c_index[b*128 + s];
  float v = c_out[((size_t)b*1024 + idx)*256 + threadIdx.x];
  c_sel   [(size_t)row*256 + threadIdx.x] = v;
  c_sel_bf[(size_t)row*256 + threadIdx.x] = f2bf(v);
}

__global__ void k_feats(const float* __restrict__ c_sel, const float* __restrict__ cw,
                        const float* __restrict__ m_, const float* __restrict__ qh,
                        unsigned short* __restrict__ feats){
  int row = blockIdx.x, tid = threadIdx.x;
  int b = row >> 7;
  float cs  = c_sel[(size_t)row*256 + tid];
  float mj  = m_[b*256 + tid];
  float qj  = qh[b*256 + tid];
  float cwj = cw[(size_t)row*256 + tid];
  float dq = cwj*qj, dm = cwj*mj;
  #pragma unroll
  for(int o=32;o>0;o>>=1){ dq += __shfl_down(dq,o); dm += __shfl_down(dm,o); }
  __shared__ float rq[4], rm[4];
  int lane = tid&63, wave=tid>>6;
  if(lane==0){ rq[wave]=dq; rm[wave]=dm; }
  __syncthreads();
  unsigned short* fr = feats + (size_t)row*1824;
  fr[tid]      = f2bf(cs);
  fr[256+tid]  = f2bf(mj);
  fr[512+tid]  = f2bf(qj);
  fr[768+tid]  = f2bf(cs*qj);
  fr[1024+tid] = f2bf(cs*mj);
  fr[1280+tid] = f2bf(fabsf(cs-qj));
  fr[1536+tid] = f2bf(fabsf(cs-mj));
  if(tid==0){
    float DQ = rq[0]+rq[1]+rq[2]+rq[3];
    float DM = rm[0]+rm[1]+rm[2]+rm[3];
    fr[1792]=f2bf(DQ); fr[1793]=f2bf(DM);
  }
  if(tid<30) fr[1794+tid]=0;   // zero K-pad
}

// ---------------- fused episodic tail: scores + masked softmax + e + mem GRU cell ----
// One block per batch row (grid=32, block=256). Keeps scores/p/e in LDS.
// Per-output arithmetic order matches the kernels it replaced.
__global__ void k_att_tail(const float* __restrict__ h1, const float* __restrict__ w2,
                           const float* __restrict__ b2, const int* __restrict__ len_c,
                           const float* __restrict__ c_sel,
                           const float* __restrict__ m_in,
                           const float* __restrict__ wihT, const float* __restrict__ whhT,
                           const float* __restrict__ bih, const float* __restrict__ bhh,
                           float* __restrict__ out_att, float* __restrict__ m_out){
  __shared__ float red[256];
  __shared__ float p[128];
  __shared__ float es[256];
  __shared__ float hs[256];
  int b = blockIdx.x, tid = threadIdx.x;
  int L = len_c[b];
  float s = -1e30f;
  if(tid < 128 && tid < L){
    const float* hr = h1 + ((size_t)b*128 + tid)*128;
    float a = 0.0f;
    for(int k=0;k<100;k++) a += hr[k]*w2[k];
    s = a + b2[0];
  }
  red[tid]=s; __syncthreads();
  for(int o=128;o>0;o>>=1){ if(tid<o) red[tid]=fmaxf(red[tid],red[tid+o]); __syncthreads(); }
  float mx = red[0]; __syncthreads();
  float ex = (tid<128 && tid<L)? __expf(s-mx) : 0.0f;
  red[tid]=ex; __syncthreads();
  for(int o=128;o>0;o>>=1){ if(tid<o) red[tid]+=red[tid+o]; __syncthreads(); }
  float inv = 1.0f/red[0];
  if(tid<128){ float pv = ex*inv; p[tid]=pv; out_att[b*128+tid]=pv; }
  hs[tid] = m_in[b*256+tid];
  __syncthreads();
  float acc = 0.0f;
  for(int si=0; si<128; si++) acc += p[si]*c_sel[((size_t)b*128+si)*256 + tid];
  es[tid] = acc;
  __syncthreads();
  float ar=0, az=0, an=0;
  for(int k=0;k<256;k++){
    float xv = es[k];
    const float* wr = wihT + (size_t)k*768;
    ar += xv*wr[tid]; az += xv*wr[256+tid]; an += xv*wr[512+tid];
  }
  float gr=0, gz=0, gn=0;
  for(int k=0;k<256;k++){
    float hv = hs[k];
    const float* wr = whhT + (size_t)k*768;
    gr += hv*wr[tid]; gz += hv*wr[256+tid]; gn += hv*wr[512+tid];
  }
  float rr = sigm_f(ar + bih[tid]     + gr + bhh[tid]);
  float zz = sigm_f(az + bih[256+tid] + gz + bhh[256+tid]);
  float nn = tanh_f(an + bih[512+tid] + rr*(gn + bhh[512+tid]));
  m_out[b*256+tid] = (1.0f-zz)*nn + zz*hs[tid];
}

// ---------------- fused final iteration + ENTIRE answer module ----
// One block per batch row (grid=32, block=256). The answer module is fully
// batch-independent, so block b runs: att_tail(it=2) -> msq = m (stays in LDS,
// same float value that previously round-tripped through global) -> 3x
// {logits -> softmax -> (ans GRU cell on first two)}. All arithmetic and
// accumulation order byte-identical to the kernels replaced; barriers placed
// exactly at the old kernel boundaries.
__global__ void k_att_ans(const float* __restrict__ h1, const float* __restrict__ w2,
                          const float* __restrict__ b2, const int* __restrict__ len_c,
                          const float* __restrict__ c_sel,
                          const float* __restrict__ m_in,
                          const float* __restrict__ mwihT, const float* __restrict__ mwhhT,
                          const float* __restrict__ mbih, const float* __restrict__ mbhh,
                          float* __restrict__ out_att,
                          const float* __restrict__ out_wT, const float* __restrict__ out_b,
                          const float* __restrict__ qh,
                          const float* __restrict__ awihT, const float* __restrict__ awhhT,
                          const float* __restrict__ abih, const float* __restrict__ abhh,
                          float* __restrict__ y_out)
{
  __shared__ float red[256];
  __shared__ float p[128];
  __shared__ float es[256];
  __shared__ float hs[256];
  __shared__ float yl[2000];
  __shared__ float ms[256];
  __shared__ float qs[256];
  int b = blockIdx.x, tid = threadIdx.x;

  // ---- att_tail part (identical to k_att_tail) ----
  int L = len_c[b];
  float s = -1e30f;
  if(tid < 128 && tid < L){
    const float* hr = h1 + ((size_t)b*128 + tid)*128;
    float a = 0.0f;
    for(int k=0;k<100;k++) a += hr[k]*w2[k];
    s = a + b2[0];
  }
  red[tid]=s; __syncthreads();
  for(int o=128;o>0;o>>=1){ if(tid<o) red[tid]=fmaxf(red[tid],red[tid+o]); __syncthreads(); }
  float mx = red[0]; __syncthreads();
  float ex = (tid<128 && tid<L)? __expf(s-mx) : 0.0f;
  red[tid]=ex; __syncthreads();
  for(int o=128;o>0;o>>=1){ if(tid<o) red[tid]+=red[tid+o]; __syncthreads(); }
  float inv = 1.0f/red[0];
  if(tid<128){ float pv = ex*inv; p[tid]=pv; out_att[b*128+tid]=pv; }
  hs[tid] = m_in[b*256+tid];
  qs[tid] = qh[b*256+tid];
  __syncthreads();
  float acc = 0.0f;
  for(int si=0; si<128; si++) acc += p[si]*c_sel[((size_t)b*128+si)*256 + tid];
  es[tid] = acc;
  __syncthreads();
  // mem GRU cell -> msq directly into LDS
  {
    float ar=0, az=0, an=0;
    for(int k=0;k<256;k++){
      float xv = es[k];
      const float* wr = mwihT + (size_t)k*768;
      ar += xv*wr[tid]; az += xv*wr[256+tid]; an += xv*wr[512+tid];
    }
    float gr=0, gz=0, gn=0;
    for(int k=0;k<256;k++){
      float hv = hs[k];
      const float* wr = mwhhT + (size_t)k*768;
      gr += hv*wr[tid]; gz += hv*wr[256+tid]; gn += hv*wr[512+tid];
    }
    float rr = sigm_f(ar + mbih[tid]     + gr + mbhh[tid]);
    float zz = sigm_f(az + mbih[256+tid] + gz + mbhh[256+tid]);
    float nn = tanh_f(an + mbih[512+tid] + rr*(gn + mbhh[512+tid]));
    ms[tid] = (1.0f-zz)*nn + zz*hs[tid];
  }
  __syncthreads();

  // ---- answer module: 3 steps (ans GRU cell after the first two) ----
  for(int step=0; step<3; step++){
    // logits (serial k, bias first — identical to original)
    for(int n=tid; n<2000; n+=256){
      float a2 = out_b[n];
      for(int k=0;k<256;k++) a2 += ms[k]*out_wT[(size_t)k*2000 + n];
      yl[n] = a2;
    }
    __syncthreads();
    // softmax over 2000 (identical structure)
    float mx2 = -1e30f;
    for(int i=tid;i<2000;i+=256) mx2 = fmaxf(mx2, yl[i]);
    red[tid]=mx2; __syncthreads();
    for(int o=128;o>0;o>>=1){ if(tid<o) red[tid]=fmaxf(red[tid],red[tid+o]); __syncthreads(); }
    mx2 = red[0]; __syncthreads();
    float sum=0.0f;
    for(int i=tid;i<2000;i+=256) sum += __expf(yl[i]-mx2);
    red[tid]=sum; __syncthreads();
    for(int o=128;o>0;o>>=1){ if(tid<o) red[tid]+=red[tid+o]; __syncthreads(); }
    float inv2 = 1.0f/red[0];
    // each yl[i] read/written only by thread i%256 -> in-place safe
    for(int i=tid;i<2000;i+=256){
      float yv = __expf(yl[i]-mx2)*inv2;
      yl[i] = yv;
      if(step==2) y_out[(size_t)b*2000+i] = yv;
    }
    if(step==2) break;
    __syncthreads();
    // ans GRU cell: x = [y(2000) || qh(256)] (identical order to original)
    float a1=0, a2=0, a3=0;
    for(int k=0;k<2000;k++){
      float xv = yl[k];
      const float* wr = awihT + (size_t)k*768;
      a1 += xv*wr[tid]; a2 += xv*wr[256+tid]; a3 += xv*wr[512+tid];
    }
    for(int k=0;k<256;k++){
      float xv = qs[k];
      const float* wr = awihT + (size_t)(2000+k)*768;
      a1 += xv*wr[tid]; a2 += xv*wr[256+tid]; a3 += xv*wr[512+tid];
    }
    float g1=0, g2=0, g3=0;
    for(int k=0;k<256;k++){
      float hv = ms[k];
      const float* wr = awhhT + (size_t)k*768;
      g1 += hv*wr[tid]; g2 += hv*wr[256+tid]; g3 += hv*wr[512+tid];
    }
    float rr = sigm_f(a1 + abih[tid]     + g1 + abhh[tid]);
    float zz = sigm_f(a2 + abih[256+tid] + g2 + abhh[256+tid]);
    float nn = tanh_f(a3 + abih[512+tid] + rr*(g3 + abhh[512+tid]));
    float newms = (1.0f-zz)*nn + zz*ms[tid];
    __syncthreads();          // all reads of ms/yl complete
    ms[tid] = newms;
    __syncthreads();
  }
}

// ---------------- launch ----------------
extern "C" void kernel_launch(void* const* d_in, const int* in_sizes, int n_in,
                              void* d_out, int out_size, void* d_ws, size_t ws_size,
                              hipStream_t stream)
{
  const float* c        = (const float*)d_in[0];
  const float* q        = (const float*)d_in[1];
  const float* i_state  = (const float*)d_in[2];
  const float* q_state  = (const float*)d_in[3];
  const float* in_w_ih  = (const float*)d_in[4];
  const float* in_w_hh  = (const float*)d_in[5];
  const float* in_b_ih  = (const float*)d_in[6];
  const float* in_b_hh  = (const float*)d_in[7];
  const float* qe_w_ih  = (const float*)d_in[8];
  const float* qe_w_hh  = (const float*)d_in[9];
  const float* qe_b_ih  = (const float*)d_in[10];
  const float* qe_b_hh  = (const float*)d_in[11];
  const float* att_weight = (const float*)d_in[12];
  const float* att_w1   = (const float*)d_in[13];
  const float* att_b1   = (const float*)d_in[14];
  const float* att_w2   = (const float*)d_in[15];
  const float* att_b2   = (const float*)d_in[16];
  const float* mem_w_ih = (const float*)d_in[17];
  const float* mem_w_hh = (const float*)d_in[18];
  const float* mem_b_ih = (const float*)d_in[19];
  const float* mem_b_hh = (const float*)d_in[20];
  const float* out_w    = (const float*)d_in[21];
  const float* out_b    = (const float*)d_in[22];
  const float* ans_w_ih = (const float*)d_in[23];
  const float* ans_w_hh = (const float*)d_in[24];
  const float* ans_b_ih = (const float*)d_in[25];
  const float* ans_b_hh = (const float*)d_in[26];
  const int*   c_index  = (const int*)d_in[27];
  const int*   len_c    = (const int*)d_in[28];
  float* outp = (float*)d_out;   // [0,64000) y ; [64000,76288) att (3,32,128)

  char* wp = (char*)d_ws;
  auto take = [&](size_t nbytes)->char*{
    char* p = wp; wp += (nbytes + 255) & ~(size_t)255; return p;
  };
  unsigned short* c_bf      = (unsigned short*)take((size_t)32*1024*128*2);
  unsigned short* q_bf      = (unsigned short*)take((size_t)32*32*128*2);
  unsigned short* wih_in_bf = (unsigned short*)take(768*128*2);
  unsigned short* wih_qe_bf = (unsigned short*)take(768*128*2);
  unsigned short* whh_in_bf = (unsigned short*)take(768*256*2);
  unsigned short* whh_qe_bf = (unsigned short*)take(768*256*2);
  unsigned short* attwT_bf  = (unsigned short*)take(256*256*2);
  unsigned short* attw1_bf  = (unsigned short*)take(128*1824*2);
  float* b1pad              = (float*)take(128*4);
  float* out_wT             = (float*)take((size_t)256*2000*4);
  float* mem_wihT           = (float*)take(256*768*4);
  float* mem_whhT           = (float*)take(256*768*4);
  float* ans_wihT           = (float*)take((size_t)2256*768*4);
  float* ans_whhT           = (float*)take(256*768*4);
  unsigned short* gi_c_bf   = (unsigned short*)take((size_t)32768*768*2);  // lane-packed
  unsigned short* gi_q_bf   = (unsigned short*)take((size_t)1024*768*2);   // lane-packed
  float* c_out              = (float*)take((size_t)32*1024*256*4);
  float* q_hT               = (float*)take(32*256*4);
  float* c_sel              = (float*)take((size_t)4096*256*4);
  unsigned short* c_sel_bf  = (unsigned short*)take((size_t)4096*256*2);
  float* cw                 = (float*)take((size_t)4096*256*4);
  unsigned short* feats_bf  = (unsigned short*)take((size_t)4096*1824*2);
  float* h1                 = (float*)take((size_t)4096*128*4);
  float* m_buf              = (float*)take(32*256*4);

  // ---- prep / conversions: ONE fused launch ----
  k_prep_all<<<31441,256,0,stream>>>(c, c_bf, q, q_bf,
                                     in_w_ih, wih_in_bf, qe_w_ih, wih_qe_bf,
                                     in_w_hh, whh_in_bf, qe_w_hh, whh_qe_bf,
                                     att_weight, attwT_bf, att_w1, attw1_bf,
                                     att_b1, b1pad,
                                     out_w, out_wT,
                                     mem_w_ih, mem_wihT, mem_w_hh, mem_whhT,
                                     ans_w_ih, ans_wihT, ans_w_hh, ans_whhT);

  // ---- time-parallel input projections (c and q problems in ONE launch) ----
  k_gemm_gi2<<<dim3(528,12),256,0,stream>>>(c_bf, wih_in_bf, in_b_ih, gi_c_bf,
                                            q_bf, wih_qe_bf, qe_b_ih, gi_q_bf);

  // ---- sequential GRU recurrences (context 1024 steps + query 32 steps) ----
  k_gru_rec<<<4,512,0,stream>>>(whh_in_bf, whh_qe_bf, gi_c_bf, gi_q_bf,
                                in_b_hh, qe_b_hh, i_state, q_state, c_out, q_hT);

  // ---- attention setup ----
  k_gather<<<4096,256,0,stream>>>(c_out, c_index, c_sel, c_sel_bf);
  k_gemm_bf16<<<dim3(64,4),256,0,stream>>>(c_sel_bf, attwT_bf, 256, nullptr, 0, cw, nullptr, 256);

  // ---- episodic iterations 0,1 (fused tail); iteration 2 fused with answer module ----
  for(int it=0; it<2; it++){
    const float* m_cur = (it==0)? q_hT : m_buf;
    k_feats<<<4096,256,0,stream>>>(c_sel, cw, m_cur, q_hT, feats_bf);
    k_gemm_bf16<<<dim3(64,2),256,0,stream>>>(feats_bf, attw1_bf, 1824, b1pad, 1, h1, nullptr, 128);
    k_att_tail<<<32,256,0,stream>>>(h1, att_w2, att_b2, len_c, c_sel, m_cur,
                                    mem_wihT, mem_whhT, mem_b_ih, mem_b_hh,
                                    outp + 64000 + it*4096, m_buf);
  }
  // iteration 2 + entire answer module in ONE kernel
  k_feats<<<4096,256,0,stream>>>(c_sel, cw, m_buf, q_hT, feats_bf);
  k_gemm_bf16<<<dim3(64,2),256,0,stream>>>(feats_bf, attw1_bf, 1824, b1pad, 1, h1, nullptr, 128);
  k_att_ans<<<32,256,0,stream>>>(h1, att_w2, att_b2, len_c, c_sel, m_buf,
                                 mem_wihT, mem_whhT, mem_b_ih, mem_b_hh,
                                 outp + 64000 + 2*4096,
                                 out_wT, out_b, q_hT,
                                 ans_wihT, ans_whhT, ans_b_ih, ans_b_hh,
                                 outp);
}

// Round 12
// 2680.772 us; speedup vs baseline: 1.7478x; 1.0874x over previous
//
#include <hip/hip_runtime.h>
#include <cstdint>
#include <cstddef>

typedef short bf16x8 __attribute__((ext_vector_type(8)));
typedef float f32x4 __attribute__((ext_vector_type(4)));
typedef int   i32x4 __attribute__((ext_vector_type(4)));

#define DEV static __device__ __forceinline__

DEV unsigned short f2bf(float x){
  union{float f; unsigned int u;} v; v.f = x;
  unsigned int r = (v.u + 0x7FFFu + ((v.u>>16)&1u)) >> 16;
  return (unsigned short)r;
}
DEV float bf2f(unsigned short h){
  union{unsigned int u; float f;} v; v.u = ((unsigned int)h)<<16;
  return v.f;
}
// unpack bf16 half of a dword: hi=0 -> low u16, hi=1 -> high u16
DEV float bfsel(int dw, int hi){
  union{unsigned int u; float f;} v;
  v.u = hi ? ((unsigned int)dw & 0xFFFF0000u) : ((unsigned int)dw << 16);
  return v.f;
}
// fast gates: v_exp_f32 + v_rcp_f32
DEV float sigm_f(float x){ return __builtin_amdgcn_rcpf(1.0f + __expf(-x)); }
DEV float tanh_f(float x){ return 2.0f*__builtin_amdgcn_rcpf(1.0f + __expf(-2.0f*x)) - 1.0f; }

// ---------------- fused prep: big c conversion + all small conversions/transposes ----
__global__ void k_prep_all(
    const float* __restrict__ c,        unsigned short* __restrict__ c_bf,
    const float* __restrict__ q,        unsigned short* __restrict__ q_bf,
    const float* __restrict__ in_w_ih,  unsigned short* __restrict__ wih_in_bf,
    const float* __restrict__ qe_w_ih,  unsigned short* __restrict__ wih_qe_bf,
    const float* __restrict__ in_w_hh,  unsigned short* __restrict__ whh_in_bf,
    const float* __restrict__ qe_w_hh,  unsigned short* __restrict__ whh_qe_bf,
    const float* __restrict__ att_weight, unsigned short* __restrict__ attwT_bf,
    const float* __restrict__ att_w1,   unsigned short* __restrict__ attw1_bf,
    const float* __restrict__ att_b1,   float* __restrict__ b1pad,
    const float* __restrict__ out_w,    float* __restrict__ out_wT,
    const float* __restrict__ mem_w_ih, float* __restrict__ mem_wihT,
    const float* __restrict__ mem_w_hh, float* __restrict__ mem_whhT,
    const float* __restrict__ ans_w_ih, float* __restrict__ ans_wihT,
    const float* __restrict__ ans_w_hh, float* __restrict__ ans_whhT)
{
  int bid = blockIdx.x;
  const int tid = threadIdx.x;
  if(bid < 16384){ int i = bid*256 + tid; if(i < 4194304) c_bf[i] = f2bf(c[i]); return; }
  bid -= 16384;
  if(bid < 512){ int i = bid*256 + tid; if(i < 131072) q_bf[i] = f2bf(q[i]); return; }
  bid -= 512;
  if(bid < 384){ int i = bid*256 + tid; if(i < 98304) wih_in_bf[i] = f2bf(in_w_ih[i]); return; }
  bid -= 384;
  if(bid < 384){ int i = bid*256 + tid; if(i < 98304) wih_qe_bf[i] = f2bf(qe_w_ih[i]); return; }
  bid -= 384;
  if(bid < 768){ int i = bid*256 + tid; if(i < 196608) whh_in_bf[i] = f2bf(in_w_hh[i]); return; }
  bid -= 768;
  if(bid < 768){ int i = bid*256 + tid; if(i < 196608) whh_qe_bf[i] = f2bf(qe_w_hh[i]); return; }
  bid -= 768;
  if(bid < 256){ int i = bid*256 + tid; if(i < 65536){ int n = i>>8, k = i&255; attwT_bf[i] = f2bf(att_weight[k*256 + n]); } return; }
  bid -= 256;
  if(bid < 912){
    int i = bid*256 + tid;
    if(i < 128*1824){
      int r = i/1824, cc = i - r*1824;
      float v = (r<100 && cc<1794)? att_w1[r*1794 + cc] : 0.0f;
      attw1_bf[i] = f2bf(v);
    }
    return;
  }
  bid -= 912;
  if(bid < 1){ if(tid < 128) b1pad[tid] = (tid<100)? att_b1[tid] : 0.0f; return; }
  bid -= 1;
  if(bid < 2000){ int i = bid*256 + tid; if(i < 2000*256){ int r = i/256, cc = i - r*256; out_wT[(size_t)cc*2000 + r] = out_w[i]; } return; }
  bid -= 2000;
  if(bid < 768){ int i = bid*256 + tid; if(i < 768*256){ int r = i/256, cc = i - r*256; mem_wihT[(size_t)cc*768 + r] = mem_w_ih[i]; } return; }
  bid -= 768;
  if(bid < 768){ int i = bid*256 + tid; if(i < 768*256){ int r = i/256, cc = i - r*256; mem_whhT[(size_t)cc*768 + r] = mem_w_hh[i]; } return; }
  bid -= 768;
  if(bid < 6768){ int i = bid*256 + tid; if(i < 768*2256){ int r = i/2256, cc = i - r*2256; ans_wihT[(size_t)cc*768 + r] = ans_w_ih[i]; } return; }
  bid -= 6768;
  if(bid < 768){ int i = bid*256 + tid; if(i < 768*256){ int r = i/256, cc = i - r*256; ans_whhT[(size_t)cc*768 + r] = ans_w_hh[i]; } return; }
}

// ---------------- generic bf16 MFMA GEMM: C(M,N) = A(M,K) @ Bt(N,K)^T ----------------
__global__ __launch_bounds__(256) void k_gemm_bf16(
    const unsigned short* __restrict__ A, const unsigned short* __restrict__ Bt,
    int K, const float* __restrict__ bias, int act,
    float* __restrict__ outf, unsigned short* __restrict__ outbf, int ldc)
{
  int lane = threadIdx.x & 63, wave = threadIdx.x >> 6;
  int m_base = blockIdx.x*64 + (wave>>1)*32;
  int n_base = blockIdx.y*64 + (wave&1)*32;
  int cl = lane & 15, q4 = lane >> 4;
  f32x4 acc00={0.f,0.f,0.f,0.f}, acc01=acc00, acc10=acc00, acc11=acc00;
  const int kf_n = K >> 5;
  for(int kf=0; kf<kf_n; kf++){
    int ko = kf*32 + q4*8;
    bf16x8 a0 = *(const bf16x8*)(A + (size_t)(m_base+cl)*K + ko);
    bf16x8 a1 = *(const bf16x8*)(A + (size_t)(m_base+16+cl)*K + ko);
    bf16x8 b0 = *(const bf16x8*)(Bt + (size_t)(n_base+cl)*K + ko);
    bf16x8 b1 = *(const bf16x8*)(Bt + (size_t)(n_base+16+cl)*K + ko);
    acc00 = __builtin_amdgcn_mfma_f32_16x16x32_bf16(a0,b0,acc00,0,0,0);
    acc01 = __builtin_amdgcn_mfma_f32_16x16x32_bf16(a0,b1,acc01,0,0,0);
    acc10 = __builtin_amdgcn_mfma_f32_16x16x32_bf16(a1,b0,acc10,0,0,0);
    acc11 = __builtin_amdgcn_mfma_f32_16x16x32_bf16(a1,b1,acc11,0,0,0);
  }
  #pragma unroll
  for(int mt=0; mt<2; mt++){
    #pragma unroll
    for(int nt=0; nt<2; nt++){
      f32x4 av = (mt==0)? (nt==0?acc00:acc01) : (nt==0?acc10:acc11);
      int col = n_base + nt*16 + cl;
      float bv = bias? bias[col] : 0.0f;
      #pragma unroll
      for(int r=0;r<4;r++){
        int row = m_base + mt*16 + q4*4 + r;
        float v = av[r] + bv;
        if(act) v = tanh_f(v);
        if(outbf) outbf[(size_t)row*ldc + col] = f2bf(v);
        else      outf [(size_t)row*ldc + col] = v;
      }
    }
  }
}

// ---------------- gi GEMM with lane-packed scatter epilogue (c and q in ONE launch) ----
__global__ __launch_bounds__(256) void k_gemm_gi2(
    const unsigned short* __restrict__ Ac, const unsigned short* __restrict__ Btc,
    const float* __restrict__ biasc, unsigned short* __restrict__ outc,
    const unsigned short* __restrict__ Aq, const unsigned short* __restrict__ Btq,
    const float* __restrict__ biasq, unsigned short* __restrict__ outq)
{
  int bx = blockIdx.x;
  const unsigned short* A; const unsigned short* Bt; const float* bias;
  unsigned short* gi_out; int ss; int mblk;
  if(bx < 512){ A = Ac; Bt = Btc; bias = biasc; gi_out = outc; ss = 10; mblk = bx; }
  else        { A = Aq; Bt = Btq; bias = biasq; gi_out = outq; ss = 5;  mblk = bx - 512; }

  int lane = threadIdx.x & 63, wave = threadIdx.x >> 6;
  int m_base = mblk*64 + (wave>>1)*32;
  int n_base = blockIdx.y*64 + (wave&1)*32;
  int cl = lane & 15, q4 = lane >> 4;
  f32x4 acc00={0.f,0.f,0.f,0.f}, acc01=acc00, acc10=acc00, acc11=acc00;
  for(int kf=0; kf<4; kf++){   // K = 128
    int ko = kf*32 + q4*8;
    bf16x8 a0 = *(const bf16x8*)(A + (size_t)(m_base+cl)*128 + ko);
    bf16x8 a1 = *(const bf16x8*)(A + (size_t)(m_base+16+cl)*128 + ko);
    bf16x8 b0 = *(const bf16x8*)(Bt + (size_t)(n_base+cl)*128 + ko);
    bf16x8 b1 = *(const bf16x8*)(Bt + (size_t)(n_base+16+cl)*128 + ko);
    acc00 = __builtin_amdgcn_mfma_f32_16x16x32_bf16(a0,b0,acc00,0,0,0);
    acc01 = __builtin_amdgcn_mfma_f32_16x16x32_bf16(a0,b1,acc01,0,0,0);
    acc10 = __builtin_amdgcn_mfma_f32_16x16x32_bf16(a1,b0,acc10,0,0,0);
    acc11 = __builtin_amdgcn_mfma_f32_16x16x32_bf16(a1,b1,acc11,0,0,0);
  }
  const int tmask = (1<<ss) - 1;
  #pragma unroll
  for(int mt=0; mt<2; mt++){
    #pragma unroll
    for(int nt=0; nt<2; nt++){
      f32x4 av = (mt==0)? (nt==0?acc00:acc01) : (nt==0?acc10:acc11);
      int col = n_base + nt*16 + cl;
      float bv = bias[col];
      int g = col >> 8, rem = col & 255;
      int w = rem >> 5, s = (rem>>4)&1, cl2 = rem & 15;
      #pragma unroll
      for(int r=0;r<4;r++){
        int arow = m_base + mt*16 + q4*4 + r;
        int t = arow & tmask, b = arow >> ss;
        int blk = b >> 4, brow = b & 15;
        int lane2 = (brow>>2)*16 + cl2, rc = brow & 3;
        size_t idx = ((((size_t)t*2 + blk)*8 + w)*64 + lane2)*24 + g*8 + s*4 + rc;
        gi_out[idx] = f2bf(av[r] + bv);
      }
    }
  }
}

// ---------------- GRU recurrence ----------------
// BYTE-IDENTICAL to the verified best (rounds 0/7/8/9/10/11: 2020-2037 us).
// DO NOT TOUCH: the compiled schedule is a knife-edge optimum; every probed
// perturbation (pass-split, 16-wave, gi prefetch, operand swap, bias-fold)
// regressed 17-75% (rounds 1-6, all code-real per round-7 reproduction).
__global__ __launch_bounds__(512,1) void k_gru_rec(
    const unsigned short* __restrict__ whh_c, const unsigned short* __restrict__ whh_q,
    const unsigned short* __restrict__ gi_c,  const unsigned short* __restrict__ gi_q,
    const float* __restrict__ bhh_c, const float* __restrict__ bhh_q,
    const float* __restrict__ h0_c,  const float* __restrict__ h0_q,
    float* __restrict__ c_out, float* __restrict__ q_hT)
{
  __shared__ unsigned short hb0[16*264];   // double-buffered h (row stride 264 u16)
  __shared__ unsigned short hb1[16*264];

  const int blk = blockIdx.x;
  const bool isq = blk >= 2;
  const int cls = isq? blk-2 : blk;        // block index within class (0/1)
  const int b0 = cls * 16;
  const unsigned short* W  = isq? whh_q : whh_c;
  const unsigned short* GI = isq? gi_q  : gi_c;
  const float* bhh = isq? bhh_q : bhh_c;
  const float* h0  = isq? h0_q  : h0_c;
  const int steps  = isq? 32 : 1024;

  const int tid = threadIdx.x;
  const int lane = tid & 63, wave = tid >> 6;
  const int cl = lane & 15, q4 = lane >> 4;

  // B-fragments: [gate][subtile][kfrag], col = g*256 + wave*32 + s*16 + cl
  bf16x8 Bf[3][2][8];
  #pragma unroll
  for(int g=0; g<3; g++)
    #pragma unroll
    for(int s=0; s<2; s++){
      const unsigned short* wrow = W + (size_t)(g*256 + wave*32 + s*16 + cl)*256;
      #pragma unroll
      for(int kf=0; kf<8; kf++)
        Bf[g][s][kf] = *(const bf16x8*)(wrow + kf*32 + q4*8);
    }

  // per-lane biases for owned cols
  float bR[2], bZ[2], bN[2];
  #pragma unroll
  for(int s=0; s<2; s++){
    const int col = wave*32 + s*16 + cl;
    bR[s] = bhh[col]; bZ[s] = bhh[256+col]; bN[s] = bhh[512+col];
  }

  // h in registers: lane owns (row=q4*4+r, col=wave*32+s*16+cl)
  float hreg[2][4];
  #pragma unroll
  for(int s=0; s<2; s++){
    const int col = wave*32 + s*16 + cl;
    #pragma unroll
    for(int r=0; r<4; r++){
      const int row = q4*4 + r;
      float v = h0[(size_t)(b0+row)*256 + col];
      hreg[s][r] = v;
      hb0[row*264 + col] = f2bf(v);
    }
  }
  __syncthreads();

  unsigned short* hb_rd = hb0;
  unsigned short* hb_wr = hb1;

  // per-lane gi base for this (blk, wave, lane)
  const unsigned short* gi_lane = GI + (((size_t)cls*8 + wave)*64 + lane)*24;
  const size_t gi_tstride = (size_t)2*8*64*24;   // per-t stride in u16

  for(int t=0; t<steps; t++){
    // gi(t): 3x dwordx4 (48 B contiguous per lane); consumed in phase B
    const unsigned short* gp = gi_lane + (size_t)t*gi_tstride;
    i32x4 G0 = *(const i32x4*)(gp);        // gate r : [s0r0..s0r3, s1r0..s1r3]
    i32x4 G1 = *(const i32x4*)(gp + 8);    // gate z
    i32x4 G2 = *(const i32x4*)(gp + 16);   // gate n

    // deferred c_out store of h(t-1): overlaps with MFMA phase
    if(!isq && t>0){
      #pragma unroll
      for(int s=0; s<2; s++){
        const int col = wave*32 + s*16 + cl;
        #pragma unroll
        for(int r=0; r<4; r++)
          c_out[((size_t)(b0+q4*4+r)*1024 + (t-1))*256 + col] = hreg[s][r];
      }
    }

    // phase A: gates = h @ W^T  (48 MFMAs/wave)
    f32x4 acc[3][2];
    #pragma unroll
    for(int g=0; g<3; g++)
      #pragma unroll
      for(int s=0; s<2; s++){ f32x4 z={0.f,0.f,0.f,0.f}; acc[g][s]=z; }
    #pragma unroll
    for(int kf=0; kf<8; kf++){
      bf16x8 a = *(const bf16x8*)&hb_rd[cl*264 + kf*32 + q4*8];
      #pragma unroll
      for(int g=0; g<3; g++)
        #pragma unroll
        for(int s=0; s<2; s++)
          acc[g][s] = __builtin_amdgcn_mfma_f32_16x16x32_bf16(a, Bf[g][s][kf], acc[g][s], 0,0,0);
    }

    // phase B: in-register GRU update (writes OTHER h buffer -> no barrier needed here)
    #pragma unroll
    for(int s=0; s<2; s++){
      const int col = wave*32 + s*16 + cl;
      #pragma unroll
      for(int r=0; r<4; r++){
        const int row = q4*4 + r;
        const int k = s*4 + r;
        float gir = bfsel(G0[k>>1], k&1);
        float giz = bfsel(G1[k>>1], k&1);
        float gin = bfsel(G2[k>>1], k&1);
        float rr = sigm_f(gir + acc[0][s][r] + bR[s]);
        float zz = sigm_f(giz + acc[1][s][r] + bZ[s]);
        float nn = tanh_f(gin + rr*(acc[2][s][r] + bN[s]));
        float x  = nn + zz*(hreg[s][r] - nn);
        hreg[s][r] = x;
        hb_wr[row*264 + col] = f2bf(x);
      }
    }
    __syncthreads();   // hb_wr complete -> next step's phase A may read it
    unsigned short* tmp = hb_rd; hb_rd = hb_wr; hb_wr = tmp;
  }

  // final stores from hreg
  #pragma unroll
  for(int s=0; s<2; s++){
    const int col = wave*32 + s*16 + cl;
    #pragma unroll
    for(int r=0; r<4; r++){
      const int row = q4*4 + r;
      if(!isq) c_out[((size_t)(b0+row)*1024 + (steps-1))*256 + col] = hreg[s][r];
      else     q_hT[(size_t)(b0+row)*256 + col] = hreg[s][r];
    }
  }
}

// ---------------- attention helpers ----------------
__global__ void k_gather(const float* __restrict__ c_out, const int* __restrict__ c_index,
                         float* __restrict__ c_sel, unsigned short* __restrict__ c_sel_bf){
  int row = blockIdx.x;                 // 0..4095 = b*128+s
  int b = row >> 7, s = row & 127;
  int idx = c_index[b*128 + s];
  float v = c_out[((size_t)b*1024 + idx)*256 + threadIdx.x];
  c_sel   [(size_t)row*256 + threadIdx.x] = v;
  c_sel_bf[(size_t)row*256 + threadIdx.x] = f2bf(v);
}

__global__ void k_feats(const float* __restrict__ c_sel, const float* __restrict__ cw,
                        const float* __restrict__ m_, const float* __restrict__ qh,
                        unsigned short* __restrict__ feats){
  int row = blockIdx.x, tid = threadIdx.x;
  int b = row >> 7;
  float cs  = c_sel[(size_t)row*256 + tid];
  float mj  = m_[b*256 + tid];
  float qj  = qh[b*256 + tid];
  float cwj = cw[(size_t)row*256 + tid];
  float dq = cwj*qj, dm = cwj*mj;
  #pragma unroll
  for(int o=32;o>0;o>>=1){ dq += __shfl_down(dq,o); dm += __shfl_down(dm,o); }
  __shared__ float rq[4], rm[4];
  int lane = tid&63, wave=tid>>6;
  if(lane==0){ rq[wave]=dq; rm[wave]=dm; }
  __syncthreads();
  unsigned short* fr = feats + (size_t)row*1824;
  fr[tid]      = f2bf(cs);
  fr[256+tid]  = f2bf(mj);
  fr[512+tid]  = f2bf(qj);
  fr[768+tid]  = f2bf(cs*qj);
  fr[1024+tid] = f2bf(cs*mj);
  fr[1280+tid] = f2bf(fabsf(cs-qj));
  fr[1536+tid] = f2bf(fabsf(cs-mj));
  if(tid==0){
    float DQ = rq[0]+rq[1]+rq[2]+rq[3];
    float DM = rm[0]+rm[1]+rm[2]+rm[3];
    fr[1792]=f2bf(DQ); fr[1793]=f2bf(DM);
  }
  if(tid<30) fr[1794+tid]=0;   // zero K-pad
}

// ---------------- fused episodic tail (1024 threads): scores + softmax + e + mem cell ----
// One block per batch row (grid=32, block=1024). The 768 gate-dots run as 768
// parallel threads (one serial dot each, SAME k-order as before -> bit-identical);
// partials staged in LDS, combined by threads<256 with the exact original
// expressions. 16 waves/CU instead of 4 -> ~4x memory parallelism on the
// per-block weight stream (the measured bottleneck).
__global__ __launch_bounds__(1024) void k_att_tail(
                           const float* __restrict__ h1, const float* __restrict__ w2,
                           const float* __restrict__ b2, const int* __restrict__ len_c,
                           const float* __restrict__ c_sel,
                           const float* __restrict__ m_in,
                           const float* __restrict__ wihT, const float* __restrict__ whhT,
                           const float* __restrict__ bih, const float* __restrict__ bhh,
                           float* __restrict__ out_att, float* __restrict__ m_out){
  __shared__ float red[256];
  __shared__ float p[128];
  __shared__ float es[256];
  __shared__ float hs[256];
  __shared__ float pa[768];   // input-proj partials, index g*256+n
  __shared__ float pg[768];   // hidden-proj partials
  int b = blockIdx.x, tid = threadIdx.x;
  int L = len_c[b];
  float s = -1e30f;
  if(tid < 128 && tid < L){
    const float* hr = h1 + ((size_t)b*128 + tid)*128;
    float a = 0.0f;
    for(int k=0;k<100;k++) a += hr[k]*w2[k];
    s = a + b2[0];
  }
  if(tid < 256) red[tid]=s;
  __syncthreads();
  for(int o=128;o>0;o>>=1){ if(tid<o) red[tid]=fmaxf(red[tid],red[tid+o]); __syncthreads(); }
  float mx = red[0]; __syncthreads();
  float ex = (tid<128 && tid<L)? __expf(s-mx) : 0.0f;
  if(tid < 256) red[tid]=ex;
  __syncthreads();
  for(int o=128;o>0;o>>=1){ if(tid<o) red[tid]+=red[tid+o]; __syncthreads(); }
  float inv = 1.0f/red[0];
  if(tid<128){ float pv = ex*inv; p[tid]=pv; out_att[b*128+tid]=pv; }
  if(tid<256) hs[tid] = m_in[b*256+tid];
  __syncthreads();
  if(tid<256){
    float acc = 0.0f;
    for(int si=0; si<128; si++) acc += p[si]*c_sel[((size_t)b*128+si)*256 + tid];
    es[tid] = acc;
  }
  __syncthreads();
  // gate dots: one output per thread, same serial k-order -> bit-identical
  if(tid < 768){
    float a = 0.0f;
    for(int k=0;k<256;k++) a += es[k]*wihT[(size_t)k*768 + tid];
    float g = 0.0f;
    for(int k=0;k<256;k++) g += hs[k]*whhT[(size_t)k*768 + tid];
    pa[tid] = a; pg[tid] = g;
  }
  __syncthreads();
  if(tid<256){
    float rr = sigm_f(pa[tid]     + bih[tid]     + pg[tid]     + bhh[tid]);
    float zz = sigm_f(pa[256+tid] + bih[256+tid] + pg[256+tid] + bhh[256+tid]);
    float nn = tanh_f(pa[512+tid] + bih[512+tid] + rr*(pg[512+tid] + bhh[512+tid]));
    m_out[b*256+tid] = (1.0f-zz)*nn + zz*hs[tid];
  }
}

// ---------------- fused final iteration + ENTIRE answer module (1024 threads) ----
// Same bit-identical restructure: gate-dots one-per-thread (768 threads),
// logits one output column per thread step, softmax max/sum kept in the
// original 256-thread form (exact summation order preserved).
__global__ __launch_bounds__(1024) void k_att_ans(
                          const float* __restrict__ h1, const float* __restrict__ w2,
                          const float* __restrict__ b2, const int* __restrict__ len_c,
                          const float* __restrict__ c_sel,
                          const float* __restrict__ m_in,
                          const float* __restrict__ mwihT, const float* __restrict__ mwhhT,
                          const float* __restrict__ mbih, const float* __restrict__ mbhh,
                          float* __restrict__ out_att,
                          const float* __restrict__ out_wT, const float* __restrict__ out_b,
                          const float* __restrict__ qh,
                          const float* __restrict__ awihT, const float* __restrict__ awhhT,
                          const float* __restrict__ abih, const float* __restrict__ abhh,
                          float* __restrict__ y_out)
{
  __shared__ float red[256];
  __shared__ float p[128];
  __shared__ float es[256];
  __shared__ float hs[256];
  __shared__ float yl[2000];
  __shared__ float ms[256];
  __shared__ float qs[256];
  __shared__ float pa[768];
  __shared__ float pg[768];
  int b = blockIdx.x, tid = threadIdx.x;

  // ---- att_tail part ----
  int L = len_c[b];
  float s = -1e30f;
  if(tid < 128 && tid < L){
    const float* hr = h1 + ((size_t)b*128 + tid)*128;
    float a = 0.0f;
    for(int k=0;k<100;k++) a += hr[k]*w2[k];
    s = a + b2[0];
  }
  if(tid < 256) red[tid]=s;
  __syncthreads();
  for(int o=128;o>0;o>>=1){ if(tid<o) red[tid]=fmaxf(red[tid],red[tid+o]); __syncthreads(); }
  float mx = red[0]; __syncthreads();
  float ex = (tid<128 && tid<L)? __expf(s-mx) : 0.0f;
  if(tid < 256) red[tid]=ex;
  __syncthreads();
  for(int o=128;o>0;o>>=1){ if(tid<o) red[tid]+=red[tid+o]; __syncthreads(); }
  float inv = 1.0f/red[0];
  if(tid<128){ float pv = ex*inv; p[tid]=pv; out_att[b*128+tid]=pv; }
  if(tid<256){ hs[tid] = m_in[b*256+tid]; qs[tid] = qh[b*256+tid]; }
  __syncthreads();
  if(tid<256){
    float acc = 0.0f;
    for(int si=0; si<128; si++) acc += p[si]*c_sel[((size_t)b*128+si)*256 + tid];
    es[tid] = acc;
  }
  __syncthreads();
  // mem gate dots -> ms (bit-identical per-output serial dots)
  if(tid < 768){
    float a = 0.0f;
    for(int k=0;k<256;k++) a += es[k]*mwihT[(size_t)k*768 + tid];
    float g = 0.0f;
    for(int k=0;k<256;k++) g += hs[k]*mwhhT[(size_t)k*768 + tid];
    pa[tid] = a; pg[tid] = g;
  }
  __syncthreads();
  if(tid<256){
    float rr = sigm_f(pa[tid]     + mbih[tid]     + pg[tid]     + mbhh[tid]);
    float zz = sigm_f(pa[256+tid] + mbih[256+tid] + pg[256+tid] + mbhh[256+tid]);
    float nn = tanh_f(pa[512+tid] + mbih[512+tid] + rr*(pg[512+tid] + mbhh[512+tid]));
    ms[tid] = (1.0f-zz)*nn + zz*hs[tid];
  }
  __syncthreads();

  // ---- answer module: 3 steps (ans GRU cell after the first two) ----
  for(int step=0; step<3; step++){
    // logits: one output column per thread-step (serial k, bias first — identical)
    for(int n=tid; n<2000; n+=1024){
      float a2 = out_b[n];
      for(int k=0;k<256;k++) a2 += ms[k]*out_wT[(size_t)k*2000 + n];
      yl[n] = a2;
    }
    __syncthreads();
    // softmax over 2000 — max/sum in the ORIGINAL 256-thread form (exact order)
    if(tid<256){
      float mx2 = -1e30f;
      for(int i=tid;i<2000;i+=256) mx2 = fmaxf(mx2, yl[i]);
      red[tid]=mx2;
    }
    __syncthreads();
    for(int o=128;o>0;o>>=1){ if(tid<o) red[tid]=fmaxf(red[tid],red[tid+o]); __syncthreads(); }
    float mx2 = red[0]; __syncthreads();
    if(tid<256){
      float sum=0.0f;
      for(int i=tid;i<2000;i+=256) sum += __expf(yl[i]-mx2);
      red[tid]=sum;
    }
    __syncthreads();
    for(int o=128;o>0;o>>=1){ if(tid<o) red[tid]+=red[tid+o]; __syncthreads(); }
    float inv2 = 1.0f/red[0];
    __syncthreads();
    // per-element normalize (value identical regardless of which thread computes it)
    for(int i=tid;i<2000;i+=1024){
      float yv = __expf(yl[i]-mx2)*inv2;
      yl[i] = yv;
      if(step==2) y_out[(size_t)b*2000+i] = yv;
    }
    if(step==2) break;
    __syncthreads();
    // ans gate dots: x = [y(2000) || qh(256)], one output per thread, same k-order
    if(tid < 768){
      float a = 0.0f;
      for(int k=0;k<2000;k++) a += yl[k]*awihT[(size_t)k*768 + tid];
      for(int k=0;k<256;k++)  a += qs[k]*awihT[(size_t)(2000+k)*768 + tid];
      float g = 0.0f;
      for(int k=0;k<256;k++)  g += ms[k]*awhhT[(size_t)k*768 + tid];
      pa[tid] = a; pg[tid] = g;
    }
    __syncthreads();
    if(tid<256){
      float rr = sigm_f(pa[tid]     + abih[tid]     + pg[tid]     + abhh[tid]);
      float zz = sigm_f(pa[256+tid] + abih[256+tid] + pg[256+tid] + abhh[256+tid]);
      float nn = tanh_f(pa[512+tid] + abih[512+tid] + rr*(pg[512+tid] + abhh[512+tid]));
      ms[tid] = (1.0f-zz)*nn + zz*ms[tid];
    }
    __syncthreads();
  }
}

// ---------------- launch ----------------
extern "C" void kernel_launch(void* const* d_in, const int* in_sizes, int n_in,
                              void* d_out, int out_size, void* d_ws, size_t ws_size,
                              hipStream_t stream)
{
  const float* c        = (const float*)d_in[0];
  const float* q        = (const float*)d_in[1];
  const float* i_state  = (const float*)d_in[2];
  const float* q_state  = (const float*)d_in[3];
  const float* in_w_ih  = (const float*)d_in[4];
  const float* in_w_hh  = (const float*)d_in[5];
  const float* in_b_ih  = (const float*)d_in[6];
  const float* in_b_hh  = (const float*)d_in[7];
  const float* qe_w_ih  = (const float*)d_in[8];
  const float* qe_w_hh  = (const float*)d_in[9];
  const float* qe_b_ih  = (const float*)d_in[10];
  const float* qe_b_hh  = (const float*)d_in[11];
  const float* att_weight = (const float*)d_in[12];
  const float* att_w1   = (const float*)d_in[13];
  const float* att_b1   = (const float*)d_in[14];
  const float* att_w2   = (const float*)d_in[15];
  const float* att_b2   = (const float*)d_in[16];
  const float* mem_w_ih = (const float*)d_in[17];
  const float* mem_w_hh = (const float*)d_in[18];
  const float* mem_b_ih = (const float*)d_in[19];
  const float* mem_b_hh = (const float*)d_in[20];
  const float* out_w    = (const float*)d_in[21];
  const float* out_b    = (const float*)d_in[22];
  const float* ans_w_ih = (const float*)d_in[23];
  const float* ans_w_hh = (const float*)d_in[24];
  const float* ans_b_ih = (const float*)d_in[25];
  const float* ans_b_hh = (const float*)d_in[26];
  const int*   c_index  = (const int*)d_in[27];
  const int*   len_c    = (const int*)d_in[28];
  float* outp = (float*)d_out;   // [0,64000) y ; [64000,76288) att (3,32,128)

  char* wp = (char*)d_ws;
  auto take = [&](size_t nbytes)->char*{
    char* p = wp; wp += (nbytes + 255) & ~(size_t)255; return p;
  };
  unsigned short* c_bf      = (unsigned short*)take((size_t)32*1024*128*2);
  unsigned short* q_bf      = (unsigned short*)take((size_t)32*32*128*2);
  unsigned short* wih_in_bf = (unsigned short*)take(768*128*2);
  unsigned short* wih_qe_bf = (unsigned short*)take(768*128*2);
  unsigned short* whh_in_bf = (unsigned short*)take(768*256*2);
  unsigned short* whh_qe_bf = (unsigned short*)take(768*256*2);
  unsigned short* attwT_bf  = (unsigned short*)take(256*256*2);
  unsigned short* attw1_bf  = (unsigned short*)take(128*1824*2);
  float* b1pad              = (float*)take(128*4);
  float* out_wT             = (float*)take((size_t)256*2000*4);
  float* mem_wihT           = (float*)take(256*768*4);
  float* mem_whhT           = (float*)take(256*768*4);
  float* ans_wihT           = (float*)take((size_t)2256*768*4);
  float* ans_whhT           = (float*)take(256*768*4);
  unsigned short* gi_c_bf   = (unsigned short*)take((size_t)32768*768*2);  // lane-packed
  unsigned short* gi_q_bf   = (unsigned short*)take((size_t)1024*768*2);   // lane-packed
  float* c_out              = (float*)take((size_t)32*1024*256*4);
  float* q_hT               = (float*)take(32*256*4);
  float* c_sel              = (float*)take((size_t)4096*256*4);
  unsigned short* c_sel_bf  = (unsigned short*)take((size_t)4096*256*2);
  float* cw                 = (float*)take((size_t)4096*256*4);
  unsigned short* feats_bf  = (unsigned short*)take((size_t)4096*1824*2);
  float* h1                 = (float*)take((size_t)4096*128*4);
  float* m_buf              = (float*)take(32*256*4);

  // ---- prep / conversions: ONE fused launch ----
  k_prep_all<<<31441,256,0,stream>>>(c, c_bf, q, q_bf,
                                     in_w_ih, wih_in_bf, qe_w_ih, wih_qe_bf,
                                     in_w_hh, whh_in_bf, qe_w_hh, whh_qe_bf,
                                     att_weight, attwT_bf, att_w1, attw1_bf,
                                     att_b1, b1pad,
                                     out_w, out_wT,
                                     mem_w_ih, mem_wihT, mem_w_hh, mem_whhT,
                                     ans_w_ih, ans_wihT, ans_w_hh, ans_whhT);

  // ---- time-parallel input projections (c and q problems in ONE launch) ----
  k_gemm_gi2<<<dim3(528,12),256,0,stream>>>(c_bf, wih_in_bf, in_b_ih, gi_c_bf,
                                            q_bf, wih_qe_bf, qe_b_ih, gi_q_bf);

  // ---- sequential GRU recurrences (context 1024 steps + query 32 steps) ----
  k_gru_rec<<<4,512,0,stream>>>(whh_in_bf, whh_qe_bf, gi_c_bf, gi_q_bf,
                                in_b_hh, qe_b_hh, i_state, q_state, c_out, q_hT);

  // ---- attention setup ----
  k_gather<<<4096,256,0,stream>>>(c_out, c_index, c_sel, c_sel_bf);
  k_gemm_bf16<<<dim3(64,4),256,0,stream>>>(c_sel_bf, attwT_bf, 256, nullptr, 0, cw, nullptr, 256);

  // ---- episodic iterations 0,1 (fused tail); iteration 2 fused with answer module ----
  for(int it=0; it<2; it++){
    const float* m_cur = (it==0)? q_hT : m_buf;
    k_feats<<<4096,256,0,stream>>>(c_sel, cw, m_cur, q_hT, feats_bf);
    k_gemm_bf16<<<dim3(64,2),256,0,stream>>>(feats_bf, attw1_bf, 1824, b1pad, 1, h1, nullptr, 128);
    k_att_tail<<<32,1024,0,stream>>>(h1, att_w2, att_b2, len_c, c_sel, m_cur,
                                     mem_wihT, mem_whhT, mem_b_ih, mem_b_hh,
                                     outp + 64000 + it*4096, m_buf);
  }
  // iteration 2 + entire answer module in ONE kernel
  k_feats<<<4096,256,0,stream>>>(c_sel, cw, m_buf, q_hT, feats_bf);
  k_gemm_bf16<<<dim3(64,2),256,0,stream>>>(feats_bf, attw1_bf, 1824, b1pad, 1, h1, nullptr, 128);
  k_att_ans<<<32,1024,0,stream>>>(h1, att_w2, att_b2, len_c, c_sel, m_buf,
                                  mem_wihT, mem_whhT, mem_b_ih, mem_b_hh,
                                  outp + 64000 + 2*4096,
                                  out_wT, out_b, q_hT,
                                  ans_wihT, ans_whhT, ans_b_ih, ans_b_hh,
                                  outp);
}